// Round 11
// baseline (1161.761 us; speedup 1.0000x reference)
//
#include <hip/hip_runtime.h>
#include <hip/hip_fp16.h>
#include <hip/hip_cooperative_groups.h>
#include <cstdint>
#include <cstddef>

namespace cg = cooperative_groups;

typedef unsigned short u16;
typedef __attribute__((ext_vector_type(8))) short short8;
typedef __attribute__((ext_vector_type(4))) float f32x4;

// ---- problem constants ----
#define B_   64
#define S_   256
#define D_   128
#define H_   8
#define FF_  512
#define L_   4
#define U_   5000
#define UP_  5120
#define N_   40000
#define NP_  40064
#define E_   160000
#define FEA_ 32
#define CED_ 16
#define TD_  6
#define NSCB 157
#define UB_CNT_END 160
#define UB_CVT_END 1592
#define UB_TOTAL   5688
#define KLS 40
#define VTS 272

static __device__ __forceinline__ u16 f2b(float f) {
    unsigned int u = __float_as_uint(f);
    unsigned int r = (u + 0x7FFFu + ((u >> 16) & 1u)) >> 16;
    return (u16)r;
}
static __device__ __forceinline__ float b2f(u16 u) {
    return __uint_as_float(((unsigned int)u) << 16);
}
static __device__ __forceinline__ u16 f2h(float f) {
    return __half_as_ushort(__float2half(f));
}
static __device__ __forceinline__ float h2f(u16 u) {
    return __half2float(__ushort_as_half(u));
}
static __device__ __forceinline__ void gload16(const void* g, void* l) {
    __builtin_amdgcn_global_load_lds(
        (const __attribute__((address_space(1))) unsigned int*)g,
        (__attribute__((address_space(3))) unsigned int*)l,
        16, 0, 0);
}

struct MegaArgs {
    // uber: weight transposes + bias + cnt zero
    const float* csrc[7];
    u16* cdst[7];
    int K[7], Npad[7], Nsrc[7], Kp[7], base[7];
    const float* tm; const float* dm; const int* maskp; const float* lambda2;
    u16* biasb; int* cnt;
    // csr
    const int* esrc; const int* edst;
    int* part; int* off; int* cursor; int* ebuf;
    // gnn
    const float* nf;
    u16* in1b; u16* h1b; u16* in2b; float* spe;
    const float* gnn_b1; const float* gnn_b2;
    const u16* gw1T; const u16* gw2T;
    // fusion
    const int* traj; const float* ue_tab; const int* uid; const float* tempx;
    const int* hwx; const float* ce_tab; const float* flw; const float* flb;
    float* x; u16* xb;
    // transformer
    const u16* wqkvT; const float* bqkv;
    const u16* woT; const float* bo;
    const float* ln1g; const float* ln1b;
    const u16* w1T; const float* fb1; const u16* w2T; const float* fb2;
    const float* ln2g; const float* ln2b;
    u16* attob;
    // head
    const u16* hwT; const float* head_b; const int* endi; float* out;
};

// ===================== phase: uber (cnt zero + 7 cvtT + attn bias) =====================
static __device__ __forceinline__ void ph_uber(const MegaArgs& a, char* smemc, int nG) {
    float (*tile)[33] = (float(*)[33])smemc;
    int tid = threadIdx.x;
    for (int bid = blockIdx.x; bid < UB_TOTAL; bid += nG) {
        __syncthreads();
        if (bid < UB_CNT_END) {
            int idx = bid * 256 + tid;
            if (idx < NP_) a.cnt[idx] = 0;
        } else if (bid < UB_CVT_END) {
            int t = 0;
#pragma unroll
            for (int i = 1; i < 7; ++i) t += (bid >= a.base[i]);
            int rb = bid - a.base[t];
            int K = a.K[t], Npad = a.Npad[t], Nsrc = a.Nsrc[t], Kp = a.Kp[t];
            int nbn = Npad >> 5, nbk = Kp >> 5;
            int per = nbn * nbk;
            int l = rb / per, rem = rb - l * per;
            int n0 = (rem % nbn) * 32, k0 = (rem / nbn) * 32;
            const float* in = a.csrc[t];
            u16* outp = a.cdst[t];
            int j = tid & 31, i2 = tid >> 5;
#pragma unroll
            for (int r = 0; r < 4; ++r) {
                int k = k0 + i2 + r * 8, n = n0 + j;
                tile[i2 + r * 8][j] = (k < K && n < Nsrc) ? in[(size_t)l * K * Nsrc + (size_t)k * Nsrc + n] : 0.f;
            }
            __syncthreads();
#pragma unroll
            for (int r = 0; r < 4; ++r) {
                int n = n0 + i2 + r * 8, k = k0 + j;
                if (n < Npad && k < Kp)
                    outp[(size_t)l * Npad * Kp + (size_t)n * Kp + k] = f2b(tile[j][i2 + r * 8]);
            }
        } else {
            int t4 = (bid - UB_CVT_END) * 256 + tid;
            if (t4 < B_ * S_ * S_ / 4) {
                float l2 = *a.lambda2, l2c = 1.f - l2;
                float4 av = ((const float4*)a.tm)[t4];
                float4 bv = ((const float4*)a.dm)[t4];
                int basei = t4 * 4;
                int bb = basei >> 16;
                int k0 = basei & 255;
                const int* mrow = a.maskp + bb * S_;
                float r0 = (mrow[k0 + 0] > 0 ? 0.f : -30000.f) - (l2 * __logf(1.f + av.x) + l2c * __logf(1.f + bv.x));
                float r1 = (mrow[k0 + 1] > 0 ? 0.f : -30000.f) - (l2 * __logf(1.f + av.y) + l2c * __logf(1.f + bv.y));
                float r2 = (mrow[k0 + 2] > 0 ? 0.f : -30000.f) - (l2 * __logf(1.f + av.z) + l2c * __logf(1.f + bv.z));
                float r3 = (mrow[k0 + 3] > 0 ? 0.f : -30000.f) - (l2 * __logf(1.f + av.w) + l2c * __logf(1.f + bv.w));
                *(ushort4*)&a.biasb[(size_t)t4 * 4] = make_ushort4(f2h(r0), f2h(r1), f2h(r2), f2h(r3));
            }
        }
    }
}

// ===================== phase: CSR =====================
static __device__ __forceinline__ void ph_count(const MegaArgs& a, int nG) {
    for (int e = blockIdx.x * 256 + threadIdx.x; e < E_; e += nG * 256)
        atomicAdd(&a.cnt[a.edst[e]], 1);
}

static __device__ __forceinline__ void ph_scanA(const MegaArgs& a, char* smemc, int nG) {
    int* sh = (int*)smemc;
    int tid = threadIdx.x;
    for (int wb = blockIdx.x; wb < NSCB; wb += nG) {
        __syncthreads();
        int idx = wb * 256 + tid;
        sh[tid] = (idx < NP_) ? a.cnt[idx] : 0;
        __syncthreads();
        for (int o = 128; o > 0; o >>= 1) {
            if (tid < o) sh[tid] += sh[tid + o];
            __syncthreads();
        }
        if (tid == 0) a.part[wb] = sh[0];
    }
}

static __device__ __forceinline__ void ph_scanB(const MegaArgs& a, char* smemc, int nG) {
    int* sh = (int*)smemc;
    int* bsum = (int*)(smemc + 1024);
    int tid = threadIdx.x;
    for (int wb = blockIdx.x; wb < NSCB; wb += nG) {
        __syncthreads();
        int pv = (tid < wb) ? a.part[tid] : 0;
        sh[tid] = pv;
        __syncthreads();
        for (int o = 128; o > 0; o >>= 1) {
            if (tid < o) sh[tid] += sh[tid + o];
            __syncthreads();
        }
        if (tid == 0) *bsum = sh[0];
        __syncthreads();
        int basev = *bsum;
        __syncthreads();
        int idx = wb * 256 + tid;
        int v = (idx < NP_) ? a.cnt[idx] : 0;
        sh[tid] = v;
        __syncthreads();
        for (int o = 1; o < 256; o <<= 1) {
            int t2 = (tid >= o) ? sh[tid - o] : 0;
            __syncthreads();
            sh[tid] += t2;
            __syncthreads();
        }
        if (idx < NP_) {
            int res = sh[tid] - v + basev;
            a.off[idx] = res;
            a.cursor[idx] = res;
        }
    }
}

static __device__ __forceinline__ void ph_fill(const MegaArgs& a, int nG) {
    for (int e = blockIdx.x * 256 + threadIdx.x; e < E_; e += nG * 256) {
        int p = atomicAdd(&a.cursor[a.edst[e]], 1);
        a.ebuf[p] = a.esrc[e];
    }
}

// ===================== phase: GNN gathers =====================
static __device__ __forceinline__ void ph_gprep1(const MegaArgs& a, int nG) {
    int tid = threadIdx.x;
    for (int wb = blockIdx.x; wb < NP_ / 8; wb += nG) {
        int n = wb * 8 + (tid >> 5);
        int f = tid & 31;
        u16 r = 0;
        if (n < N_) {
            int start = a.off[n], c = a.cnt[n];
            float acc = 0.f;
            int i = 0;
            for (; i + 4 <= c; i += 4) {
                int s0 = a.ebuf[start + i], s1 = a.ebuf[start + i + 1];
                int s2 = a.ebuf[start + i + 2], s3 = a.ebuf[start + i + 3];
                float v0 = a.nf[(size_t)s0 * FEA_ + f];
                float v1 = a.nf[(size_t)s1 * FEA_ + f];
                float v2 = a.nf[(size_t)s2 * FEA_ + f];
                float v3 = a.nf[(size_t)s3 * FEA_ + f];
                acc += (v0 + v1) + (v2 + v3);
            }
            for (; i < c; ++i) acc += a.nf[(size_t)a.ebuf[start + i] * FEA_ + f];
            r = f2b(a.nf[(size_t)n * FEA_ + f] + acc / (float)(c + 1));
        }
        a.in1b[(size_t)n * 64 + f] = r;
        a.in1b[(size_t)n * 64 + 32 + f] = 0;
    }
}

static __device__ __forceinline__ void ph_gprep2(const MegaArgs& a, int nG) {
    int tid = threadIdx.x;
    for (int wb = blockIdx.x; wb < NP_ / 4; wb += nG) {
        int n = wb * 4 + (tid >> 6);
        int d2 = (tid & 63) * 2;
        u16 r0 = 0, r1 = 0;
        if (n < N_) {
            int start = a.off[n], c = a.cnt[n];
            float a0 = 0.f, a1 = 0.f;
            int i = 0;
            for (; i + 4 <= c; i += 4) {
                int s0 = a.ebuf[start + i], s1 = a.ebuf[start + i + 1];
                int s2 = a.ebuf[start + i + 2], s3 = a.ebuf[start + i + 3];
                ushort2 v0 = *(const ushort2*)&a.h1b[(size_t)s0 * D_ + d2];
                ushort2 v1 = *(const ushort2*)&a.h1b[(size_t)s1 * D_ + d2];
                ushort2 v2 = *(const ushort2*)&a.h1b[(size_t)s2 * D_ + d2];
                ushort2 v3 = *(const ushort2*)&a.h1b[(size_t)s3 * D_ + d2];
                a0 += (b2f(v0.x) + b2f(v1.x)) + (b2f(v2.x) + b2f(v3.x));
                a1 += (b2f(v0.y) + b2f(v1.y)) + (b2f(v2.y) + b2f(v3.y));
            }
            for (; i < c; ++i) {
                ushort2 v = *(const ushort2*)&a.h1b[(size_t)a.ebuf[start + i] * D_ + d2];
                a0 += b2f(v.x); a1 += b2f(v.y);
            }
            float rinv = 1.f / (float)(c + 1);
            ushort2 sv = *(const ushort2*)&a.h1b[(size_t)n * D_ + d2];
            r0 = f2b(b2f(sv.x) + a0 * rinv);
            r1 = f2b(b2f(sv.y) + a1 * rinv);
        }
        *(ushort2*)&a.in2b[(size_t)n * D_ + d2] = make_ushort2(r0, r1);
    }
}

// ===================== phase: MFMA GEMM =====================
template<int BM, int ACT, int OUTB, int GAT>
static __device__ __forceinline__ void ph_mgemm(char* smemc, const u16* A, const u16* BT,
                                                const float* bias, void* Cout, const int* endi,
                                                int M, int N, int K, int nbx, int nby, int nG) {
    u16* Al = (u16*)smemc;
    u16* Bl = Al + (BM == 128 ? 128 * 64 : 64 * 64);
    int tid = threadIdx.x;
    int wid = tid >> 6, lane = tid & 63;
    int rA = lane & 15, kq = lane >> 4;
    for (int wb = blockIdx.x; wb < nbx * nby; wb += nG) {
        __syncthreads();
        int bx = wb % nbx, by = wb / nbx;
        int row0 = bx * BM, col0 = by * 128;
        f32x4 acc[4][4] = {};
        for (int k0 = 0; k0 < K; k0 += 64) {
            if (k0) __syncthreads();
            if (BM == 128) {
                int srow = wid * 32 + (lane >> 3);
                int ks8 = ((lane & 7) ^ (lane >> 3)) * 8;
#pragma unroll
                for (int i = 0; i < 4; ++i) {
                    int row = srow + i * 8;
                    size_t arow = (size_t)(row0 + row);
                    if (GAT) {
                        int bb2 = row0 + row;
                        arow = (bb2 < B_) ? ((size_t)bb2 * S_ + endi[bb2]) : 0;
                    }
                    gload16(A + arow * K + k0 + ks8, &Al[(wid * 32 + i * 8) * 64]);
                    gload16(BT + (size_t)(col0 + row) * K + k0 + ks8, &Bl[(wid * 32 + i * 8) * 64]);
                }
            } else {
#pragma unroll
                for (int i = 0; i < 6; ++i) {
                    int c = wid * 6 + i;
                    int rr = c * 8 + (lane >> 3);
                    int sl = (((lane & 7) ^ (rr & 7)) << 3);
                    if (c < 8) {
                        size_t arow = (size_t)(row0 + rr);
                        if (GAT) {
                            int bb2 = row0 + rr;
                            arow = (bb2 < B_) ? ((size_t)bb2 * S_ + endi[bb2]) : 0;
                        }
                        gload16(A + arow * K + k0 + sl, &Al[rr * 64]);
                    } else {
                        gload16(BT + (size_t)(col0 + rr - 64) * K + k0 + sl, &Bl[(rr - 64) * 64]);
                    }
                }
            }
            __syncthreads();
#pragma unroll
            for (int ks = 0; ks < 2; ++ks) {
                int sw = ((ks * 4 + kq) ^ (rA & 7)) * 8;
                if (BM == 128) {
                    int wr = wid >> 1, wc = wid & 1;
                    short8 af[4], bfr[4];
#pragma unroll
                    for (int m = 0; m < 4; ++m)
                        af[m] = *(const short8*)&Al[(64 * wr + m * 16 + rA) * 64 + sw];
#pragma unroll
                    for (int n = 0; n < 4; ++n)
                        bfr[n] = *(const short8*)&Bl[(64 * wc + n * 16 + rA) * 64 + sw];
#pragma unroll
                    for (int m = 0; m < 4; ++m)
#pragma unroll
                        for (int n = 0; n < 4; ++n)
                            acc[m][n] = __builtin_amdgcn_mfma_f32_16x16x32_bf16(af[m], bfr[n], acc[m][n], 0, 0, 0);
                } else {
                    int wr2 = wid & 1, wc2 = wid >> 1;
                    short8 af[2], bfr[4];
#pragma unroll
                    for (int m = 0; m < 2; ++m)
                        af[m] = *(const short8*)&Al[(wr2 * 32 + m * 16 + rA) * 64 + sw];
#pragma unroll
                    for (int n = 0; n < 4; ++n)
                        bfr[n] = *(const short8*)&Bl[(wc2 * 64 + n * 16 + rA) * 64 + sw];
#pragma unroll
                    for (int m = 0; m < 2; ++m)
#pragma unroll
                        for (int n = 0; n < 4; ++n)
                            acc[m][n] = __builtin_amdgcn_mfma_f32_16x16x32_bf16(af[m], bfr[n], acc[m][n], 0, 0, 0);
                }
            }
        }
        constexpr int MR = (BM == 128) ? 4 : 2;
#pragma unroll
        for (int m = 0; m < MR; ++m) {
#pragma unroll
            for (int n = 0; n < 4; ++n) {
                int cc, cr0;
                if (BM == 128) { cc = col0 + (wid & 1) * 64 + n * 16 + rA; cr0 = row0 + (wid >> 1) * 64 + m * 16 + kq * 4; }
                else           { cc = col0 + (wid >> 1) * 64 + n * 16 + rA; cr0 = row0 + (wid & 1) * 32 + m * 16 + kq * 4; }
                if (cc >= N) continue;
                float bv = bias[cc];
#pragma unroll
                for (int r = 0; r < 4; ++r) {
                    int cr = cr0 + r;
                    if (cr >= M) continue;
                    float v = acc[m][n][r] + bv;
                    if (ACT) v = fmaxf(v, 0.f);
                    if (OUTB) ((u16*)Cout)[(size_t)cr * N + cc] = f2b(v);
                    else      ((float*)Cout)[(size_t)cr * N + cc] = v;
                }
            }
        }
    }
}

// ===================== phase: fusion =====================
static __device__ __forceinline__ void ph_fusion(const MegaArgs& a, char* smemc, int nG) {
    float* Ws = (float*)smemc;                    // 22*128
    float* bs = (float*)(smemc + 11264);          // 128
    float (*ins)[22] = (float(*)[22])(smemc + 11776);
    int tid = threadIdx.x;
    for (int wb = blockIdx.x; wb < (B_ * S_) / 32; wb += nG) {
        __syncthreads();
        for (int i = tid; i < 22 * D_; i += 256) Ws[i] = a.flw[i];
        if (tid < D_) bs[tid] = a.flb[tid];
        __syncthreads();
        int ro = tid >> 7, d = tid & 127;
        int base = wb * 32;
        for (int ir = 0; ir < 16; ++ir) {
            int tok = base + ir * 2 + ro;
            int b = tok >> 8, s = tok & 255;
            if (d < TD_) ins[ro][d] = a.tempx[(size_t)tok * TD_ + d];
            else if (d < 22) ins[ro][d] = a.ce_tab[(size_t)a.hwx[tok] * CED_ + (d - TD_)];
            __syncthreads();
            float acc = bs[d];
#pragma unroll
            for (int k = 0; k < 22; ++k) acc = fmaf(ins[ro][k], Ws[k * D_ + d], acc);
            acc = fmaxf(acc, 0.f);
            int i2 = d & ~1;
            float ang = (float)s * __expf(-(float)i2 * 0.0719557841560639f);
            float pe = (d & 1) ? cosf(ang) : sinf(ang);
            float v = a.spe[(size_t)a.traj[tok] * D_ + d] + a.ue_tab[(size_t)a.uid[b] * D_ + d] + acc + pe;
            a.x[(size_t)tok * D_ + d] = v;
            a.xb[(size_t)tok * D_ + d] = f2b(v);
            __syncthreads();
        }
    }
}

// ===================== phase: fused QKV-proj + attention =====================
static __device__ __forceinline__ void ph_qkvatt(const MegaArgs& a, char* smemc, int l, int nG) {
    u16* Kl  = (u16*)smemc;
    u16* Vt  = (u16*)(smemc + 20480);
    u16* Ql  = (u16*)(smemc + 29184);
    u16* Pl  = (u16*)(smemc + 37376);
    u16* Ast = (u16*)smemc;
    u16* Bst = (u16*)(smemc + 32768);
    const u16* wT = a.wqkvT + (size_t)l * 384 * 128;
    const float* bq = a.bqkv + (size_t)l * 384;
    int tid = threadIdx.x, wid = tid >> 6, lane = tid & 63;
    int rA = lane & 15, kq = lane >> 4;
    for (int wb = blockIdx.x; wb < B_ * H_; wb += nG) {
        __syncthreads();
        int b = (wb & 7) * 8 + (wb >> 6);
        int h = (wb >> 3) & 7;
        f32x4 acc[4][3] = {};
        for (int k0 = 0; k0 < 128; k0 += 64) {
            if (k0) __syncthreads();
#pragma unroll
            for (int i = 0; i < 8; ++i) {
                int row = wid * 64 + i * 8 + (lane >> 3);
                int sl = (((lane & 7) ^ (row & 7)) << 3);
                gload16(a.xb + ((size_t)(b * S_ + row)) * 128 + k0 + sl, &Ast[(wid * 64 + i * 8) * 64]);
            }
            if (wid < 3) {
#pragma unroll
                for (int i = 0; i < 2; ++i) {
                    int c = wid * 2 + i;
                    int brow = c * 8 + (lane >> 3);
                    int grow = wid * 128 + h * 16 + (brow & 15);
                    int sl = (((lane & 7) ^ (brow & 7)) << 3);
                    gload16(wT + (size_t)grow * 128 + k0 + sl, &Bst[c * 8 * 64]);
                }
            }
            __syncthreads();
#pragma unroll
            for (int ks = 0; ks < 2; ++ks) {
                int sw = ((ks * 4 + kq) ^ (rA & 7)) * 8;
                short8 af[4], bfr[3];
#pragma unroll
                for (int m = 0; m < 4; ++m)
                    af[m] = *(const short8*)&Ast[(wid * 64 + m * 16 + rA) * 64 + sw];
#pragma unroll
                for (int n = 0; n < 3; ++n)
                    bfr[n] = *(const short8*)&Bst[(n * 16 + rA) * 64 + sw];
#pragma unroll
                for (int m = 0; m < 4; ++m)
#pragma unroll
                    for (int n = 0; n < 3; ++n)
                        acc[m][n] = __builtin_amdgcn_mfma_f32_16x16x32_bf16(af[m], bfr[n], acc[m][n], 0, 0, 0);
            }
        }
        __syncthreads();
        {
            short8 z = {};
            *(short8*)&Kl[tid * KLS + 16] = z;
            *(short8*)&Kl[tid * KLS + 24] = z;
        }
        {
            float bq0 = bq[h * 16 + rA];
            float bq1 = bq[128 + h * 16 + rA];
            float bq2 = bq[256 + h * 16 + rA];
#pragma unroll
            for (int m = 0; m < 4; ++m) {
                int cr0 = wid * 64 + m * 16 + kq * 4;
#pragma unroll
                for (int r = 0; r < 4; ++r) {
                    int row = cr0 + r;
                    Ql[row * 16 + rA]  = f2b(acc[m][0][r] + bq0);
                    Kl[row * KLS + rA] = f2b(acc[m][1][r] + bq1);
                    Vt[rA * VTS + row] = f2b(acc[m][2][r] + bq2);
                }
            }
        }
        __syncthreads();
        u16* pl = Pl + wid * 16 * VTS;
        int qi = lane & 15;
        for (int qt = 0; qt < 4; ++qt) {
            int q = wid * 64 + qt * 16 + qi;
            ushort4 bb[16];
            const u16* bp = a.biasb + (size_t)b * (S_ * S_) + (size_t)q * S_ + kq * 4;
#pragma unroll
            for (int t = 0; t < 16; ++t) bb[t] = *(const ushort4*)(bp + t * 16);
            short8 qf = {};
            if (lane < 32)
                qf = *(const short8*)&Ql[q * 16 + kq * 8];
            f32x4 sc[16];
#pragma unroll
            for (int t = 0; t < 16; ++t) {
                short8 kf = *(const short8*)&Kl[(t * 16 + qi) * KLS + kq * 8];
                f32x4 zz = {0.f, 0.f, 0.f, 0.f};
                sc[t] = __builtin_amdgcn_mfma_f32_16x16x32_bf16(kf, qf, zz, 0, 0, 0);
            }
            float m = -1e30f;
#pragma unroll
            for (int t = 0; t < 16; ++t) {
                sc[t][0] = sc[t][0] * 0.25f + h2f(bb[t].x);
                sc[t][1] = sc[t][1] * 0.25f + h2f(bb[t].y);
                sc[t][2] = sc[t][2] * 0.25f + h2f(bb[t].z);
                sc[t][3] = sc[t][3] * 0.25f + h2f(bb[t].w);
                m = fmaxf(m, fmaxf(fmaxf(sc[t][0], sc[t][1]), fmaxf(sc[t][2], sc[t][3])));
            }
            m = fmaxf(m, __shfl_xor(m, 16, 64));
            m = fmaxf(m, __shfl_xor(m, 32, 64));
            float lsum = 0.f;
#pragma unroll
            for (int t = 0; t < 16; ++t) {
                sc[t][0] = __expf(sc[t][0] - m);
                sc[t][1] = __expf(sc[t][1] - m);
                sc[t][2] = __expf(sc[t][2] - m);
                sc[t][3] = __expf(sc[t][3] - m);
                lsum += (sc[t][0] + sc[t][1]) + (sc[t][2] + sc[t][3]);
            }
            lsum += __shfl_xor(lsum, 16, 64);
            lsum += __shfl_xor(lsum, 32, 64);
            float inv = 1.f / lsum;
#pragma unroll
            for (int t = 0; t < 16; ++t) {
                ushort4 pw = make_ushort4(f2b(sc[t][0] * inv), f2b(sc[t][1] * inv),
                                          f2b(sc[t][2] * inv), f2b(sc[t][3] * inv));
                *(ushort4*)&pl[qi * VTS + t * 16 + kq * 4] = pw;
            }
            f32x4 oa = {0.f, 0.f, 0.f, 0.f};
#pragma unroll
            for (int w8 = 0; w8 < 8; ++w8) {
                short8 vf = *(const short8*)&Vt[qi * VTS + w8 * 32 + kq * 8];
                short8 pf = *(const short8*)&pl[qi * VTS + w8 * 32 + kq * 8];
                oa = __builtin_amdgcn_mfma_f32_16x16x32_bf16(vf, pf, oa, 0, 0, 0);
            }
            ushort4 ow = make_ushort4(f2b(oa[0]), f2b(oa[1]), f2b(oa[2]), f2b(oa[3]));
            *(ushort4*)&a.attob[((size_t)(b * S_ + q)) * D_ + h * 16 + kq * 4] = ow;
        }
    }
}

// ===================== phase: layer tail (wo+LN1+FFN+LN2) =====================
static __device__ __forceinline__ void ph_layer(const MegaArgs& a, char* smemc, int l, int nG) {
    u16* Alds = (u16*)smemc;
    u16* Wlds = (u16*)(smemc + 8192);
    u16* f1   = (u16*)(smemc + 40960);
    float* vbuf = (float*)smemc;
    const u16* woT = a.woT + (size_t)l * 128 * 128;
    const float* bo = a.bo + (size_t)l * D_;
    const float* ln1g = a.ln1g + (size_t)l * D_;
    const float* ln1b = a.ln1b + (size_t)l * D_;
    const u16* w1T = a.w1T + (size_t)l * 512 * 128;
    const float* b1 = a.fb1 + (size_t)l * FF_;
    const u16* w2T = a.w2T + (size_t)l * 128 * 512;
    const float* b2 = a.fb2 + (size_t)l * D_;
    const float* ln2g = a.ln2g + (size_t)l * D_;
    const float* ln2b = a.ln2b + (size_t)l * D_;
    int tid = threadIdx.x, wid = tid >> 6, lane = tid & 63;
    int rA = lane & 15, kq = lane >> 4;
    int row = tid >> 3, sub = tid & 7;
    for (int wb = blockIdx.x; wb < (B_ * S_) / 32; wb += nG) {
        __syncthreads();
        int rows0 = wb * 32;
#pragma unroll
        for (int j = 0; j < 2; ++j) {
            int srow = wid * 8 + j * 4 + (lane >> 4);
            int win = (lane >> 3) & 1, slot = lane & 7;
            gload16(a.attob + (size_t)(rows0 + srow) * 128 + win * 64 + ((slot ^ (srow & 7)) << 3),
                    Alds + (wid * 8 + j * 4) * 128);
        }
        f32x4 accw[2][2] = {};
        for (int k0 = 0; k0 < 128; k0 += 64) {
            __syncthreads();
#pragma unroll
            for (int i = 0; i < 4; ++i) {
                int rl2 = i * 32 + wid * 8 + (lane >> 3);
                gload16(woT + (size_t)rl2 * 128 + k0 + (((lane & 7) ^ (rl2 & 7)) << 3),
                        Wlds + (i * 32 + wid * 8) * 64);
            }
            __syncthreads();
#pragma unroll
            for (int ks = 0; ks < 2; ++ks) {
                int sw = ((ks * 4 + kq) ^ (rA & 7)) << 3;
                short8 af0 = *(const short8*)&Alds[rA * 128 + k0 + sw];
                short8 af1 = *(const short8*)&Alds[(16 + rA) * 128 + k0 + sw];
                short8 bf0 = *(const short8*)&Wlds[(wid * 32 + rA) * 64 + sw];
                short8 bf1 = *(const short8*)&Wlds[(wid * 32 + 16 + rA) * 64 + sw];
                accw[0][0] = __builtin_amdgcn_mfma_f32_16x16x32_bf16(af0, bf0, accw[0][0], 0, 0, 0);
                accw[0][1] = __builtin_amdgcn_mfma_f32_16x16x32_bf16(af0, bf1, accw[0][1], 0, 0, 0);
                accw[1][0] = __builtin_amdgcn_mfma_f32_16x16x32_bf16(af1, bf0, accw[1][0], 0, 0, 0);
                accw[1][1] = __builtin_amdgcn_mfma_f32_16x16x32_bf16(af1, bf1, accw[1][1], 0, 0, 0);
            }
        }
        __syncthreads();
#pragma unroll
        for (int m = 0; m < 2; ++m)
#pragma unroll
            for (int n = 0; n < 2; ++n) {
                int cc = wid * 32 + n * 16 + rA;
                float bv = bo[cc];
#pragma unroll
                for (int r = 0; r < 4; ++r) {
                    int rl = m * 16 + kq * 4 + r;
                    vbuf[rl * 133 + cc] = accw[m][n][r] + bv + a.x[(size_t)(rows0 + rl) * 128 + cc];
                }
            }
        __syncthreads();
        float x1[16];
        {
            const float* vr = vbuf + row * 133 + sub * 16;
            float s = 0.f, s2 = 0.f;
#pragma unroll
            for (int j = 0; j < 16; ++j) {
                x1[j] = vr[j];
                s += x1[j];
                s2 += x1[j] * x1[j];
            }
            s += __shfl_xor(s, 1, 64);  s2 += __shfl_xor(s2, 1, 64);
            s += __shfl_xor(s, 2, 64);  s2 += __shfl_xor(s2, 2, 64);
            s += __shfl_xor(s, 4, 64);  s2 += __shfl_xor(s2, 4, 64);
            float mean = s * (1.f / 128.f);
            float var = s2 * (1.f / 128.f) - mean * mean;
            float rs = rsqrtf(var + 1e-5f);
#pragma unroll
            for (int j = 0; j < 4; ++j) {
                float4 gv = *(const float4*)(ln1g + sub * 16 + j * 4);
                float4 bv = *(const float4*)(ln1b + sub * 16 + j * 4);
                x1[j * 4 + 0] = (x1[j * 4 + 0] - mean) * rs * gv.x + bv.x;
                x1[j * 4 + 1] = (x1[j * 4 + 1] - mean) * rs * gv.y + bv.y;
                x1[j * 4 + 2] = (x1[j * 4 + 2] - mean) * rs * gv.z + bv.z;
                x1[j * 4 + 3] = (x1[j * 4 + 3] - mean) * rs * gv.w + bv.w;
            }
        }
        __syncthreads();
#pragma unroll
        for (int j = 0; j < 16; ++j) {
            int c = sub * 16 + j;
            int scol = (c & ~63) | ((((c >> 3) & 7) ^ (row & 7)) << 3) | (c & 7);
            Alds[row * 128 + scol] = f2b(x1[j]);
        }
        for (int nh = 0; nh < 2; ++nh) {
            f32x4 acc1[2][4] = {};
            for (int k0 = 0; k0 < 128; k0 += 64) {
                __syncthreads();
#pragma unroll
                for (int i = 0; i < 8; ++i) {
                    int rl2 = i * 32 + wid * 8 + (lane >> 3);
                    gload16(w1T + (size_t)(nh * 256 + rl2) * 128 + k0 + (((lane & 7) ^ (rl2 & 7)) << 3),
                            Wlds + (i * 32 + wid * 8) * 64);
                }
                __syncthreads();
#pragma unroll
                for (int ks = 0; ks < 2; ++ks) {
                    int sw = ((ks * 4 + kq) ^ (rA & 7)) << 3;
                    short8 af[2], bf4[4];
                    af[0] = *(const short8*)&Alds[rA * 128 + k0 + sw];
                    af[1] = *(const short8*)&Alds[(16 + rA) * 128 + k0 + sw];
#pragma unroll
                    for (int n = 0; n < 4; ++n)
                        bf4[n] = *(const short8*)&Wlds[(wid * 64 + n * 16 + rA) * 64 + sw];
#pragma unroll
                    for (int m = 0; m < 2; ++m)
#pragma unroll
                        for (int n = 0; n < 4; ++n)
                            acc1[m][n] = __builtin_amdgcn_mfma_f32_16x16x32_bf16(af[m], bf4[n], acc1[m][n], 0, 0, 0);
                }
            }
#pragma unroll
            for (int m = 0; m < 2; ++m)
#pragma unroll
                for (int n = 0; n < 4; ++n) {
                    int cc = nh * 256 + wid * 64 + n * 16 + rA;
                    float bv = b1[cc];
#pragma unroll
                    for (int r = 0; r < 4; ++r) {
                        int rl = m * 16 + kq * 4 + r;
                        float v = fmaxf(acc1[m][n][r] + bv, 0.f);
                        int scol = (cc & ~63) | (((((cc >> 3) & 7) ^ (rl & 7)) & 7) << 3) | (cc & 7);
                        f1[rl * 512 + scol] = f2b(v);
                    }
                }
        }
        __syncthreads();
        f32x4 acc2[2][2] = {};
        for (int k0 = 0; k0 < 512; k0 += 64) {
            if (k0) __syncthreads();
#pragma unroll
            for (int i = 0; i < 4; ++i) {
                int rl2 = i * 32 + wid * 8 + (lane >> 3);
                gload16(w2T + (size_t)rl2 * 512 + k0 + (((lane & 7) ^ (rl2 & 7)) << 3),
                        Wlds + (i * 32 + wid * 8) * 64);
            }
            __syncthreads();
#pragma unroll
            for (int ks = 0; ks < 2; ++ks) {
                int sw = ((ks * 4 + kq) ^ (rA & 7)) << 3;
                short8 af0 = *(const short8*)&f1[rA * 512 + k0 + sw];
                short8 af1 = *(const short8*)&f1[(16 + rA) * 512 + k0 + sw];
                short8 bf0 = *(const short8*)&Wlds[(wid * 32 + rA) * 64 + sw];
                short8 bf1 = *(const short8*)&Wlds[(wid * 32 + 16 + rA) * 64 + sw];
                acc2[0][0] = __builtin_amdgcn_mfma_f32_16x16x32_bf16(af0, bf0, acc2[0][0], 0, 0, 0);
                acc2[0][1] = __builtin_amdgcn_mfma_f32_16x16x32_bf16(af0, bf1, acc2[0][1], 0, 0, 0);
                acc2[1][0] = __builtin_amdgcn_mfma_f32_16x16x32_bf16(af1, bf0, acc2[1][0], 0, 0, 0);
                acc2[1][1] = __builtin_amdgcn_mfma_f32_16x16x32_bf16(af1, bf1, acc2[1][1], 0, 0, 0);
            }
        }
        __syncthreads();
#pragma unroll
        for (int m = 0; m < 2; ++m)
#pragma unroll
            for (int n = 0; n < 2; ++n) {
                int cc = wid * 32 + n * 16 + rA;
                float bv = b2[cc];
#pragma unroll
                for (int r = 0; r < 4; ++r) {
                    int rl = m * 16 + kq * 4 + r;
                    vbuf[rl * 133 + cc] = acc2[m][n][r] + bv;
                }
            }
        __syncthreads();
        {
            const float* vr = vbuf + row * 133 + sub * 16;
            float vv[16];
            float s = 0.f, s2 = 0.f;
#pragma unroll
            for (int j = 0; j < 16; ++j) {
                vv[j] = vr[j] + x1[j];
                s += vv[j];
                s2 += vv[j] * vv[j];
            }
            s += __shfl_xor(s, 1, 64);  s2 += __shfl_xor(s2, 1, 64);
            s += __shfl_xor(s, 2, 64);  s2 += __shfl_xor(s2, 2, 64);
            s += __shfl_xor(s, 4, 64);  s2 += __shfl_xor(s2, 4, 64);
            float mean = s * (1.f / 128.f);
            float var = s2 * (1.f / 128.f) - mean * mean;
            float rs = rsqrtf(var + 1e-5f);
            int grow = rows0 + row;
            float* xrow = a.x + (size_t)grow * 128 + sub * 16;
            u16* xbrow = a.xb + (size_t)grow * 128 + sub * 16;
#pragma unroll
            for (int j = 0; j < 4; ++j) {
                float4 gv = *(const float4*)(ln2g + sub * 16 + j * 4);
                float4 bv = *(const float4*)(ln2b + sub * 16 + j * 4);
                float o0 = (vv[j * 4 + 0] - mean) * rs * gv.x + bv.x;
                float o1 = (vv[j * 4 + 1] - mean) * rs * gv.y + bv.y;
                float o2 = (vv[j * 4 + 2] - mean) * rs * gv.z + bv.z;
                float o3 = (vv[j * 4 + 3] - mean) * rs * gv.w + bv.w;
                *(float4*)(xrow + j * 4) = make_float4(o0, o1, o2, o3);
                *(ushort4*)(xbrow + j * 4) = make_ushort4(f2b(o0), f2b(o1), f2b(o2), f2b(o3));
            }
        }
    }
}

// ===================== mega kernel =====================
__global__ __launch_bounds__(256, 2) void k_mega(MegaArgs a) {
    __shared__ __align__(16) char smem[73728];
    cg::grid_group g = cg::this_grid();
    int nG = gridDim.x;
    ph_uber(a, smem, nG);                                   g.sync();
    ph_count(a, nG);                                        g.sync();
    ph_scanA(a, smem, nG);                                  g.sync();
    ph_scanB(a, smem, nG);                                  g.sync();
    ph_fill(a, nG);                                         g.sync();
    ph_gprep1(a, nG);                                       g.sync();
    ph_mgemm<128, 1, 1, 0>(smem, a.in1b, a.gw1T, a.gnn_b1, a.h1b, nullptr,
                           NP_, 128, 64, NP_ / 128, 1, nG); g.sync();
    ph_gprep2(a, nG);                                       g.sync();
    ph_mgemm<128, 1, 0, 0>(smem, a.in2b, a.gw2T, a.gnn_b2, a.spe, nullptr,
                           NP_, 128, 128, NP_ / 128, 1, nG); g.sync();
    ph_fusion(a, smem, nG);                                 g.sync();
    for (int l = 0; l < L_; ++l) {
        ph_qkvatt(a, smem, l, nG);                          g.sync();
        ph_layer(a, smem, l, nG);                           g.sync();
    }
    ph_mgemm<64, 0, 0, 1>(smem, a.xb, a.hwT, a.head_b, a.out, a.endi,
                          B_, U_, 128, 1, UP_ / 128, nG);
}

// ===================== launch =====================
extern "C" void kernel_launch(void* const* d_in, const int* in_sizes, int n_in,
                              void* d_out, int out_size, void* d_ws, size_t ws_size,
                              hipStream_t stream) {
    const float* node_feature = (const float*)d_in[0];
    const int*   edge_index   = (const int*)d_in[1];
    const int*   traj_x       = (const int*)d_in[2];
    const float* temporal_x   = (const float*)d_in[3];
    const int*   user_id_x    = (const int*)d_in[4];
    const int*   mask         = (const int*)d_in[5];
    const int*   end_idx      = (const int*)d_in[6];
    const float* tmat         = (const float*)d_in[8];
    const float* dmat         = (const float*)d_in[9];
    const int*   highway_x    = (const int*)d_in[10];
    const float* lambda2      = (const float*)d_in[11];
    const float* gnn_w1       = (const float*)d_in[12];
    const float* gnn_b1       = (const float*)d_in[13];
    const float* gnn_w2       = (const float*)d_in[14];
    const float* gnn_b2       = (const float*)d_in[15];
    const float* ue_tab       = (const float*)d_in[16];
    const float* ce_tab       = (const float*)d_in[17];
    const float* fl_w         = (const float*)d_in[18];
    const float* fl_b         = (const float*)d_in[19];
    const float* wqkv         = (const float*)d_in[20];
    const float* bqkv         = (const float*)d_in[21];
    const float* wo           = (const float*)d_in[22];
    const float* bo           = (const float*)d_in[23];
    const float* ln1_g        = (const float*)d_in[24];
    const float* ln1_b        = (const float*)d_in[25];
    const float* ln2_g        = (const float*)d_in[26];
    const float* ln2_b        = (const float*)d_in[27];
    const float* ffn_w1       = (const float*)d_in[28];
    const float* ffn_b1       = (const float*)d_in[29];
    const float* ffn_w2       = (const float*)d_in[30];
    const float* ffn_b2       = (const float*)d_in[31];
    const float* head_w       = (const float*)d_in[32];
    const float* head_b       = (const float*)d_in[33];

    // ---- workspace layout (float units), identical to round 10 ----
    float* w     = (float*)d_ws;
    int*   cnt   = (int*)w;
    float* spe   = w + 40960;
    u16*   biasb = (u16*)(w + 5169152);
    float* wreg  = w + 7266304;
    u16* wqkvT = (u16*)wreg;
    u16* woT   = wqkvT + 4 * 384 * 128;
    u16* w1T   = woT + 4 * 128 * 128;
    u16* w2T   = w1T + 4 * 512 * 128;
    u16* gw1T  = w2T + 4 * 128 * 512;
    u16* gw2T  = gw1T + 128 * 64;
    u16* hwT   = gw2T + 128 * 128;
    float* pool  = w + 8000000;
    u16*   h1b   = (u16*)pool;
    u16*   in1b  = (u16*)(pool + 2564096);
    u16*   in2b  = (u16*)(pool + 3846144);
    int*   off   = (int*)(pool + 6410240);
    int*   cursor= (int*)(pool + 6450304);
    int*   ebuf  = (int*)(pool + 6490368);
    int*   part  = (int*)(pool + 6650368);
    float* x     = pool;
    u16*   xb    = (u16*)(pool + 2097152);
    u16*   attob = (u16*)(pool + 4718592);

    MegaArgs ma;
    const float* srcs[7] = {wqkv, wo, ffn_w1, ffn_w2, gnn_w1, gnn_w2, head_w};
    u16* dsts[7]        = {wqkvT, woT, w1T, w2T, gw1T, gw2T, hwT};
    int Ks[7]    = {128, 128, 128, 512, 32, 128, 128};
    int Npads[7] = {384, 128, 512, 128, 128, 128, UP_};
    int Nsrcs[7] = {384, 128, 512, 128, 128, 128, U_};
    int Kps[7]   = {128, 128, 128, 512, 64, 128, 128};
    int Ls[7]    = {4, 4, 4, 4, 1, 1, 1};
    int bb = UB_CNT_END;
    for (int t = 0; t < 7; ++t) {
        ma.csrc[t] = srcs[t]; ma.cdst[t] = dsts[t];
        ma.K[t] = Ks[t]; ma.Npad[t] = Npads[t]; ma.Nsrc[t] = Nsrcs[t]; ma.Kp[t] = Kps[t];
        ma.base[t] = bb;
        bb += (Npads[t] / 32) * (Kps[t] / 32) * Ls[t];
    }
    ma.tm = tmat; ma.dm = dmat; ma.maskp = mask; ma.lambda2 = lambda2;
    ma.biasb = biasb; ma.cnt = cnt;
    ma.esrc = edge_index; ma.edst = edge_index + E_;
    ma.part = part; ma.off = off; ma.cursor = cursor; ma.ebuf = ebuf;
    ma.nf = node_feature;
    ma.in1b = in1b; ma.h1b = h1b; ma.in2b = in2b; ma.spe = spe;
    ma.gnn_b1 = gnn_b1; ma.gnn_b2 = gnn_b2; ma.gw1T = gw1T; ma.gw2T = gw2T;
    ma.traj = traj_x; ma.ue_tab = ue_tab; ma.uid = user_id_x; ma.tempx = temporal_x;
    ma.hwx = highway_x; ma.ce_tab = ce_tab; ma.flw = fl_w; ma.flb = fl_b;
    ma.x = x; ma.xb = xb;
    ma.wqkvT = wqkvT; ma.bqkv = bqkv;
    ma.woT = woT; ma.bo = bo;
    ma.ln1g = ln1_g; ma.ln1b = ln1_b;
    ma.w1T = w1T; ma.fb1 = ffn_b1; ma.w2T = w2T; ma.fb2 = ffn_b2;
    ma.ln2g = ln2_g; ma.ln2b = ln2_b;
    ma.attob = attob;
    ma.hwT = hwT; ma.head_b = head_b; ma.endi = end_idx; ma.out = (float*)d_out;

    int occ = 0;
    hipOccupancyMaxActiveBlocksPerMultiprocessor(&occ, k_mega, 256, 0);
    if (occ < 1) occ = 1;
    hipDeviceProp_t prop;
    int dev = 0;
    hipGetDevice(&dev);
    hipGetDeviceProperties(&prop, dev);
    int grid = occ * prop.multiProcessorCount;
    if (grid > 512) grid = 512;
    if (grid < 64) grid = 64;

    void* kargs[] = {(void*)&ma};
    hipLaunchCooperativeKernel((void*)k_mega, dim3(grid), dim3(256), kargs, 0, stream);
}

// Round 13
// 1044.954 us; speedup vs baseline: 1.1118x; 1.1118x over previous
//
#include <hip/hip_runtime.h>
#include <hip/hip_fp16.h>
#include <hip/hip_cooperative_groups.h>
#include <cstdint>
#include <cstddef>

namespace cg = cooperative_groups;

typedef unsigned short u16;
typedef __attribute__((ext_vector_type(8))) short short8;
typedef __attribute__((ext_vector_type(4))) float f32x4;

// ---- problem constants ----
#define B_   64
#define S_   256
#define D_   128
#define H_   8
#define FF_  512
#define L_   4
#define U_   5000
#define UP_  5120
#define N_   40000
#define NP_  40064
#define E_   160000
#define FEA_ 32
#define CED_ 16
#define TD_  6
#define NSCB 157
#define UB_CNT_END 160
#define UB_CVT_END 1592
#define UB_TOTAL   5688
#define KLS 40
#define VTS 272

static __device__ __forceinline__ u16 f2b(float f) {
    unsigned int u = __float_as_uint(f);
    unsigned int r = (u + 0x7FFFu + ((u >> 16) & 1u)) >> 16;
    return (u16)r;
}
static __device__ __forceinline__ float b2f(u16 u) {
    return __uint_as_float(((unsigned int)u) << 16);
}
static __device__ __forceinline__ u16 f2h(float f) {
    return __half_as_ushort(__float2half(f));
}
static __device__ __forceinline__ float h2f(u16 u) {
    return __half2float(__ushort_as_half(u));
}
static __device__ __forceinline__ void gload16(const void* g, void* l) {
    __builtin_amdgcn_global_load_lds(
        (const __attribute__((address_space(1))) unsigned int*)g,
        (__attribute__((address_space(3))) unsigned int*)l,
        16, 0, 0);
}

struct MegaArgs {
    const float* csrc[7];
    u16* cdst[7];
    int K[7], Npad[7], Nsrc[7], Kp[7], base[7];
    const float* tm; const float* dm; const int* maskp; const float* lambda2;
    u16* biasb; int* cnt;
    const int* esrc; const int* edst;
    int* part; int* off; int* cursor; int* ebuf;
    const float* nf;
    u16* in1b; u16* h1b; u16* in2b; float* spe;
    const float* gnn_b1; const float* gnn_b2;
    const u16* gw1T; const u16* gw2T;
    const int* traj; const float* ue_tab; const int* uid; const float* tempx;
    const int* hwx; const float* ce_tab; const float* flw; const float* flb;
    float* x; u16* xb;
    const u16* wqkvT; const float* bqkv;
    const u16* woT; const float* bo;
    const float* ln1g; const float* ln1b;
    const u16* w1T; const float* fb1; const u16* w2T; const float* fb2;
    const float* ln2g; const float* ln2b;
    u16* attob;
    const u16* hwT; const float* head_b; const int* endi; float* out;
};

// ===================== phase: uber (cnt zero + 7 cvtT + attn bias) =====================
static __device__ __forceinline__ void ph_uber(const MegaArgs& a, char* smemc, int nG) {
    float (*tile)[33] = (float(*)[33])smemc;
    int tid = threadIdx.x;
    for (int bid = blockIdx.x; bid < UB_TOTAL; bid += nG) {
        __syncthreads();
        if (bid < UB_CNT_END) {
            int idx = bid * 256 + tid;
            if (idx < NP_) a.cnt[idx] = 0;
        } else if (bid < UB_CVT_END) {
            int t = 0;
#pragma unroll
            for (int i = 1; i < 7; ++i) t += (bid >= a.base[i]);
            int rb = bid - a.base[t];
            int K = a.K[t], Npad = a.Npad[t], Nsrc = a.Nsrc[t], Kp = a.Kp[t];
            int nbn = Npad >> 5, nbk = Kp >> 5;
            int per = nbn * nbk;
            int l = rb / per, rem = rb - l * per;
            int n0 = (rem % nbn) * 32, k0 = (rem / nbn) * 32;
            const float* in = a.csrc[t];
            u16* outp = a.cdst[t];
            int j = tid & 31, i2 = tid >> 5;
#pragma unroll
            for (int r = 0; r < 4; ++r) {
                int k = k0 + i2 + r * 8, n = n0 + j;
                tile[i2 + r * 8][j] = (k < K && n < Nsrc) ? in[(size_t)l * K * Nsrc + (size_t)k * Nsrc + n] : 0.f;
            }
            __syncthreads();
#pragma unroll
            for (int r = 0; r < 4; ++r) {
                int n = n0 + i2 + r * 8, k = k0 + j;
                if (n < Npad && k < Kp)
                    outp[(size_t)l * Npad * Kp + (size_t)n * Kp + k] = f2b(tile[j][i2 + r * 8]);
            }
        } else {
            int t4 = (bid - UB_CVT_END) * 256 + tid;
            if (t4 < B_ * S_ * S_ / 4) {
                float l2 = *a.lambda2, l2c = 1.f - l2;
                float4 av = ((const float4*)a.tm)[t4];
                float4 bv = ((const float4*)a.dm)[t4];
                int basei = t4 * 4;
                int bb = basei >> 16;
                int k0 = basei & 255;
                const int* mrow = a.maskp + bb * S_;
                float r0 = (mrow[k0 + 0] > 0 ? 0.f : -30000.f) - (l2 * __logf(1.f + av.x) + l2c * __logf(1.f + bv.x));
                float r1 = (mrow[k0 + 1] > 0 ? 0.f : -30000.f) - (l2 * __logf(1.f + av.y) + l2c * __logf(1.f + bv.y));
                float r2 = (mrow[k0 + 2] > 0 ? 0.f : -30000.f) - (l2 * __logf(1.f + av.z) + l2c * __logf(1.f + bv.z));
                float r3 = (mrow[k0 + 3] > 0 ? 0.f : -30000.f) - (l2 * __logf(1.f + av.w) + l2c * __logf(1.f + bv.w));
                *(ushort4*)&a.biasb[(size_t)t4 * 4] = make_ushort4(f2h(r0), f2h(r1), f2h(r2), f2h(r3));
            }
        }
    }
}

// ===================== phase: CSR =====================
static __device__ __forceinline__ void ph_count(const MegaArgs& a, int nG) {
    for (int e = blockIdx.x * 256 + threadIdx.x; e < E_; e += nG * 256)
        atomicAdd(&a.cnt[a.edst[e]], 1);
}

static __device__ __forceinline__ void ph_scanA(const MegaArgs& a, char* smemc, int nG) {
    int* sh = (int*)smemc;
    int tid = threadIdx.x;
    for (int wb = blockIdx.x; wb < NSCB; wb += nG) {
        __syncthreads();
        int idx = wb * 256 + tid;
        sh[tid] = (idx < NP_) ? a.cnt[idx] : 0;
        __syncthreads();
        for (int o = 128; o > 0; o >>= 1) {
            if (tid < o) sh[tid] += sh[tid + o];
            __syncthreads();
        }
        if (tid == 0) a.part[wb] = sh[0];
    }
}

static __device__ __forceinline__ void ph_scanB(const MegaArgs& a, char* smemc, int nG) {
    int* sh = (int*)smemc;
    int* bsum = (int*)(smemc + 1024);
    int tid = threadIdx.x;
    for (int wb = blockIdx.x; wb < NSCB; wb += nG) {
        __syncthreads();
        int pv = (tid < wb) ? a.part[tid] : 0;
        sh[tid] = pv;
        __syncthreads();
        for (int o = 128; o > 0; o >>= 1) {
            if (tid < o) sh[tid] += sh[tid + o];
            __syncthreads();
        }
        if (tid == 0) *bsum = sh[0];
        __syncthreads();
        int basev = *bsum;
        __syncthreads();
        int idx = wb * 256 + tid;
        int v = (idx < NP_) ? a.cnt[idx] : 0;
        sh[tid] = v;
        __syncthreads();
        for (int o = 1; o < 256; o <<= 1) {
            int t2 = (tid >= o) ? sh[tid - o] : 0;
            __syncthreads();
            sh[tid] += t2;
            __syncthreads();
        }
        if (idx < NP_) {
            int res = sh[tid] - v + basev;
            a.off[idx] = res;
            a.cursor[idx] = res;
        }
    }
}

static __device__ __forceinline__ void ph_fill(const MegaArgs& a, int nG) {
    for (int e = blockIdx.x * 256 + threadIdx.x; e < E_; e += nG * 256) {
        int p = atomicAdd(&a.cursor[a.edst[e]], 1);
        a.ebuf[p] = a.esrc[e];
    }
}

// ===================== phase: GNN gathers =====================
static __device__ __forceinline__ void ph_gprep1(const MegaArgs& a, int nG) {
    int tid = threadIdx.x;
    for (int wb = blockIdx.x; wb < NP_ / 8; wb += nG) {
        int n = wb * 8 + (tid >> 5);
        int f = tid & 31;
        u16 r = 0;
        if (n < N_) {
            int start = a.off[n], c = a.cnt[n];
            float acc = 0.f;
            int i = 0;
            for (; i + 4 <= c; i += 4) {
                int s0 = a.ebuf[start + i], s1 = a.ebuf[start + i + 1];
                int s2 = a.ebuf[start + i + 2], s3 = a.ebuf[start + i + 3];
                float v0 = a.nf[(size_t)s0 * FEA_ + f];
                float v1 = a.nf[(size_t)s1 * FEA_ + f];
                float v2 = a.nf[(size_t)s2 * FEA_ + f];
                float v3 = a.nf[(size_t)s3 * FEA_ + f];
                acc += (v0 + v1) + (v2 + v3);
            }
            for (; i < c; ++i) acc += a.nf[(size_t)a.ebuf[start + i] * FEA_ + f];
            r = f2b(a.nf[(size_t)n * FEA_ + f] + acc / (float)(c + 1));
        }
        a.in1b[(size_t)n * 64 + f] = r;
        a.in1b[(size_t)n * 64 + 32 + f] = 0;
    }
}

static __device__ __forceinline__ void ph_gprep2(const MegaArgs& a, int nG) {
    int tid = threadIdx.x;
    for (int wb = blockIdx.x; wb < NP_ / 4; wb += nG) {
        int n = wb * 4 + (tid >> 6);
        int d2 = (tid & 63) * 2;
        u16 r0 = 0, r1 = 0;
        if (n < N_) {
            int start = a.off[n], c = a.cnt[n];
            float a0 = 0.f, a1 = 0.f;
            int i = 0;
            for (; i + 4 <= c; i += 4) {
                int s0 = a.ebuf[start + i], s1 = a.ebuf[start + i + 1];
                int s2 = a.ebuf[start + i + 2], s3 = a.ebuf[start + i + 3];
                ushort2 v0 = *(const ushort2*)&a.h1b[(size_t)s0 * D_ + d2];
                ushort2 v1 = *(const ushort2*)&a.h1b[(size_t)s1 * D_ + d2];
                ushort2 v2 = *(const ushort2*)&a.h1b[(size_t)s2 * D_ + d2];
                ushort2 v3 = *(const ushort2*)&a.h1b[(size_t)s3 * D_ + d2];
                a0 += (b2f(v0.x) + b2f(v1.x)) + (b2f(v2.x) + b2f(v3.x));
                a1 += (b2f(v0.y) + b2f(v1.y)) + (b2f(v2.y) + b2f(v3.y));
            }
            for (; i < c; ++i) {
                ushort2 v = *(const ushort2*)&a.h1b[(size_t)a.ebuf[start + i] * D_ + d2];
                a0 += b2f(v.x); a1 += b2f(v.y);
            }
            float rinv = 1.f / (float)(c + 1);
            ushort2 sv = *(const ushort2*)&a.h1b[(size_t)n * D_ + d2];
            r0 = f2b(b2f(sv.x) + a0 * rinv);
            r1 = f2b(b2f(sv.y) + a1 * rinv);
        }
        *(ushort2*)&a.in2b[(size_t)n * D_ + d2] = make_ushort2(r0, r1);
    }
}

// ===================== phase: MFMA GEMM =====================
template<int BM, int ACT, int OUTB, int GAT>
static __device__ __forceinline__ void ph_mgemm(char* smemc, const u16* A, const u16* BT,
                                                const float* bias, void* Cout, const int* endi,
                                                int M, int N, int K, int nbx, int nby, int nG) {
    u16* Al = (u16*)smemc;
    u16* Bl = Al + (BM == 128 ? 128 * 64 : 64 * 64);
    int tid = threadIdx.x;
    int wid = tid >> 6, lane = tid & 63;
    int rA = lane & 15, kq = lane >> 4;
    for (int wb = blockIdx.x; wb < nbx * nby; wb += nG) {
        __syncthreads();
        int bx = wb % nbx, by = wb / nbx;
        int row0 = bx * BM, col0 = by * 128;
        f32x4 acc[4][4] = {};
        for (int k0 = 0; k0 < K; k0 += 64) {
            if (k0) __syncthreads();
            if (BM == 128) {
                int srow = wid * 32 + (lane >> 3);
                int ks8 = ((lane & 7) ^ (lane >> 3)) * 8;
#pragma unroll
                for (int i = 0; i < 4; ++i) {
                    int row = srow + i * 8;
                    size_t arow = (size_t)(row0 + row);
                    if (GAT) {
                        int bb2 = row0 + row;
                        arow = (bb2 < B_) ? ((size_t)bb2 * S_ + endi[bb2]) : 0;
                    }
                    gload16(A + arow * K + k0 + ks8, &Al[(wid * 32 + i * 8) * 64]);
                    gload16(BT + (size_t)(col0 + row) * K + k0 + ks8, &Bl[(wid * 32 + i * 8) * 64]);
                }
            } else {
#pragma unroll
                for (int i = 0; i < 6; ++i) {
                    int c = wid * 6 + i;
                    int rr = c * 8 + (lane >> 3);
                    int sl = (((lane & 7) ^ (rr & 7)) << 3);
                    if (c < 8) {
                        size_t arow = (size_t)(row0 + rr);
                        if (GAT) {
                            int bb2 = row0 + rr;
                            arow = (bb2 < B_) ? ((size_t)bb2 * S_ + endi[bb2]) : 0;
                        }
                        gload16(A + arow * K + k0 + sl, &Al[rr * 64]);
                    } else {
                        gload16(BT + (size_t)(col0 + rr - 64) * K + k0 + sl, &Bl[(rr - 64) * 64]);
                    }
                }
            }
            __syncthreads();
#pragma unroll
            for (int ks = 0; ks < 2; ++ks) {
                int sw = ((ks * 4 + kq) ^ (rA & 7)) * 8;
                if (BM == 128) {
                    int wr = wid >> 1, wc = wid & 1;
                    short8 af[4], bfr[4];
#pragma unroll
                    for (int m = 0; m < 4; ++m)
                        af[m] = *(const short8*)&Al[(64 * wr + m * 16 + rA) * 64 + sw];
#pragma unroll
                    for (int n = 0; n < 4; ++n)
                        bfr[n] = *(const short8*)&Bl[(64 * wc + n * 16 + rA) * 64 + sw];
#pragma unroll
                    for (int m = 0; m < 4; ++m)
#pragma unroll
                        for (int n = 0; n < 4; ++n)
                            acc[m][n] = __builtin_amdgcn_mfma_f32_16x16x32_bf16(af[m], bfr[n], acc[m][n], 0, 0, 0);
                } else {
                    int wr2 = wid & 1, wc2 = wid >> 1;
                    short8 af[2], bfr[4];
#pragma unroll
                    for (int m = 0; m < 2; ++m)
                        af[m] = *(const short8*)&Al[(wr2 * 32 + m * 16 + rA) * 64 + sw];
#pragma unroll
                    for (int n = 0; n < 4; ++n)
                        bfr[n] = *(const short8*)&Bl[(wc2 * 64 + n * 16 + rA) * 64 + sw];
#pragma unroll
                    for (int m = 0; m < 2; ++m)
#pragma unroll
                        for (int n = 0; n < 4; ++n)
                            acc[m][n] = __builtin_amdgcn_mfma_f32_16x16x32_bf16(af[m], bfr[n], acc[m][n], 0, 0, 0);
                }
            }
        }
        constexpr int MR = (BM == 128) ? 4 : 2;
#pragma unroll
        for (int m = 0; m < MR; ++m) {
#pragma unroll
            for (int n = 0; n < 4; ++n) {
                int cc, cr0;
                if (BM == 128) { cc = col0 + (wid & 1) * 64 + n * 16 + rA; cr0 = row0 + (wid >> 1) * 64 + m * 16 + kq * 4; }
                else           { cc = col0 + (wid >> 1) * 64 + n * 16 + rA; cr0 = row0 + (wid & 1) * 32 + m * 16 + kq * 4; }
                if (cc >= N) continue;
                float bv = bias[cc];
#pragma unroll
                for (int r = 0; r < 4; ++r) {
                    int cr = cr0 + r;
                    if (cr >= M) continue;
                    float v = acc[m][n][r] + bv;
                    if (ACT) v = fmaxf(v, 0.f);
                    if (OUTB) ((u16*)Cout)[(size_t)cr * N + cc] = f2b(v);
                    else      ((float*)Cout)[(size_t)cr * N + cc] = v;
                }
            }
        }
    }
}

// ===================== phase: fusion =====================
static __device__ __forceinline__ void ph_fusion(const MegaArgs& a, char* smemc, int nG) {
    float* Ws = (float*)smemc;
    float* bs = (float*)(smemc + 11264);
    float (*ins)[22] = (float(*)[22])(smemc + 11776);
    int tid = threadIdx.x;
    for (int wb = blockIdx.x; wb < (B_ * S_) / 32; wb += nG) {
        __syncthreads();
        for (int i = tid; i < 22 * D_; i += 256) Ws[i] = a.flw[i];
        if (tid < D_) bs[tid] = a.flb[tid];
        __syncthreads();
        int ro = tid >> 7, d = tid & 127;
        int base = wb * 32;
        for (int ir = 0; ir < 16; ++ir) {
            int tok = base + ir * 2 + ro;
            int b = tok >> 8, s = tok & 255;
            if (d < TD_) ins[ro][d] = a.tempx[(size_t)tok * TD_ + d];
            else if (d < 22) ins[ro][d] = a.ce_tab[(size_t)a.hwx[tok] * CED_ + (d - TD_)];
            __syncthreads();
            float acc = bs[d];
#pragma unroll
            for (int k = 0; k < 22; ++k) acc = fmaf(ins[ro][k], Ws[k * D_ + d], acc);
            acc = fmaxf(acc, 0.f);
            int i2 = d & ~1;
            float ang = (float)s * __expf(-(float)i2 * 0.0719557841560639f);
            float pe = (d & 1) ? cosf(ang) : sinf(ang);
            float v = a.spe[(size_t)a.traj[tok] * D_ + d] + a.ue_tab[(size_t)a.uid[b] * D_ + d] + acc + pe;
            a.x[(size_t)tok * D_ + d] = v;
            a.xb[(size_t)tok * D_ + d] = f2b(v);
            __syncthreads();
        }
    }
}

// ===================== phase: fused QKV-proj + attention =====================
static __device__ __forceinline__ void ph_qkvatt(const MegaArgs& a, char* smemc, int l, int nG) {
    u16* Kl  = (u16*)smemc;
    u16* Vt  = (u16*)(smemc + 20480);
    u16* Ql  = (u16*)(smemc + 29184);
    u16* Pl  = (u16*)(smemc + 37376);
    u16* Ast = (u16*)smemc;
    u16* Bst = (u16*)(smemc + 32768);
    const u16* wT = a.wqkvT + (size_t)l * 384 * 128;
    const float* bq = a.bqkv + (size_t)l * 384;
    int tid = threadIdx.x, wid = tid >> 6, lane = tid & 63;
    int rA = lane & 15, kq = lane >> 4;
    for (int wb = blockIdx.x; wb < B_ * H_; wb += nG) {
        __syncthreads();
        int b = (wb & 7) * 8 + (wb >> 6);
        int h = (wb >> 3) & 7;
        f32x4 acc[4][3] = {};
        for (int k0 = 0; k0 < 128; k0 += 64) {
            if (k0) __syncthreads();
#pragma unroll
            for (int i = 0; i < 8; ++i) {
                int row = wid * 64 + i * 8 + (lane >> 3);
                int sl = (((lane & 7) ^ (row & 7)) << 3);
                gload16(a.xb + ((size_t)(b * S_ + row)) * 128 + k0 + sl, &Ast[(wid * 64 + i * 8) * 64]);
            }
            if (wid < 3) {
#pragma unroll
                for (int i = 0; i < 2; ++i) {
                    int c = wid * 2 + i;
                    int brow = c * 8 + (lane >> 3);
                    int grow = wid * 128 + h * 16 + (brow & 15);
                    int sl = (((lane & 7) ^ (brow & 7)) << 3);
                    gload16(wT + (size_t)grow * 128 + k0 + sl, &Bst[c * 8 * 64]);
                }
            }
            __syncthreads();
#pragma unroll
            for (int ks = 0; ks < 2; ++ks) {
                int sw = ((ks * 4 + kq) ^ (rA & 7)) * 8;
                short8 af[4], bfr[3];
#pragma unroll
                for (int m = 0; m < 4; ++m)
                    af[m] = *(const short8*)&Ast[(wid * 64 + m * 16 + rA) * 64 + sw];
#pragma unroll
                for (int n = 0; n < 3; ++n)
                    bfr[n] = *(const short8*)&Bst[(n * 16 + rA) * 64 + sw];
#pragma unroll
                for (int m = 0; m < 4; ++m)
#pragma unroll
                    for (int n = 0; n < 3; ++n)
                        acc[m][n] = __builtin_amdgcn_mfma_f32_16x16x32_bf16(af[m], bfr[n], acc[m][n], 0, 0, 0);
            }
        }
        __syncthreads();
        {
            short8 z = {};
            *(short8*)&Kl[tid * KLS + 16] = z;
            *(short8*)&Kl[tid * KLS + 24] = z;
        }
        {
            float bq0 = bq[h * 16 + rA];
            float bq1 = bq[128 + h * 16 + rA];
            float bq2 = bq[256 + h * 16 + rA];
#pragma unroll
            for (int m = 0; m < 4; ++m) {
                int cr0 = wid * 64 + m * 16 + kq * 4;
#pragma unroll
                for (int r = 0; r < 4; ++r) {
                    int row = cr0 + r;
                    Ql[row * 16 + rA]  = f2b(acc[m][0][r] + bq0);
                    Kl[row * KLS + rA] = f2b(acc[m][1][r] + bq1);
                    Vt[rA * VTS + row] = f2b(acc[m][2][r] + bq2);
                }
            }
        }
        __syncthreads();
        u16* pl = Pl + wid * 16 * VTS;
        int qi = lane & 15;
        for (int qt = 0; qt < 4; ++qt) {
            int q = wid * 64 + qt * 16 + qi;
            ushort4 bb[16];
            const u16* bp = a.biasb + (size_t)b * (S_ * S_) + (size_t)q * S_ + kq * 4;
#pragma unroll
            for (int t = 0; t < 16; ++t) bb[t] = *(const ushort4*)(bp + t * 16);
            short8 qf = {};
            if (lane < 32)
                qf = *(const short8*)&Ql[q * 16 + kq * 8];
            f32x4 sc[16];
#pragma unroll
            for (int t = 0; t < 16; ++t) {
                short8 kf = *(const short8*)&Kl[(t * 16 + qi) * KLS + kq * 8];
                f32x4 zz = {0.f, 0.f, 0.f, 0.f};
                sc[t] = __builtin_amdgcn_mfma_f32_16x16x32_bf16(kf, qf, zz, 0, 0, 0);
            }
            float m = -1e30f;
#pragma unroll
            for (int t = 0; t < 16; ++t) {
                sc[t][0] = sc[t][0] * 0.25f + h2f(bb[t].x);
                sc[t][1] = sc[t][1] * 0.25f + h2f(bb[t].y);
                sc[t][2] = sc[t][2] * 0.25f + h2f(bb[t].z);
                sc[t][3] = sc[t][3] * 0.25f + h2f(bb[t].w);
                m = fmaxf(m, fmaxf(fmaxf(sc[t][0], sc[t][1]), fmaxf(sc[t][2], sc[t][3])));
            }
            m = fmaxf(m, __shfl_xor(m, 16, 64));
            m = fmaxf(m, __shfl_xor(m, 32, 64));
            float lsum = 0.f;
#pragma unroll
            for (int t = 0; t < 16; ++t) {
                sc[t][0] = __expf(sc[t][0] - m);
                sc[t][1] = __expf(sc[t][1] - m);
                sc[t][2] = __expf(sc[t][2] - m);
                sc[t][3] = __expf(sc[t][3] - m);
                lsum += (sc[t][0] + sc[t][1]) + (sc[t][2] + sc[t][3]);
            }
            lsum += __shfl_xor(lsum, 16, 64);
            lsum += __shfl_xor(lsum, 32, 64);
            float inv = 1.f / lsum;
#pragma unroll
            for (int t = 0; t < 16; ++t) {
                ushort4 pw = make_ushort4(f2b(sc[t][0] * inv), f2b(sc[t][1] * inv),
                                          f2b(sc[t][2] * inv), f2b(sc[t][3] * inv));
                *(ushort4*)&pl[qi * VTS + t * 16 + kq * 4] = pw;
            }
            f32x4 oa = {0.f, 0.f, 0.f, 0.f};
#pragma unroll
            for (int w8 = 0; w8 < 8; ++w8) {
                short8 vf = *(const short8*)&Vt[qi * VTS + w8 * 32 + kq * 8];
                short8 pf = *(const short8*)&pl[qi * VTS + w8 * 32 + kq * 8];
                oa = __builtin_amdgcn_mfma_f32_16x16x32_bf16(vf, pf, oa, 0, 0, 0);
            }
            ushort4 ow = make_ushort4(f2b(oa[0]), f2b(oa[1]), f2b(oa[2]), f2b(oa[3]));
            *(ushort4*)&a.attob[((size_t)(b * S_ + q)) * D_ + h * 16 + kq * 4] = ow;
        }
    }
}

// ===================== phase: layer tail (wo+LN1+FFN+LN2) =====================
static __device__ __forceinline__ void ph_layer(const MegaArgs& a, char* smemc, int l, int nG) {
    u16* Alds = (u16*)smemc;
    u16* Wlds = (u16*)(smemc + 8192);
    u16* f1   = (u16*)(smemc + 40960);
    float* vbuf = (float*)smemc;
    const u16* woT = a.woT + (size_t)l * 128 * 128;
    const float* bo = a.bo + (size_t)l * D_;
    const float* ln1g = a.ln1g + (size_t)l * D_;
    const float* ln1b = a.ln1b + (size_t)l * D_;
    const u16* w1T = a.w1T + (size_t)l * 512 * 128;
    const float* b1 = a.fb1 + (size_t)l * FF_;
    const u16* w2T = a.w2T + (size_t)l * 128 * 512;
    const float* b2 = a.fb2 + (size_t)l * D_;
    const float* ln2g = a.ln2g + (size_t)l * D_;
    const float* ln2b = a.ln2b + (size_t)l * D_;
    int tid = threadIdx.x, wid = tid >> 6, lane = tid & 63;
    int rA = lane & 15, kq = lane >> 4;
    int row = tid >> 3, sub = tid & 7;
    for (int wb = blockIdx.x; wb < (B_ * S_) / 32; wb += nG) {
        __syncthreads();
        int rows0 = wb * 32;
#pragma unroll
        for (int j = 0; j < 2; ++j) {
            int srow = wid * 8 + j * 4 + (lane >> 4);
            int win = (lane >> 3) & 1, slot = lane & 7;
            gload16(a.attob + (size_t)(rows0 + srow) * 128 + win * 64 + ((slot ^ (srow & 7)) << 3),
                    Alds + (wid * 8 + j * 4) * 128);
        }
        f32x4 accw[2][2] = {};
        for (int k0 = 0; k0 < 128; k0 += 64) {
            __syncthreads();
#pragma unroll
            for (int i = 0; i < 4; ++i) {
                int rl2 = i * 32 + wid * 8 + (lane >> 3);
                gload16(woT + (size_t)rl2 * 128 + k0 + (((lane & 7) ^ (rl2 & 7)) << 3),
                        Wlds + (i * 32 + wid * 8) * 64);
            }
            __syncthreads();
#pragma unroll
            for (int ks = 0; ks < 2; ++ks) {
                int sw = ((ks * 4 + kq) ^ (rA & 7)) << 3;
                short8 af0 = *(const short8*)&Alds[rA * 128 + k0 + sw];
                short8 af1 = *(const short8*)&Alds[(16 + rA) * 128 + k0 + sw];
                short8 bf0 = *(const short8*)&Wlds[(wid * 32 + rA) * 64 + sw];
                short8 bf1 = *(const short8*)&Wlds[(wid * 32 + 16 + rA) * 64 + sw];
                accw[0][0] = __builtin_amdgcn_mfma_f32_16x16x32_bf16(af0, bf0, accw[0][0], 0, 0, 0);
                accw[0][1] = __builtin_amdgcn_mfma_f32_16x16x32_bf16(af0, bf1, accw[0][1], 0, 0, 0);
                accw[1][0] = __builtin_amdgcn_mfma_f32_16x16x32_bf16(af1, bf0, accw[1][0], 0, 0, 0);
                accw[1][1] = __builtin_amdgcn_mfma_f32_16x16x32_bf16(af1, bf1, accw[1][1], 0, 0, 0);
            }
        }
        __syncthreads();
#pragma unroll
        for (int m = 0; m < 2; ++m)
#pragma unroll
            for (int n = 0; n < 2; ++n) {
                int cc = wid * 32 + n * 16 + rA;
                float bv = bo[cc];
#pragma unroll
                for (int r = 0; r < 4; ++r) {
                    int rl = m * 16 + kq * 4 + r;
                    vbuf[rl * 133 + cc] = accw[m][n][r] + bv + a.x[(size_t)(rows0 + rl) * 128 + cc];
                }
            }
        __syncthreads();
        float x1[16];
        {
            const float* vr = vbuf + row * 133 + sub * 16;
            float s = 0.f, s2 = 0.f;
#pragma unroll
            for (int j = 0; j < 16; ++j) {
                x1[j] = vr[j];
                s += x1[j];
                s2 += x1[j] * x1[j];
            }
            s += __shfl_xor(s, 1, 64);  s2 += __shfl_xor(s2, 1, 64);
            s += __shfl_xor(s, 2, 64);  s2 += __shfl_xor(s2, 2, 64);
            s += __shfl_xor(s, 4, 64);  s2 += __shfl_xor(s2, 4, 64);
            float mean = s * (1.f / 128.f);
            float var = s2 * (1.f / 128.f) - mean * mean;
            float rs = rsqrtf(var + 1e-5f);
#pragma unroll
            for (int j = 0; j < 4; ++j) {
                float4 gv = *(const float4*)(ln1g + sub * 16 + j * 4);
                float4 bv = *(const float4*)(ln1b + sub * 16 + j * 4);
                x1[j * 4 + 0] = (x1[j * 4 + 0] - mean) * rs * gv.x + bv.x;
                x1[j * 4 + 1] = (x1[j * 4 + 1] - mean) * rs * gv.y + bv.y;
                x1[j * 4 + 2] = (x1[j * 4 + 2] - mean) * rs * gv.z + bv.z;
                x1[j * 4 + 3] = (x1[j * 4 + 3] - mean) * rs * gv.w + bv.w;
            }
        }
        __syncthreads();
#pragma unroll
        for (int j = 0; j < 16; ++j) {
            int c = sub * 16 + j;
            int scol = (c & ~63) | ((((c >> 3) & 7) ^ (row & 7)) << 3) | (c & 7);
            Alds[row * 128 + scol] = f2b(x1[j]);
        }
        for (int nh = 0; nh < 2; ++nh) {
            f32x4 acc1[2][4] = {};
            for (int k0 = 0; k0 < 128; k0 += 64) {
                __syncthreads();
#pragma unroll
                for (int i = 0; i < 8; ++i) {
                    int rl2 = i * 32 + wid * 8 + (lane >> 3);
                    gload16(w1T + (size_t)(nh * 256 + rl2) * 128 + k0 + (((lane & 7) ^ (rl2 & 7)) << 3),
                            Wlds + (i * 32 + wid * 8) * 64);
                }
                __syncthreads();
#pragma unroll
                for (int ks = 0; ks < 2; ++ks) {
                    int sw = ((ks * 4 + kq) ^ (rA & 7)) << 3;
                    short8 af[2], bf4[4];
                    af[0] = *(const short8*)&Alds[rA * 128 + k0 + sw];
                    af[1] = *(const short8*)&Alds[(16 + rA) * 128 + k0 + sw];
#pragma unroll
                    for (int n = 0; n < 4; ++n)
                        bf4[n] = *(const short8*)&Wlds[(wid * 64 + n * 16 + rA) * 64 + sw];
#pragma unroll
                    for (int m = 0; m < 2; ++m)
#pragma unroll
                        for (int n = 0; n < 4; ++n)
                            acc1[m][n] = __builtin_amdgcn_mfma_f32_16x16x32_bf16(af[m], bf4[n], acc1[m][n], 0, 0, 0);
                }
            }
#pragma unroll
            for (int m = 0; m < 2; ++m)
#pragma unroll
                for (int n = 0; n < 4; ++n) {
                    int cc = nh * 256 + wid * 64 + n * 16 + rA;
                    float bv = b1[cc];
#pragma unroll
                    for (int r = 0; r < 4; ++r) {
                        int rl = m * 16 + kq * 4 + r;
                        float v = fmaxf(acc1[m][n][r] + bv, 0.f);
                        int scol = (cc & ~63) | (((((cc >> 3) & 7) ^ (rl & 7)) & 7) << 3) | (cc & 7);
                        f1[rl * 512 + scol] = f2b(v);
                    }
                }
        }
        __syncthreads();
        f32x4 acc2[2][2] = {};
        for (int k0 = 0; k0 < 512; k0 += 64) {
            if (k0) __syncthreads();
#pragma unroll
            for (int i = 0; i < 4; ++i) {
                int rl2 = i * 32 + wid * 8 + (lane >> 3);
                gload16(w2T + (size_t)rl2 * 512 + k0 + (((lane & 7) ^ (rl2 & 7)) << 3),
                        Wlds + (i * 32 + wid * 8) * 64);
            }
            __syncthreads();
#pragma unroll
            for (int ks = 0; ks < 2; ++ks) {
                int sw = ((ks * 4 + kq) ^ (rA & 7)) << 3;
                short8 af0 = *(const short8*)&f1[rA * 512 + k0 + sw];
                short8 af1 = *(const short8*)&f1[(16 + rA) * 512 + k0 + sw];
                short8 bf0 = *(const short8*)&Wlds[(wid * 32 + rA) * 64 + sw];
                short8 bf1 = *(const short8*)&Wlds[(wid * 32 + 16 + rA) * 64 + sw];
                acc2[0][0] = __builtin_amdgcn_mfma_f32_16x16x32_bf16(af0, bf0, acc2[0][0], 0, 0, 0);
                acc2[0][1] = __builtin_amdgcn_mfma_f32_16x16x32_bf16(af0, bf1, acc2[0][1], 0, 0, 0);
                acc2[1][0] = __builtin_amdgcn_mfma_f32_16x16x32_bf16(af1, bf0, acc2[1][0], 0, 0, 0);
                acc2[1][1] = __builtin_amdgcn_mfma_f32_16x16x32_bf16(af1, bf1, acc2[1][1], 0, 0, 0);
            }
        }
        __syncthreads();
#pragma unroll
        for (int m = 0; m < 2; ++m)
#pragma unroll
            for (int n = 0; n < 2; ++n) {
                int cc = wid * 32 + n * 16 + rA;
                float bv = b2[cc];
#pragma unroll
                for (int r = 0; r < 4; ++r) {
                    int rl = m * 16 + kq * 4 + r;
                    vbuf[rl * 133 + cc] = acc2[m][n][r] + bv;
                }
            }
        __syncthreads();
        {
            const float* vr = vbuf + row * 133 + sub * 16;
            float vv[16];
            float s = 0.f, s2 = 0.f;
#pragma unroll
            for (int j = 0; j < 16; ++j) {
                vv[j] = vr[j] + x1[j];
                s += vv[j];
                s2 += vv[j] * vv[j];
            }
            s += __shfl_xor(s, 1, 64);  s2 += __shfl_xor(s2, 1, 64);
            s += __shfl_xor(s, 2, 64);  s2 += __shfl_xor(s2, 2, 64);
            s += __shfl_xor(s, 4, 64);  s2 += __shfl_xor(s2, 4, 64);
            float mean = s * (1.f / 128.f);
            float var = s2 * (1.f / 128.f) - mean * mean;
            float rs = rsqrtf(var + 1e-5f);
            int grow = rows0 + row;
            float* xrow = a.x + (size_t)grow * 128 + sub * 16;
            u16* xbrow = a.xb + (size_t)grow * 128 + sub * 16;
#pragma unroll
            for (int j = 0; j < 4; ++j) {
                float4 gv = *(const float4*)(ln2g + sub * 16 + j * 4);
                float4 bv = *(const float4*)(ln2b + sub * 16 + j * 4);
                float o0 = (vv[j * 4 + 0] - mean) * rs * gv.x + bv.x;
                float o1 = (vv[j * 4 + 1] - mean) * rs * gv.y + bv.y;
                float o2 = (vv[j * 4 + 2] - mean) * rs * gv.z + bv.z;
                float o3 = (vv[j * 4 + 3] - mean) * rs * gv.w + bv.w;
                *(float4*)(xrow + j * 4) = make_float4(o0, o1, o2, o3);
                *(ushort4*)(xbrow + j * 4) = make_ushort4(f2b(o0), f2b(o1), f2b(o2), f2b(o3));
            }
        }
    }
}

// ===================== mega kernel (cooperative) =====================
// (256,1): allows up to 512 VGPRs -> no scratch spill (round 11's (256,2)
// clamped to 128 VGPRs and spilled ~730MB). Grid sized by occupancy query,
// launch error-checked with a multi-kernel fallback.
__global__ __launch_bounds__(256, 1) void k_mega(MegaArgs a) {
    __shared__ __align__(16) char smem[73728];
    cg::grid_group g = cg::this_grid();
    int nG = gridDim.x;
    ph_uber(a, smem, nG);                                   g.sync();
    ph_count(a, nG);                                        g.sync();
    ph_scanA(a, smem, nG);                                  g.sync();
    ph_scanB(a, smem, nG);                                  g.sync();
    ph_fill(a, nG);                                         g.sync();
    ph_gprep1(a, nG);                                       g.sync();
    ph_mgemm<128, 1, 1, 0>(smem, a.in1b, a.gw1T, a.gnn_b1, a.h1b, nullptr,
                           NP_, 128, 64, NP_ / 128, 1, nG); g.sync();
    ph_gprep2(a, nG);                                       g.sync();
    ph_mgemm<128, 1, 0, 0>(smem, a.in2b, a.gw2T, a.gnn_b2, a.spe, nullptr,
                           NP_, 128, 128, NP_ / 128, 1, nG); g.sync();
    ph_fusion(a, smem, nG);                                 g.sync();
    for (int l = 0; l < L_; ++l) {
        ph_qkvatt(a, smem, l, nG);                          g.sync();
        ph_layer(a, smem, l, nG);                           g.sync();
    }
    ph_mgemm<64, 0, 0, 1>(smem, a.xb, a.hwT, a.head_b, a.out, a.endi,
                          B_, U_, 128, 1, UP_ / 128, nG);
}

// ===================== fallback wrappers (round-10-style multi-kernel) =====================
__global__ __launch_bounds__(256) void kw_uber(MegaArgs a) {
    __shared__ __align__(16) char s[4352];
    ph_uber(a, s, gridDim.x);
}
__global__ __launch_bounds__(256) void kw_count(MegaArgs a) { ph_count(a, gridDim.x); }
__global__ __launch_bounds__(256) void kw_scanA(MegaArgs a) {
    __shared__ __align__(16) char s[1024];
    ph_scanA(a, s, gridDim.x);
}
__global__ __launch_bounds__(256) void kw_scanB(MegaArgs a) {
    __shared__ __align__(16) char s[1056];
    ph_scanB(a, s, gridDim.x);
}
__global__ __launch_bounds__(256) void kw_fill(MegaArgs a) { ph_fill(a, gridDim.x); }
__global__ __launch_bounds__(256) void kw_gprep1(MegaArgs a) { ph_gprep1(a, gridDim.x); }
__global__ __launch_bounds__(256) void kw_gprep2(MegaArgs a) { ph_gprep2(a, gridDim.x); }
__global__ __launch_bounds__(256) void kw_gemm1(MegaArgs a) {
    __shared__ __align__(16) char s[32768];
    ph_mgemm<128, 1, 1, 0>(s, a.in1b, a.gw1T, a.gnn_b1, a.h1b, nullptr, NP_, 128, 64, NP_ / 128, 1, gridDim.x);
}
__global__ __launch_bounds__(256) void kw_gemm2(MegaArgs a) {
    __shared__ __align__(16) char s[32768];
    ph_mgemm<128, 1, 0, 0>(s, a.in2b, a.gw2T, a.gnn_b2, a.spe, nullptr, NP_, 128, 128, NP_ / 128, 1, gridDim.x);
}
__global__ __launch_bounds__(256) void kw_fusion(MegaArgs a) {
    __shared__ __align__(16) char s[12032];
    ph_fusion(a, s, gridDim.x);
}
__global__ __launch_bounds__(256) void kw_qkvatt(MegaArgs a, int l) {
    __shared__ __align__(16) char s[73728];
    ph_qkvatt(a, s, l, gridDim.x);
}
__global__ __launch_bounds__(256) void kw_layer(MegaArgs a, int l) {
    __shared__ __align__(16) char s[73728];
    ph_layer(a, s, l, gridDim.x);
}
__global__ __launch_bounds__(256) void kw_head(MegaArgs a) {
    __shared__ __align__(16) char s[24576];
    ph_mgemm<64, 0, 0, 1>(s, a.xb, a.hwT, a.head_b, a.out, a.endi, B_, U_, 128, 1, UP_ / 128, gridDim.x);
}

// ===================== launch =====================
extern "C" void kernel_launch(void* const* d_in, const int* in_sizes, int n_in,
                              void* d_out, int out_size, void* d_ws, size_t ws_size,
                              hipStream_t stream) {
    const float* node_feature = (const float*)d_in[0];
    const int*   edge_index   = (const int*)d_in[1];
    const int*   traj_x       = (const int*)d_in[2];
    const float* temporal_x   = (const float*)d_in[3];
    const int*   user_id_x    = (const int*)d_in[4];
    const int*   mask         = (const int*)d_in[5];
    const int*   end_idx      = (const int*)d_in[6];
    const float* tmat         = (const float*)d_in[8];
    const float* dmat         = (const float*)d_in[9];
    const int*   highway_x    = (const int*)d_in[10];
    const float* lambda2      = (const float*)d_in[11];
    const float* gnn_w1       = (const float*)d_in[12];
    const float* gnn_b1       = (const float*)d_in[13];
    const float* gnn_w2       = (const float*)d_in[14];
    const float* gnn_b2       = (const float*)d_in[15];
    const float* ue_tab       = (const float*)d_in[16];
    const float* ce_tab       = (const float*)d_in[17];
    const float* fl_w         = (const float*)d_in[18];
    const float* fl_b         = (const float*)d_in[19];
    const float* wqkv         = (const float*)d_in[20];
    const float* bqkv         = (const float*)d_in[21];
    const float* wo           = (const float*)d_in[22];
    const float* bo           = (const float*)d_in[23];
    const float* ln1_g        = (const float*)d_in[24];
    const float* ln1_b        = (const float*)d_in[25];
    const float* ln2_g        = (const float*)d_in[26];
    const float* ln2_b        = (const float*)d_in[27];
    const float* ffn_w1       = (const float*)d_in[28];
    const float* ffn_b1       = (const float*)d_in[29];
    const float* ffn_w2       = (const float*)d_in[30];
    const float* ffn_b2       = (const float*)d_in[31];
    const float* head_w       = (const float*)d_in[32];
    const float* head_b       = (const float*)d_in[33];

    // ---- workspace layout (float units), identical to round 10 ----
    float* w     = (float*)d_ws;
    int*   cnt   = (int*)w;
    float* spe   = w + 40960;
    u16*   biasb = (u16*)(w + 5169152);
    float* wreg  = w + 7266304;
    u16* wqkvT = (u16*)wreg;
    u16* woT   = wqkvT + 4 * 384 * 128;
    u16* w1T   = woT + 4 * 128 * 128;
    u16* w2T   = w1T + 4 * 512 * 128;
    u16* gw1T  = w2T + 4 * 128 * 512;
    u16* gw2T  = gw1T + 128 * 64;
    u16* hwT   = gw2T + 128 * 128;
    float* pool  = w + 8000000;
    u16*   h1b   = (u16*)pool;
    u16*   in1b  = (u16*)(pool + 2564096);
    u16*   in2b  = (u16*)(pool + 3846144);
    int*   off   = (int*)(pool + 6410240);
    int*   cursor= (int*)(pool + 6450304);
    int*   ebuf  = (int*)(pool + 6490368);
    int*   part  = (int*)(pool + 6650368);
    float* x     = pool;
    u16*   xb    = (u16*)(pool + 2097152);
    u16*   attob = (u16*)(pool + 4718592);

    MegaArgs ma;
    const float* srcs[7] = {wqkv, wo, ffn_w1, ffn_w2, gnn_w1, gnn_w2, head_w};
    u16* dsts[7]        = {wqkvT, woT, w1T, w2T, gw1T, gw2T, hwT};
    int Ks[7]    = {128, 128, 128, 512, 32, 128, 128};
    int Npads[7] = {384, 128, 512, 128, 128, 128, UP_};
    int Nsrcs[7] = {384, 128, 512, 128, 128, 128, U_};
    int Kps[7]   = {128, 128, 128, 512, 64, 128, 128};
    int Ls[7]    = {4, 4, 4, 4, 1, 1, 1};
    int bb = UB_CNT_END;
    for (int t = 0; t < 7; ++t) {
        ma.csrc[t] = srcs[t]; ma.cdst[t] = dsts[t];
        ma.K[t] = Ks[t]; ma.Npad[t] = Npads[t]; ma.Nsrc[t] = Nsrcs[t]; ma.Kp[t] = Kps[t];
        ma.base[t] = bb;
        bb += (Npads[t] / 32) * (Kps[t] / 32) * Ls[t];
    }
    ma.tm = tmat; ma.dm = dmat; ma.maskp = mask; ma.lambda2 = lambda2;
    ma.biasb = biasb; ma.cnt = cnt;
    ma.esrc = edge_index; ma.edst = edge_index + E_;
    ma.part = part; ma.off = off; ma.cursor = cursor; ma.ebuf = ebuf;
    ma.nf = node_feature;
    ma.in1b = in1b; ma.h1b = h1b; ma.in2b = in2b; ma.spe = spe;
    ma.gnn_b1 = gnn_b1; ma.gnn_b2 = gnn_b2; ma.gw1T = gw1T; ma.gw2T = gw2T;
    ma.traj = traj_x; ma.ue_tab = ue_tab; ma.uid = user_id_x; ma.tempx = temporal_x;
    ma.hwx = highway_x; ma.ce_tab = ce_tab; ma.flw = fl_w; ma.flb = fl_b;
    ma.x = x; ma.xb = xb;
    ma.wqkvT = wqkvT; ma.bqkv = bqkv;
    ma.woT = woT; ma.bo = bo;
    ma.ln1g = ln1_g; ma.ln1b = ln1_b;
    ma.w1T = w1T; ma.fb1 = ffn_b1; ma.w2T = w2T; ma.fb2 = ffn_b2;
    ma.ln2g = ln2_g; ma.ln2b = ln2_b;
    ma.attob = attob;
    ma.hwT = hwT; ma.head_b = head_b; ma.endi = end_idx; ma.out = (float*)d_out;

    int occ = 0;
    hipError_t oe = hipOccupancyMaxActiveBlocksPerMultiprocessor(&occ, k_mega, 256, 0);
    if (oe != hipSuccess || occ < 1) occ = 1;
    int grid = occ * 256;     // 256 CUs on MI355X
    if (grid > 512) grid = 512;
    if (grid < 256) grid = 256;

    void* kargs[] = {(void*)&ma};
    hipError_t err = hipLaunchCooperativeKernel((void*)k_mega, dim3(grid), dim3(256), kargs, 0, stream);
    if (err != hipSuccess && grid != 256) {
        err = hipLaunchCooperativeKernel((void*)k_mega, dim3(256), dim3(256), kargs, 0, stream);
    }
    if (err != hipSuccess) {
        // fallback: proven round-10-style multi-kernel schedule
        kw_uber<<<UB_TOTAL, 256, 0, stream>>>(ma);
        kw_count<<<(E_ + 255) / 256, 256, 0, stream>>>(ma);
        kw_scanA<<<NSCB, 256, 0, stream>>>(ma);
        kw_scanB<<<NSCB, 256, 0, stream>>>(ma);
        kw_fill<<<(E_ + 255) / 256, 256, 0, stream>>>(ma);
        kw_gprep1<<<NP_ / 8, 256, 0, stream>>>(ma);
        kw_gemm1<<<NP_ / 128, 256, 0, stream>>>(ma);
        kw_gprep2<<<NP_ / 4, 256, 0, stream>>>(ma);
        kw_gemm2<<<NP_ / 128, 256, 0, stream>>>(ma);
        kw_fusion<<<(B_ * S_) / 32, 256, 0, stream>>>(ma);
        for (int l = 0; l < L_; ++l) {
            kw_qkvatt<<<B_ * H_, 256, 0, stream>>>(ma, l);
            kw_layer<<<(B_ * S_) / 32, 256, 0, stream>>>(ma, l);
        }
        kw_head<<<UP_ / 128, 256, 0, stream>>>(ma);
    }
}

// Round 14
// 350.692 us; speedup vs baseline: 3.3128x; 2.9797x over previous
//
#include <hip/hip_runtime.h>
#include <hip/hip_fp16.h>
#include <cstdint>
#include <cstddef>

typedef unsigned short u16;
typedef __attribute__((ext_vector_type(8))) short short8;
typedef __attribute__((ext_vector_type(4))) float f32x4;

// ---- problem constants ----
#define B_   64
#define S_   256
#define D_   128
#define H_   8
#define FF_  512
#define L_   4
#define U_   5000
#define UP_  5120
#define N_   40000
#define NP_  40064
#define E_   160000
#define FEA_ 32
#define CED_ 16
#define TD_  6
#define NSCB 157
#define UB_CNT_END 160
#define UB_CVT_END 1592
#define UB_TOTAL   5688
#define KLS 40
#define VTS 272

static __device__ __forceinline__ u16 f2b(float f) {
    unsigned int u = __float_as_uint(f);
    unsigned int r = (u + 0x7FFFu + ((u >> 16) & 1u)) >> 16;
    return (u16)r;
}
static __device__ __forceinline__ float b2f(u16 u) {
    return __uint_as_float(((unsigned int)u) << 16);
}
static __device__ __forceinline__ u16 f2h(float f) {
    return __half_as_ushort(__float2half(f));
}
static __device__ __forceinline__ float h2f(u16 u) {
    return __half2float(__ushort_as_half(u));
}
static __device__ __forceinline__ void gload16(const void* g, void* l) {
    __builtin_amdgcn_global_load_lds(
        (const __attribute__((address_space(1))) unsigned int*)g,
        (__attribute__((address_space(3))) unsigned int*)l,
        16, 0, 0);
}

// ===================== uber prep: cnt-zero + 7 weight transposes + attn bias =====================
struct UberArgs {
    const float* csrc[7];
    u16* cdst[7];
    int K[7], Npad[7], Nsrc[7], Kp[7], base[7];
    const float* tm; const float* dm; const int* maskp; const float* lambda2;
    u16* bias; int* cnt;
};

__global__ __launch_bounds__(256) void k_uber(UberArgs a) {
    __shared__ float tile[32][33];
    int bid = blockIdx.x, tid = threadIdx.x;
    if (bid < UB_CNT_END) {
        int idx = bid * 256 + tid;
        if (idx < NP_) a.cnt[idx] = 0;
        return;
    }
    if (bid < UB_CVT_END) {
        int t = 0;
#pragma unroll
        for (int i = 1; i < 7; ++i) t += (bid >= a.base[i]);
        int rb = bid - a.base[t];
        int K = a.K[t], Npad = a.Npad[t], Nsrc = a.Nsrc[t], Kp = a.Kp[t];
        int nbn = Npad >> 5, nbk = Kp >> 5;
        int per = nbn * nbk;
        int l = rb / per, rem = rb - l * per;
        int n0 = (rem % nbn) * 32, k0 = (rem / nbn) * 32;
        const float* in = a.csrc[t];
        u16* outp = a.cdst[t];
        int j = tid & 31, i2 = tid >> 5;
#pragma unroll
        for (int r = 0; r < 4; ++r) {
            int k = k0 + i2 + r * 8, n = n0 + j;
            tile[i2 + r * 8][j] = (k < K && n < Nsrc) ? in[(size_t)l * K * Nsrc + (size_t)k * Nsrc + n] : 0.f;
        }
        __syncthreads();
#pragma unroll
        for (int r = 0; r < 4; ++r) {
            int n = n0 + i2 + r * 8, k = k0 + j;
            if (n < Npad && k < Kp)
                outp[(size_t)l * Npad * Kp + (size_t)n * Kp + k] = f2b(tile[j][i2 + r * 8]);
        }
        return;
    }
    int t4 = (bid - UB_CVT_END) * 256 + tid;
    const int total = B_ * S_ * S_ / 4;
    if (t4 >= total) return;
    float l2 = *a.lambda2, l2c = 1.f - l2;
    float4 av = ((const float4*)a.tm)[t4];
    float4 bv = ((const float4*)a.dm)[t4];
    int basei = t4 * 4;
    int bb = basei >> 16;
    int k0 = basei & 255;
    const int* mrow = a.maskp + bb * S_;
    float r0 = (mrow[k0 + 0] > 0 ? 0.f : -30000.f) - (l2 * __logf(1.f + av.x) + l2c * __logf(1.f + bv.x));
    float r1 = (mrow[k0 + 1] > 0 ? 0.f : -30000.f) - (l2 * __logf(1.f + av.y) + l2c * __logf(1.f + bv.y));
    float r2 = (mrow[k0 + 2] > 0 ? 0.f : -30000.f) - (l2 * __logf(1.f + av.z) + l2c * __logf(1.f + bv.z));
    float r3 = (mrow[k0 + 3] > 0 ? 0.f : -30000.f) - (l2 * __logf(1.f + av.w) + l2c * __logf(1.f + bv.w));
    *(ushort4*)&a.bias[(size_t)t4 * 4] = make_ushort4(f2h(r0), f2h(r1), f2h(r2), f2h(r3));
}

// ===================== CSR build =====================
__global__ __launch_bounds__(256) void k_count(const int* __restrict__ dst, int* __restrict__ cnt) {
    int e = blockIdx.x * 256 + threadIdx.x;
    if (e < E_) atomicAdd(&cnt[dst[e]], 1);
}

__global__ __launch_bounds__(256) void k_scanA(const int* __restrict__ cnt, int* __restrict__ part) {
    __shared__ int sh[256];
    int idx = blockIdx.x * 256 + threadIdx.x;
    sh[threadIdx.x] = (idx < NP_) ? cnt[idx] : 0;
    __syncthreads();
    for (int o = 128; o > 0; o >>= 1) {
        if (threadIdx.x < o) sh[threadIdx.x] += sh[threadIdx.x + o];
        __syncthreads();
    }
    if (threadIdx.x == 0) part[blockIdx.x] = sh[0];
}

__global__ __launch_bounds__(256) void k_scanB(const int* __restrict__ cnt, const int* __restrict__ part,
                                               int* __restrict__ off, int* __restrict__ cursor) {
    __shared__ int sh[256];
    __shared__ int bsum;
    int tid = threadIdx.x;
    int pv = (tid < blockIdx.x) ? part[tid] : 0;
    sh[tid] = pv;
    __syncthreads();
    for (int o = 128; o > 0; o >>= 1) {
        if (tid < o) sh[tid] += sh[tid + o];
        __syncthreads();
    }
    if (tid == 0) bsum = sh[0];
    __syncthreads();
    int basev = bsum;
    __syncthreads();
    int idx = blockIdx.x * 256 + tid;
    int v = (idx < NP_) ? cnt[idx] : 0;
    sh[tid] = v;
    __syncthreads();
    for (int o = 1; o < 256; o <<= 1) {
        int t2 = (tid >= o) ? sh[tid - o] : 0;
        __syncthreads();
        sh[tid] += t2;
        __syncthreads();
    }
    if (idx < NP_) {
        int res = sh[tid] - v + basev;
        off[idx] = res;
        cursor[idx] = res;
    }
}

__global__ __launch_bounds__(256) void k_fill(const int* __restrict__ src, const int* __restrict__ dst,
                                              int* __restrict__ cursor, int* __restrict__ ebuf) {
    int e = blockIdx.x * 256 + threadIdx.x;
    if (e >= E_) return;
    int p = atomicAdd(&cursor[dst[e]], 1);
    ebuf[p] = src[e];
}

// ===================== fused GNN layer 1: gather+prep -> MFMA GEMM (K=64) =====================
// h1b[rows0+128][128] = relu(bf16(nf + agg/(cnt+1)) @ gw1T^T + b1), A built in LDS
__global__ __launch_bounds__(256) void k_ggemm1(const float* __restrict__ nf, const int* __restrict__ off,
                                                const int* __restrict__ cnt, const int* __restrict__ ebuf,
                                                const u16* __restrict__ gw1T, const float* __restrict__ b1,
                                                u16* __restrict__ h1b) {
    __shared__ u16 Al[128 * 64];
    __shared__ u16 Bl[128 * 64];
    int tid = threadIdx.x, wid = tid >> 6, lane = tid & 63;
    int rows0 = blockIdx.x * 128;
    // stage B (weights) early
#pragma unroll
    for (int i = 0; i < 4; ++i) {
        int rr = wid * 32 + i * 8 + (lane >> 3);
        gload16(gw1T + (size_t)rr * 64 + (((lane & 7) ^ (rr & 7)) << 3), &Bl[(wid * 32 + i * 8) * 64]);
    }
    // gather A into swizzled LDS
    int f = tid & 31;
    int c = f >> 3, fo = f & 7;
    for (int it = 0; it < 16; ++it) {
        int rl = it * 8 + (tid >> 5);
        int n = rows0 + rl;
        u16 r = 0;
        if (n < N_) {
            int start = off[n], cdeg = cnt[n];
            float acc = 0.f;
            int i = 0;
            for (; i + 4 <= cdeg; i += 4) {
                int s0 = ebuf[start + i], s1 = ebuf[start + i + 1];
                int s2 = ebuf[start + i + 2], s3 = ebuf[start + i + 3];
                float v0 = nf[(size_t)s0 * FEA_ + f];
                float v1 = nf[(size_t)s1 * FEA_ + f];
                float v2 = nf[(size_t)s2 * FEA_ + f];
                float v3 = nf[(size_t)s3 * FEA_ + f];
                acc += (v0 + v1) + (v2 + v3);
            }
            for (; i < cdeg; ++i) acc += nf[(size_t)ebuf[start + i] * FEA_ + f];
            r = f2b(nf[(size_t)n * FEA_ + f] + acc / (float)(cdeg + 1));
        }
        Al[rl * 64 + ((c ^ (rl & 7)) << 3) + fo] = r;
        Al[rl * 64 + (((c + 4) ^ (rl & 7)) << 3) + fo] = 0;
    }
    __syncthreads();
    int rA = lane & 15, kq = lane >> 4;
    int wr = wid >> 1, wc = wid & 1;
    f32x4 acc[4][4] = {};
#pragma unroll
    for (int ks = 0; ks < 2; ++ks) {
        int sw = ((ks * 4 + kq) ^ (rA & 7)) * 8;
        short8 af[4], bfr[4];
#pragma unroll
        for (int m = 0; m < 4; ++m)
            af[m] = *(const short8*)&Al[(64 * wr + m * 16 + rA) * 64 + sw];
#pragma unroll
        for (int n = 0; n < 4; ++n)
            bfr[n] = *(const short8*)&Bl[(64 * wc + n * 16 + rA) * 64 + sw];
#pragma unroll
        for (int m = 0; m < 4; ++m)
#pragma unroll
            for (int n = 0; n < 4; ++n)
                acc[m][n] = __builtin_amdgcn_mfma_f32_16x16x32_bf16(af[m], bfr[n], acc[m][n], 0, 0, 0);
    }
#pragma unroll
    for (int m = 0; m < 4; ++m)
#pragma unroll
        for (int n = 0; n < 4; ++n) {
            int cc = (wid & 1) * 64 + n * 16 + rA;
            float bv = b1[cc];
#pragma unroll
            for (int r = 0; r < 4; ++r) {
                int cr = rows0 + (wid >> 1) * 64 + m * 16 + kq * 4 + r;
                h1b[(size_t)cr * 128 + cc] = f2b(fmaxf(acc[m][n][r] + bv, 0.f));
            }
        }
}

// ===================== fused GNN layer 2: gather+prep -> MFMA GEMM (K=128) =====================
// spe[rows0+128][128] = relu(bf16(h1b + agg/(cnt+1)) @ gw2T^T + b2)
__global__ __launch_bounds__(256) void k_ggemm2(const u16* __restrict__ h1b, const int* __restrict__ off,
                                                const int* __restrict__ cnt, const int* __restrict__ ebuf,
                                                const u16* __restrict__ gw2T, const float* __restrict__ b2,
                                                float* __restrict__ spe) {
    __shared__ u16 Al[128 * 128];   // 32KB
    __shared__ u16 Bl[128 * 64];    // 16KB
    int tid = threadIdx.x, wid = tid >> 6, lane = tid & 63;
    int rows0 = blockIdx.x * 128;
    int d2 = (tid & 63) * 2;
    int w = d2 >> 6, cch = (d2 >> 3) & 7, fo = d2 & 7;
    for (int it = 0; it < 32; ++it) {
        int rl = it * 4 + (tid >> 6);
        int n = rows0 + rl;
        u16 r0 = 0, r1 = 0;
        if (n < N_) {
            int start = off[n], cdeg = cnt[n];
            float a0 = 0.f, a1 = 0.f;
            int i = 0;
            for (; i + 4 <= cdeg; i += 4) {
                int s0 = ebuf[start + i], s1 = ebuf[start + i + 1];
                int s2 = ebuf[start + i + 2], s3 = ebuf[start + i + 3];
                ushort2 v0 = *(const ushort2*)&h1b[(size_t)s0 * D_ + d2];
                ushort2 v1 = *(const ushort2*)&h1b[(size_t)s1 * D_ + d2];
                ushort2 v2 = *(const ushort2*)&h1b[(size_t)s2 * D_ + d2];
                ushort2 v3 = *(const ushort2*)&h1b[(size_t)s3 * D_ + d2];
                a0 += (b2f(v0.x) + b2f(v1.x)) + (b2f(v2.x) + b2f(v3.x));
                a1 += (b2f(v0.y) + b2f(v1.y)) + (b2f(v2.y) + b2f(v3.y));
            }
            for (; i < cdeg; ++i) {
                ushort2 v = *(const ushort2*)&h1b[(size_t)ebuf[start + i] * D_ + d2];
                a0 += b2f(v.x); a1 += b2f(v.y);
            }
            float rinv = 1.f / (float)(cdeg + 1);
            ushort2 sv = *(const ushort2*)&h1b[(size_t)n * D_ + d2];
            r0 = f2b(b2f(sv.x) + a0 * rinv);
            r1 = f2b(b2f(sv.y) + a1 * rinv);
        }
        int pos = rl * 128 + w * 64 + ((cch ^ (rl & 7)) << 3) + fo;
        Al[pos] = r0;
        Al[pos + 1] = r1;
    }
    int rA = lane & 15, kq = lane >> 4;
    int wr = wid >> 1, wc = wid & 1;
    f32x4 acc[4][4] = {};
    for (int k0 = 0; k0 < 128; k0 += 64) {
        if (k0) __syncthreads();
#pragma unroll
        for (int i = 0; i < 4; ++i) {
            int rr = wid * 32 + i * 8 + (lane >> 3);
            gload16(gw2T + (size_t)rr * 128 + k0 + (((lane & 7) ^ (rr & 7)) << 3), &Bl[(wid * 32 + i * 8) * 64]);
        }
        __syncthreads();
#pragma unroll
        for (int ks = 0; ks < 2; ++ks) {
            int sw = ((ks * 4 + kq) ^ (rA & 7)) * 8;
            short8 af[4], bfr[4];
#pragma unroll
            for (int m = 0; m < 4; ++m)
                af[m] = *(const short8*)&Al[(64 * wr + m * 16 + rA) * 128 + k0 + sw];
#pragma unroll
            for (int n = 0; n < 4; ++n)
                bfr[n] = *(const short8*)&Bl[(64 * wc + n * 16 + rA) * 64 + sw];
#pragma unroll
            for (int m = 0; m < 4; ++m)
#pragma unroll
                for (int n = 0; n < 4; ++n)
                    acc[m][n] = __builtin_amdgcn_mfma_f32_16x16x32_bf16(af[m], bfr[n], acc[m][n], 0, 0, 0);
        }
    }
#pragma unroll
    for (int m = 0; m < 4; ++m)
#pragma unroll
        for (int n = 0; n < 4; ++n) {
            int cc = (wid & 1) * 64 + n * 16 + rA;
            float bv = b2[cc];
#pragma unroll
            for (int r = 0; r < 4; ++r) {
                int cr = rows0 + (wid >> 1) * 64 + m * 16 + kq * 4 + r;
                spe[(size_t)cr * 128 + cc] = fmaxf(acc[m][n][r] + bv, 0.f);
            }
        }
}

// ===================== MFMA GEMM (BM=64, gathered A rows) — head only =====================
__global__ __launch_bounds__(256) void k_head(const u16* __restrict__ A, const u16* __restrict__ BT,
                                              const float* __restrict__ bias, float* __restrict__ Cout,
                                              const int* __restrict__ endi, int M, int N, int K) {
    __shared__ __align__(16) char smem[24576];
    u16* Al = (u16*)smem;
    u16* Bl = Al + 64 * 64;
    int tid = threadIdx.x;
    int wid = tid >> 6, lane = tid & 63;
    int col0 = blockIdx.y * 128;
    f32x4 acc[2][4] = {};
    int rA = lane & 15, kq = lane >> 4;

    for (int k0 = 0; k0 < K; k0 += 64) {
        if (k0) __syncthreads();
#pragma unroll
        for (int i = 0; i < 6; ++i) {
            int c = wid * 6 + i;
            int rr = c * 8 + (lane >> 3);
            int sl = (((lane & 7) ^ (rr & 7)) << 3);
            if (c < 8) {
                size_t arow = (rr < B_) ? ((size_t)rr * S_ + endi[rr]) : 0;
                gload16(A + arow * K + k0 + sl, &Al[rr * 64]);
            } else {
                gload16(BT + (size_t)(col0 + rr - 64) * K + k0 + sl, &Bl[(rr - 64) * 64]);
            }
        }
        __syncthreads();
#pragma unroll
        for (int ks = 0; ks < 2; ++ks) {
            int sw = ((ks * 4 + kq) ^ (rA & 7)) * 8;
            int wr2 = wid & 1, wc2 = wid >> 1;
            short8 af[2], bfr[4];
#pragma unroll
            for (int m = 0; m < 2; ++m)
                af[m] = *(const short8*)&Al[(wr2 * 32 + m * 16 + rA) * 64 + sw];
#pragma unroll
            for (int n = 0; n < 4; ++n)
                bfr[n] = *(const short8*)&Bl[(wc2 * 64 + n * 16 + rA) * 64 + sw];
#pragma unroll
            for (int m = 0; m < 2; ++m)
#pragma unroll
                for (int n = 0; n < 4; ++n)
                    acc[m][n] = __builtin_amdgcn_mfma_f32_16x16x32_bf16(af[m], bfr[n], acc[m][n], 0, 0, 0);
        }
    }
#pragma unroll
    for (int m = 0; m < 2; ++m) {
#pragma unroll
        for (int n = 0; n < 4; ++n) {
            int cc = col0 + (wid >> 1) * 64 + n * 16 + rA;
            int cr0 = (wid & 1) * 32 + m * 16 + kq * 4;
            if (cc >= N) continue;
            float bv = bias[cc];
#pragma unroll
            for (int r = 0; r < 4; ++r) {
                int cr = cr0 + r;
                if (cr >= M) continue;
                Cout[(size_t)cr * N + cc] = acc[m][n][r] + bv;
            }
        }
    }
}

// ===================== fused QKV-proj + flash attention =====================
__global__ __launch_bounds__(256) void k_qkvatt(const u16* __restrict__ xb, const u16* __restrict__ wT,
                                                const float* __restrict__ bq, const u16* __restrict__ bias,
                                                u16* __restrict__ o) {
    __shared__ __align__(16) char smem[73728];
    u16* Kl  = (u16*)smem;
    u16* Vt  = (u16*)(smem + 20480);
    u16* Ql  = (u16*)(smem + 29184);
    u16* Pl  = (u16*)(smem + 37376);
    u16* Ast = (u16*)smem;
    u16* Bst = (u16*)(smem + 32768);
    int idx = blockIdx.x;
    int b = (idx & 7) * 8 + (idx >> 6);
    int h = (idx >> 3) & 7;
    int tid = threadIdx.x, wid = tid >> 6, lane = tid & 63;
    int rA = lane & 15, kq = lane >> 4;

    f32x4 acc[4][3] = {};
    for (int k0 = 0; k0 < 128; k0 += 64) {
        if (k0) __syncthreads();
#pragma unroll
        for (int i = 0; i < 8; ++i) {
            int row = wid * 64 + i * 8 + (lane >> 3);
            int sl = (((lane & 7) ^ (row & 7)) << 3);
            gload16(xb + ((size_t)(b * S_ + row)) * 128 + k0 + sl, &Ast[(wid * 64 + i * 8) * 64]);
        }
        if (wid < 3) {
#pragma unroll
            for (int i = 0; i < 2; ++i) {
                int c = wid * 2 + i;
                int brow = c * 8 + (lane >> 3);
                int grow = wid * 128 + h * 16 + (brow & 15);
                int sl = (((lane & 7) ^ (brow & 7)) << 3);
                gload16(wT + (size_t)grow * 128 + k0 + sl, &Bst[c * 8 * 64]);
            }
        }
        __syncthreads();
#pragma unroll
        for (int ks = 0; ks < 2; ++ks) {
            int sw = ((ks * 4 + kq) ^ (rA & 7)) * 8;
            short8 af[4], bfr[3];
#pragma unroll
            for (int m = 0; m < 4; ++m)
                af[m] = *(const short8*)&Ast[(wid * 64 + m * 16 + rA) * 64 + sw];
#pragma unroll
            for (int n = 0; n < 3; ++n)
                bfr[n] = *(const short8*)&Bst[(n * 16 + rA) * 64 + sw];
#pragma unroll
            for (int m = 0; m < 4; ++m)
#pragma unroll
                for (int n = 0; n < 3; ++n)
                    acc[m][n] = __builtin_amdgcn_mfma_f32_16x16x32_bf16(af[m], bfr[n], acc[m][n], 0, 0, 0);
        }
    }
    __syncthreads();
    {
        short8 z = {};
        *(short8*)&Kl[tid * KLS + 16] = z;
        *(short8*)&Kl[tid * KLS + 24] = z;
    }
    {
        float bq0 = bq[h * 16 + rA];
        float bq1 = bq[128 + h * 16 + rA];
        float bq2 = bq[256 + h * 16 + rA];
#pragma unroll
        for (int m = 0; m < 4; ++m) {
            int cr0 = wid * 64 + m * 16 + kq * 4;
#pragma unroll
            for (int r = 0; r < 4; ++r) {
                int row = cr0 + r;
                Ql[row * 16 + rA]  = f2b(acc[m][0][r] + bq0);
                Kl[row * KLS + rA] = f2b(acc[m][1][r] + bq1);
                Vt[rA * VTS + row] = f2b(acc[m][2][r] + bq2);
            }
        }
    }
    __syncthreads();

    u16* pl = Pl + wid * 16 * VTS;
    int qi = lane & 15;
    for (int qt = 0; qt < 4; ++qt) {
        int q = wid * 64 + qt * 16 + qi;
        ushort4 bb[16];
        const u16* bp = bias + (size_t)b * (S_ * S_) + (size_t)q * S_ + kq * 4;
#pragma unroll
        for (int t = 0; t < 16; ++t) bb[t] = *(const ushort4*)(bp + t * 16);
        short8 qf = {};
        if (lane < 32)
            qf = *(const short8*)&Ql[q * 16 + kq * 8];
        f32x4 sc[16];
#pragma unroll
        for (int t = 0; t < 16; ++t) {
            short8 kf = *(const short8*)&Kl[(t * 16 + qi) * KLS + kq * 8];
            f32x4 zz = {0.f, 0.f, 0.f, 0.f};
            sc[t] = __builtin_amdgcn_mfma_f32_16x16x32_bf16(kf, qf, zz, 0, 0, 0);
        }
        float m = -1e30f;
#pragma unroll
        for (int t = 0; t < 16; ++t) {
            sc[t][0] = sc[t][0] * 0.25f + h2f(bb[t].x);
            sc[t][1] = sc[t][1] * 0.25f + h2f(bb[t].y);
            sc[t][2] = sc[t][2] * 0.25f + h2f(bb[t].z);
            sc[t][3] = sc[t][3] * 0.25f + h2f(bb[t].w);
            m = fmaxf(m, fmaxf(fmaxf(sc[t][0], sc[t][1]), fmaxf(sc[t][2], sc[t][3])));
        }
        m = fmaxf(m, __shfl_xor(m, 16, 64));
        m = fmaxf(m, __shfl_xor(m, 32, 64));
        float lsum = 0.f;
#pragma unroll
        for (int t = 0; t < 16; ++t) {
            sc[t][0] = __expf(sc[t][0] - m);
            sc[t][1] = __expf(sc[t][1] - m);
            sc[t][2] = __expf(sc[t][2] - m);
            sc[t][3] = __expf(sc[t][3] - m);
            lsum += (sc[t][0] + sc[t][1]) + (sc[t][2] + sc[t][3]);
        }
        lsum += __shfl_xor(lsum, 16, 64);
        lsum += __shfl_xor(lsum, 32, 64);
        float inv = 1.f / lsum;
#pragma unroll
        for (int t = 0; t < 16; ++t) {
            ushort4 pw = make_ushort4(f2b(sc[t][0] * inv), f2b(sc[t][1] * inv),
                                      f2b(sc[t][2] * inv), f2b(sc[t][3] * inv));
            *(ushort4*)&pl[qi * VTS + t * 16 + kq * 4] = pw;
        }
        f32x4 oa = {0.f, 0.f, 0.f, 0.f};
#pragma unroll
        for (int w8 = 0; w8 < 8; ++w8) {
            short8 vf = *(const short8*)&Vt[qi * VTS + w8 * 32 + kq * 8];
            short8 pf = *(const short8*)&pl[qi * VTS + w8 * 32 + kq * 8];
            oa = __builtin_amdgcn_mfma_f32_16x16x32_bf16(vf, pf, oa, 0, 0, 0);
        }
        ushort4 ow = make_ushort4(f2b(oa[0]), f2b(oa[1]), f2b(oa[2]), f2b(oa[3]));
        *(ushort4*)&o[((size_t)(b * S_ + q)) * D_ + h * 16 + kq * 4] = ow;
    }
}

// ===================== fused layer-tail: LN1(x + atto@wo + bo) -> FFN -> LN2 =====================
__global__ __launch_bounds__(256) void k_layer(const u16* __restrict__ atto,
                                               const u16* __restrict__ woT, const float* __restrict__ bo,
                                               const float* __restrict__ ln1g, const float* __restrict__ ln1b,
                                               const u16* __restrict__ w1T, const float* __restrict__ b1,
                                               const u16* __restrict__ w2T, const float* __restrict__ b2,
                                               const float* __restrict__ ln2g, const float* __restrict__ ln2b,
                                               float* __restrict__ x, u16* __restrict__ xbout) {
    __shared__ __align__(16) char smem[73728];
    u16* Alds = (u16*)smem;
    u16* Wlds = (u16*)(smem + 8192);
    u16* f1   = (u16*)(smem + 40960);
    float* vbuf = (float*)smem;
    int tid = threadIdx.x, wid = tid >> 6, lane = tid & 63;
    int rows0 = blockIdx.x * 32;
    int rA = lane & 15, kq = lane >> 4;
    int row = tid >> 3, sub = tid & 7;

#pragma unroll
    for (int j = 0; j < 2; ++j) {
        int srow = wid * 8 + j * 4 + (lane >> 4);
        int win = (lane >> 3) & 1, slot = lane & 7;
        gload16(atto + (size_t)(rows0 + srow) * 128 + win * 64 + ((slot ^ (srow & 7)) << 3),
                Alds + (wid * 8 + j * 4) * 128);
    }
    f32x4 accw[2][2] = {};
    for (int k0 = 0; k0 < 128; k0 += 64) {
        __syncthreads();
#pragma unroll
        for (int i = 0; i < 4; ++i) {
            int rl2 = i * 32 + wid * 8 + (lane >> 3);
            gload16(woT + (size_t)rl2 * 128 + k0 + (((lane & 7) ^ (rl2 & 7)) << 3),
                    Wlds + (i * 32 + wid * 8) * 64);
        }
        __syncthreads();
#pragma unroll
        for (int ks = 0; ks < 2; ++ks) {
            int sw = ((ks * 4 + kq) ^ (rA & 7)) << 3;
            short8 af0 = *(const short8*)&Alds[rA * 128 + k0 + sw];
            short8 af1 = *(const short8*)&Alds[(16 + rA) * 128 + k0 + sw];
            short8 bf0 = *(const short8*)&Wlds[(wid * 32 + rA) * 64 + sw];
            short8 bf1 = *(const short8*)&Wlds[(wid * 32 + 16 + rA) * 64 + sw];
            accw[0][0] = __builtin_amdgcn_mfma_f32_16x16x32_bf16(af0, bf0, accw[0][0], 0, 0, 0);
            accw[0][1] = __builtin_amdgcn_mfma_f32_16x16x32_bf16(af0, bf1, accw[0][1], 0, 0, 0);
            accw[1][0] = __builtin_amdgcn_mfma_f32_16x16x32_bf16(af1, bf0, accw[1][0], 0, 0, 0);
            accw[1][1] = __builtin_amdgcn_mfma_f32_16x16x32_bf16(af1, bf1, accw[1][1], 0, 0, 0);
        }
    }
    __syncthreads();
#pragma unroll
    for (int m = 0; m < 2; ++m)
#pragma unroll
        for (int n = 0; n < 2; ++n) {
            int cc = wid * 32 + n * 16 + rA;
            float bv = bo[cc];
#pragma unroll
            for (int r = 0; r < 4; ++r) {
                int rl = m * 16 + kq * 4 + r;
                vbuf[rl * 133 + cc] = accw[m][n][r] + bv + x[(size_t)(rows0 + rl) * 128 + cc];
            }
        }
    __syncthreads();
    float x1[16];
    {
        const float* vr = vbuf + row * 133 + sub * 16;
        float s = 0.f, s2 = 0.f;
#pragma unroll
        for (int j = 0; j < 16; ++j) {
            x1[j] = vr[j];
            s += x1[j];
            s2 += x1[j] * x1[j];
        }
        s += __shfl_xor(s, 1, 64);  s2 += __shfl_xor(s2, 1, 64);
        s += __shfl_xor(s, 2, 64);  s2 += __shfl_xor(s2, 2, 64);
        s += __shfl_xor(s, 4, 64);  s2 += __shfl_xor(s2, 4, 64);
        float mean = s * (1.f / 128.f);
        float var = s2 * (1.f / 128.f) - mean * mean;
        float rs = rsqrtf(var + 1e-5f);
#pragma unroll
        for (int j = 0; j < 4; ++j) {
            float4 gv = *(const float4*)(ln1g + sub * 16 + j * 4);
            float4 bv = *(const float4*)(ln1b + sub * 16 + j * 4);
            x1[j * 4 + 0] = (x1[j * 4 + 0] - mean) * rs * gv.x + bv.x;
            x1[j * 4 + 1] = (x1[j * 4 + 1] - mean) * rs * gv.y + bv.y;
            x1[j * 4 + 2] = (x1[j * 4 + 2] - mean) * rs * gv.z + bv.z;
            x1[j * 4 + 3] = (x1[j * 4 + 3] - mean) * rs * gv.w + bv.w;
        }
    }
    __syncthreads();
#pragma unroll
    for (int j = 0; j < 16; ++j) {
        int c = sub * 16 + j;
        int scol = (c & ~63) | ((((c >> 3) & 7) ^ (row & 7)) << 3) | (c & 7);
        Alds[row * 128 + scol] = f2b(x1[j]);
    }
    for (int nh = 0; nh < 2; ++nh) {
        f32x4 acc1[2][4] = {};
        for (int k0 = 0; k0 < 128; k0 += 64) {
            __syncthreads();
#pragma unroll
            for (int i = 0; i < 8; ++i) {
                int rl2 = i * 32 + wid * 8 + (lane >> 3);
                gload16(w1T + (size_t)(nh * 256 + rl2) * 128 + k0 + (((lane & 7) ^ (rl2 & 7)) << 3),
                        Wlds + (i * 32 + wid * 8) * 64);
            }
            __syncthreads();
#pragma unroll
            for (int ks = 0; ks < 2; ++ks) {
                int sw = ((ks * 4 + kq) ^ (rA & 7)) << 3;
                short8 af[2], bf4[4];
                af[0] = *(const short8*)&Alds[rA * 128 + k0 + sw];
                af[1] = *(const short8*)&Alds[(16 + rA) * 128 + k0 + sw];
#pragma unroll
                for (int n = 0; n < 4; ++n)
                    bf4[n] = *(const short8*)&Wlds[(wid * 64 + n * 16 + rA) * 64 + sw];
#pragma unroll
                for (int m = 0; m < 2; ++m)
#pragma unroll
                    for (int n = 0; n < 4; ++n)
                        acc1[m][n] = __builtin_amdgcn_mfma_f32_16x16x32_bf16(af[m], bf4[n], acc1[m][n], 0, 0, 0);
            }
        }
#pragma unroll
        for (int m = 0; m < 2; ++m)
#pragma unroll
            for (int n = 0; n < 4; ++n) {
                int cc = nh * 256 + wid * 64 + n * 16 + rA;
                float bv = b1[cc];
#pragma unroll
                for (int r = 0; r < 4; ++r) {
                    int rl = m * 16 + kq * 4 + r;
                    float v = fmaxf(acc1[m][n][r] + bv, 0.f);
                    int scol = (cc & ~63) | (((((cc >> 3) & 7) ^ (rl & 7)) & 7) << 3) | (cc & 7);
                    f1[rl * 512 + scol] = f2b(v);
                }
            }
    }
    __syncthreads();
    f32x4 acc2[2][2] = {};
    for (int k0 = 0; k0 < 512; k0 += 64) {
        if (k0) __syncthreads();
#pragma unroll
        for (int i = 0; i < 4; ++i) {
            int rl2 = i * 32 + wid * 8 + (lane >> 3);
            gload16(w2T + (size_t)rl2 * 512 + k0 + (((lane & 7) ^ (rl2 & 7)) << 3),
                    Wlds + (i * 32 + wid * 8) * 64);
        }
        __syncthreads();
#pragma unroll
        for (int ks = 0; ks < 2; ++ks) {
            int sw = ((ks * 4 + kq) ^ (rA & 7)) << 3;
            short8 af0 = *(const short8*)&f1[rA * 512 + k0 + sw];
            short8 af1 = *(const short8*)&f1[(16 + rA) * 512 + k0 + sw];
            short8 bf0 = *(const short8*)&Wlds[(wid * 32 + rA) * 64 + sw];
            short8 bf1 = *(const short8*)&Wlds[(wid * 32 + 16 + rA) * 64 + sw];
            acc2[0][0] = __builtin_amdgcn_mfma_f32_16x16x32_bf16(af0, bf0, acc2[0][0], 0, 0, 0);
            acc2[0][1] = __builtin_amdgcn_mfma_f32_16x16x32_bf16(af0, bf1, acc2[0][1], 0, 0, 0);
            acc2[1][0] = __builtin_amdgcn_mfma_f32_16x16x32_bf16(af1, bf0, acc2[1][0], 0, 0, 0);
            acc2[1][1] = __builtin_amdgcn_mfma_f32_16x16x32_bf16(af1, bf1, acc2[1][1], 0, 0, 0);
        }
    }
    __syncthreads();
#pragma unroll
    for (int m = 0; m < 2; ++m)
#pragma unroll
        for (int n = 0; n < 2; ++n) {
            int cc = wid * 32 + n * 16 + rA;
            float bv = b2[cc];
#pragma unroll
            for (int r = 0; r < 4; ++r) {
                int rl = m * 16 + kq * 4 + r;
                vbuf[rl * 133 + cc] = acc2[m][n][r] + bv;
            }
        }
    __syncthreads();
    {
        const float* vr = vbuf + row * 133 + sub * 16;
        float vv[16];
        float s = 0.f, s2 = 0.f;
#pragma unroll
        for (int j = 0; j < 16; ++j) {
            vv[j] = vr[j] + x1[j];
            s += vv[j];
            s2 += vv[j] * vv[j];
        }
        s += __shfl_xor(s, 1, 64);  s2 += __shfl_xor(s2, 1, 64);
        s += __shfl_xor(s, 2, 64);  s2 += __shfl_xor(s2, 2, 64);
        s += __shfl_xor(s, 4, 64);  s2 += __shfl_xor(s2, 4, 64);
        float mean = s * (1.f / 128.f);
        float var = s2 * (1.f / 128.f) - mean * mean;
        float rs = rsqrtf(var + 1e-5f);
        int grow = rows0 + row;
        float* xrow = x + (size_t)grow * 128 + sub * 16;
        u16* xbrow = xbout + (size_t)grow * 128 + sub * 16;
#pragma unroll
        for (int j = 0; j < 4; ++j) {
            float4 gv = *(const float4*)(ln2g + sub * 16 + j * 4);
            float4 bv = *(const float4*)(ln2b + sub * 16 + j * 4);
            float o0 = (vv[j * 4 + 0] - mean) * rs * gv.x + bv.x;
            float o1 = (vv[j * 4 + 1] - mean) * rs * gv.y + bv.y;
            float o2 = (vv[j * 4 + 2] - mean) * rs * gv.z + bv.z;
            float o3 = (vv[j * 4 + 3] - mean) * rs * gv.w + bv.w;
            *(float4*)(xrow + j * 4) = make_float4(o0, o1, o2, o3);
            *(ushort4*)(xbrow + j * 4) = make_ushort4(f2b(o0), f2b(o1), f2b(o2), f2b(o3));
        }
    }
}

// ===================== fusion + positional encoding =====================
__global__ __launch_bounds__(256) void k_fusion(const float* __restrict__ spe, const int* __restrict__ traj,
                                                const float* __restrict__ ue_tab, const int* __restrict__ uid,
                                                const float* __restrict__ tempx, const int* __restrict__ hwx,
                                                const float* __restrict__ ce_tab, const float* __restrict__ flw,
                                                const float* __restrict__ flb, float* __restrict__ x,
                                                u16* __restrict__ xb) {
    __shared__ float Ws[22 * D_];
    __shared__ float bs[D_];
    __shared__ float ins[2][22];
    int tid = threadIdx.x;
    for (int i = tid; i < 22 * D_; i += 256) Ws[i] = flw[i];
    if (tid < D_) bs[tid] = flb[tid];
    __syncthreads();
    int ro = tid >> 7, d = tid & 127;
    int base = blockIdx.x * 32;
    for (int ir = 0; ir < 16; ++ir) {
        int tok = base + ir * 2 + ro;
        int b = tok >> 8, s = tok & 255;
        if (d < TD_) ins[ro][d] = tempx[(size_t)tok * TD_ + d];
        else if (d < 22) ins[ro][d] = ce_tab[(size_t)hwx[tok] * CED_ + (d - TD_)];
        __syncthreads();
        float acc = bs[d];
#pragma unroll
        for (int k = 0; k < 22; ++k) acc = fmaf(ins[ro][k], Ws[k * D_ + d], acc);
        acc = fmaxf(acc, 0.f);
        int i2 = d & ~1;
        float ang = (float)s * __expf(-(float)i2 * 0.0719557841560639f);
        float pe = (d & 1) ? cosf(ang) : sinf(ang);
        float v = spe[(size_t)traj[tok] * D_ + d] + ue_tab[(size_t)uid[b] * D_ + d] + acc + pe;
        x[(size_t)tok * D_ + d] = v;
        xb[(size_t)tok * D_ + d] = f2b(v);
        __syncthreads();
    }
}

// ===================== launch =====================
extern "C" void kernel_launch(void* const* d_in, const int* in_sizes, int n_in,
                              void* d_out, int out_size, void* d_ws, size_t ws_size,
                              hipStream_t stream) {
    const float* node_feature = (const float*)d_in[0];
    const int*   edge_index   = (const int*)d_in[1];
    const int*   traj_x       = (const int*)d_in[2];
    const float* temporal_x   = (const float*)d_in[3];
    const int*   user_id_x    = (const int*)d_in[4];
    const int*   mask         = (const int*)d_in[5];
    const int*   end_idx      = (const int*)d_in[6];
    const float* tmat         = (const float*)d_in[8];
    const float* dmat         = (const float*)d_in[9];
    const int*   highway_x    = (const int*)d_in[10];
    const float* lambda2      = (const float*)d_in[11];
    const float* gnn_w1       = (const float*)d_in[12];
    const float* gnn_b1       = (const float*)d_in[13];
    const float* gnn_w2       = (const float*)d_in[14];
    const float* gnn_b2       = (const float*)d_in[15];
    const float* ue_tab       = (const float*)d_in[16];
    const float* ce_tab       = (const float*)d_in[17];
    const float* fl_w         = (const float*)d_in[18];
    const float* fl_b         = (const float*)d_in[19];
    const float* wqkv         = (const float*)d_in[20];
    const float* bqkv         = (const float*)d_in[21];
    const float* wo           = (const float*)d_in[22];
    const float* bo           = (const float*)d_in[23];
    const float* ln1_g        = (const float*)d_in[24];
    const float* ln1_b        = (const float*)d_in[25];
    const float* ln2_g        = (const float*)d_in[26];
    const float* ln2_b        = (const float*)d_in[27];
    const float* ffn_w1       = (const float*)d_in[28];
    const float* ffn_b1       = (const float*)d_in[29];
    const float* ffn_w2       = (const float*)d_in[30];
    const float* ffn_b2       = (const float*)d_in[31];
    const float* head_w       = (const float*)d_in[32];
    const float* head_b       = (const float*)d_in[33];
    float* out = (float*)d_out;

    // ---- workspace layout (float units) ----
    float* w     = (float*)d_ws;
    int*   cnt   = (int*)w;                  // [0, 40,960)
    float* spe   = w + 40960;                // [40,960, 5,169,152)
    u16*   biasb = (u16*)(w + 5169152);      // [5,169,152, 7,266,304)
    float* wreg  = w + 7266304;              // bf16 weights -> ends 7,999,488
    u16* wqkvT = (u16*)wreg;
    u16* woT   = wqkvT + 4 * 384 * 128;
    u16* w1T   = woT + 4 * 128 * 128;
    u16* w2T   = w1T + 4 * 512 * 128;
    u16* gw1T  = w2T + 4 * 128 * 512;
    u16* gw2T  = gw1T + 128 * 64;
    u16* hwT   = gw2T + 128 * 128;
    float* pool  = w + 8000000;
    // GNN phase
    u16*   h1b   = (u16*)pool;               // [0, 2,564,096) f
    int*   off   = (int*)(pool + 2564096);
    int*   cursor= (int*)(pool + 2604160);
    int*   ebuf  = (int*)(pool + 2644224);
    int*   part  = (int*)(pool + 2804224);
    // transformer phase (GNN fully done before fusion)
    float* x     = pool;                     // [0, 2,097,152)  (overlaps h1b after GNN)
    u16*   xb    = (u16*)(pool + 3145728);   // placed after CSR arrays
    u16*   attob = (u16*)(pool + 4718592);

    const int* esrc = edge_index;
    const int* edst = edge_index + E_;

    // ---- uber prep ----
    UberArgs ua;
    const float* srcs[7] = {wqkv, wo, ffn_w1, ffn_w2, gnn_w1, gnn_w2, head_w};
    u16* dsts[7]        = {wqkvT, woT, w1T, w2T, gw1T, gw2T, hwT};
    int Ks[7]    = {128, 128, 128, 512, 32, 128, 128};
    int Npads[7] = {384, 128, 512, 128, 128, 128, UP_};
    int Nsrcs[7] = {384, 128, 512, 128, 128, 128, U_};
    int Kps[7]   = {128, 128, 128, 512, 64, 128, 128};
    int Ls[7]    = {4, 4, 4, 4, 1, 1, 1};
    int bb = UB_CNT_END;
    for (int t = 0; t < 7; ++t) {
        ua.csrc[t] = srcs[t]; ua.cdst[t] = dsts[t];
        ua.K[t] = Ks[t]; ua.Npad[t] = Npads[t]; ua.Nsrc[t] = Nsrcs[t]; ua.Kp[t] = Kps[t];
        ua.base[t] = bb;
        bb += (Npads[t] / 32) * (Kps[t] / 32) * Ls[t];
    }
    ua.tm = tmat; ua.dm = dmat; ua.maskp = mask; ua.lambda2 = lambda2;
    ua.bias = biasb; ua.cnt = cnt;
    k_uber<<<UB_TOTAL, 256, 0, stream>>>(ua);

    // ---- GNN: CSR build + fused gather-GEMMs ----
    k_count<<<(E_ + 255) / 256, 256, 0, stream>>>(edst, cnt);
    k_scanA<<<NSCB, 256, 0, stream>>>(cnt, part);
    k_scanB<<<NSCB, 256, 0, stream>>>(cnt, part, off, cursor);
    k_fill<<<(E_ + 255) / 256, 256, 0, stream>>>(esrc, edst, cursor, ebuf);
    k_ggemm1<<<NP_ / 128, 256, 0, stream>>>(node_feature, off, cnt, ebuf, gw1T, gnn_b1, h1b);
    k_ggemm2<<<NP_ / 128, 256, 0, stream>>>(h1b, off, cnt, ebuf, gw2T, gnn_b2, spe);

    // ---- fusion ----
    k_fusion<<<(B_ * S_) / 32, 256, 0, stream>>>(spe, traj_x, ue_tab, user_id_x,
                                                 temporal_x, highway_x, ce_tab, fl_w, fl_b, x, xb);

    // ---- transformer: 2 kernels per layer ----
    for (int l = 0; l < L_; ++l) {
        k_qkvatt<<<B_ * H_, 256, 0, stream>>>(xb, wqkvT + (size_t)l * 384 * 128,
                                              bqkv + (size_t)l * 384, biasb, attob);
        k_layer<<<(B_ * S_) / 32, 256, 0, stream>>>(attob, woT + (size_t)l * 128 * 128, bo + l * D_,
                                                    ln1_g + l * D_, ln1_b + l * D_,
                                                    w1T + (size_t)l * 512 * 128, ffn_b1 + l * FF_,
                                                    w2T + (size_t)l * 128 * 512, ffn_b2 + l * D_,
                                                    ln2_g + l * D_, ln2_b + l * D_, x, xb);
    }

    // ---- head (gather fused) ----
    k_head<<<dim3(1, UP_ / 128), 256, 0, stream>>>(xb, hwT, head_b, out, end_idx, B_, U_, D_);
}

// Round 15
// 320.067 us; speedup vs baseline: 3.6297x; 1.0957x over previous
//
#include <hip/hip_runtime.h>
#include <hip/hip_fp16.h>
#include <cstdint>
#include <cstddef>

typedef unsigned short u16;
typedef __attribute__((ext_vector_type(8))) short short8;
typedef __attribute__((ext_vector_type(4))) float f32x4;

// ---- problem constants ----
#define B_   64
#define S_   256
#define D_   128
#define H_   8
#define FF_  512
#define L_   4
#define U_   5000
#define UP_  5120
#define N_   40000
#define NP_  40064
#define E_   160000
#define FEA_ 32
#define CED_ 16
#define TD_  6
#define NSCB 157
#define UB_CNT_END 160
#define UB_CVT_END 1592
#define UB_TOTAL   5688
#define KLS 40
#define VTS 272

static __device__ __forceinline__ u16 f2b(float f) {
    unsigned int u = __float_as_uint(f);
    unsigned int r = (u + 0x7FFFu + ((u >> 16) & 1u)) >> 16;
    return (u16)r;
}
static __device__ __forceinline__ float b2f(u16 u) {
    return __uint_as_float(((unsigned int)u) << 16);
}
static __device__ __forceinline__ u16 f2h(float f) {
    return __half_as_ushort(__float2half(f));
}
static __device__ __forceinline__ float h2f(u16 u) {
    return __half2float(__ushort_as_half(u));
}
static __device__ __forceinline__ void gload16(const void* g, void* l) {
    __builtin_amdgcn_global_load_lds(
        (const __attribute__((address_space(1))) unsigned int*)g,
        (__attribute__((address_space(3))) unsigned int*)l,
        16, 0, 0);
}

// ===================== uber prep: cnt-zero + 7 weight transposes + attn bias =====================
struct UberArgs {
    const float* csrc[7];
    u16* cdst[7];
    int K[7], Npad[7], Nsrc[7], Kp[7], base[7];
    const float* tm; const float* dm; const int* maskp; const float* lambda2;
    u16* bias; int* cnt;
};

__global__ __launch_bounds__(256) void k_uber(UberArgs a) {
    __shared__ float tile[32][33];
    int bid = blockIdx.x, tid = threadIdx.x;
    if (bid < UB_CNT_END) {
        int idx = bid * 256 + tid;
        if (idx < NP_) a.cnt[idx] = 0;
        return;
    }
    if (bid < UB_CVT_END) {
        int t = 0;
#pragma unroll
        for (int i = 1; i < 7; ++i) t += (bid >= a.base[i]);
        int rb = bid - a.base[t];
        int K = a.K[t], Npad = a.Npad[t], Nsrc = a.Nsrc[t], Kp = a.Kp[t];
        int nbn = Npad >> 5, nbk = Kp >> 5;
        int per = nbn * nbk;
        int l = rb / per, rem = rb - l * per;
        int n0 = (rem % nbn) * 32, k0 = (rem / nbn) * 32;
        const float* in = a.csrc[t];
        u16* outp = a.cdst[t];
        int j = tid & 31, i2 = tid >> 5;
#pragma unroll
        for (int r = 0; r < 4; ++r) {
            int k = k0 + i2 + r * 8, n = n0 + j;
            tile[i2 + r * 8][j] = (k < K && n < Nsrc) ? in[(size_t)l * K * Nsrc + (size_t)k * Nsrc + n] : 0.f;
        }
        __syncthreads();
#pragma unroll
        for (int r = 0; r < 4; ++r) {
            int n = n0 + i2 + r * 8, k = k0 + j;
            if (n < Npad && k < Kp)
                outp[(size_t)l * Npad * Kp + (size_t)n * Kp + k] = f2b(tile[j][i2 + r * 8]);
        }
        return;
    }
    int t4 = (bid - UB_CVT_END) * 256 + tid;
    const int total = B_ * S_ * S_ / 4;
    if (t4 >= total) return;
    float l2 = *a.lambda2, l2c = 1.f - l2;
    float4 av = ((const float4*)a.tm)[t4];
    float4 bv = ((const float4*)a.dm)[t4];
    int basei = t4 * 4;
    int bb = basei >> 16;
    int k0 = basei & 255;
    const int* mrow = a.maskp + bb * S_;
    float r0 = (mrow[k0 + 0] > 0 ? 0.f : -30000.f) - (l2 * __logf(1.f + av.x) + l2c * __logf(1.f + bv.x));
    float r1 = (mrow[k0 + 1] > 0 ? 0.f : -30000.f) - (l2 * __logf(1.f + av.y) + l2c * __logf(1.f + bv.y));
    float r2 = (mrow[k0 + 2] > 0 ? 0.f : -30000.f) - (l2 * __logf(1.f + av.z) + l2c * __logf(1.f + bv.z));
    float r3 = (mrow[k0 + 3] > 0 ? 0.f : -30000.f) - (l2 * __logf(1.f + av.w) + l2c * __logf(1.f + bv.w));
    *(ushort4*)&a.bias[(size_t)t4 * 4] = make_ushort4(f2h(r0), f2h(r1), f2h(r2), f2h(r3));
}

// ===================== CSR build =====================
__global__ __launch_bounds__(256) void k_count(const int* __restrict__ dst, int* __restrict__ cnt) {
    int e = blockIdx.x * 256 + threadIdx.x;
    if (e < E_) atomicAdd(&cnt[dst[e]], 1);
}

// fused scan: base = direct sum of cnt[0 .. blk*256), then intra-block inclusive scan
__global__ __launch_bounds__(256) void k_scan(const int* __restrict__ cnt,
                                              int* __restrict__ off, int* __restrict__ cursor) {
    __shared__ int sh[256];
    __shared__ int bsum;
    int tid = threadIdx.x;
    int lim = blockIdx.x * 256;
    int s = 0;
    for (int i = tid; i < lim; i += 256) s += cnt[i];
    sh[tid] = s;
    __syncthreads();
    for (int o = 128; o > 0; o >>= 1) {
        if (tid < o) sh[tid] += sh[tid + o];
        __syncthreads();
    }
    if (tid == 0) bsum = sh[0];
    __syncthreads();
    int basev = bsum;
    __syncthreads();
    int idx = lim + tid;
    int v = (idx < NP_) ? cnt[idx] : 0;
    sh[tid] = v;
    __syncthreads();
    for (int o = 1; o < 256; o <<= 1) {
        int t2 = (tid >= o) ? sh[tid - o] : 0;
        __syncthreads();
        sh[tid] += t2;
        __syncthreads();
    }
    if (idx < NP_) {
        int res = sh[tid] - v + basev;
        off[idx] = res;
        cursor[idx] = res;
    }
}

__global__ __launch_bounds__(256) void k_fill(const int* __restrict__ src, const int* __restrict__ dst,
                                              int* __restrict__ cursor, int* __restrict__ ebuf) {
    int e = blockIdx.x * 256 + threadIdx.x;
    if (e >= E_) return;
    int p = atomicAdd(&cursor[dst[e]], 1);
    ebuf[p] = src[e];
}

// ===================== GNN gather+prep (high-TLP, ILP-unrolled) =====================
__global__ __launch_bounds__(256) void k_gprep1(const float* __restrict__ nf, const int* __restrict__ off,
                                                const int* __restrict__ cnt, const int* __restrict__ ebuf,
                                                u16* __restrict__ out) {
    int n = blockIdx.x * 8 + (threadIdx.x >> 5);
    int f = threadIdx.x & 31;
    u16 r = 0;
    if (n < N_) {
        int start = off[n], c = cnt[n];
        float acc = 0.f;
        int i = 0;
        for (; i + 4 <= c; i += 4) {
            int s0 = ebuf[start + i], s1 = ebuf[start + i + 1];
            int s2 = ebuf[start + i + 2], s3 = ebuf[start + i + 3];
            float v0 = nf[(size_t)s0 * FEA_ + f];
            float v1 = nf[(size_t)s1 * FEA_ + f];
            float v2 = nf[(size_t)s2 * FEA_ + f];
            float v3 = nf[(size_t)s3 * FEA_ + f];
            acc += (v0 + v1) + (v2 + v3);
        }
        for (; i < c; ++i) acc += nf[(size_t)ebuf[start + i] * FEA_ + f];
        r = f2b(nf[(size_t)n * FEA_ + f] + acc / (float)(c + 1));
    }
    if (n < NP_) {
        out[(size_t)n * 64 + f] = r;
        out[(size_t)n * 64 + 32 + f] = 0;
    }
}

__global__ __launch_bounds__(256) void k_gprep2(const u16* __restrict__ h1b, const int* __restrict__ off,
                                                const int* __restrict__ cnt, const int* __restrict__ ebuf,
                                                u16* __restrict__ out) {
    int n = blockIdx.x * 4 + (threadIdx.x >> 6);
    int d2 = (threadIdx.x & 63) * 2;
    if (n >= NP_) return;
    u16 r0 = 0, r1 = 0;
    if (n < N_) {
        int start = off[n], c = cnt[n];
        float a0 = 0.f, a1 = 0.f;
        int i = 0;
        for (; i + 4 <= c; i += 4) {
            int s0 = ebuf[start + i], s1 = ebuf[start + i + 1];
            int s2 = ebuf[start + i + 2], s3 = ebuf[start + i + 3];
            ushort2 v0 = *(const ushort2*)&h1b[(size_t)s0 * D_ + d2];
            ushort2 v1 = *(const ushort2*)&h1b[(size_t)s1 * D_ + d2];
            ushort2 v2 = *(const ushort2*)&h1b[(size_t)s2 * D_ + d2];
            ushort2 v3 = *(const ushort2*)&h1b[(size_t)s3 * D_ + d2];
            a0 += (b2f(v0.x) + b2f(v1.x)) + (b2f(v2.x) + b2f(v3.x));
            a1 += (b2f(v0.y) + b2f(v1.y)) + (b2f(v2.y) + b2f(v3.y));
        }
        for (; i < c; ++i) {
            ushort2 v = *(const ushort2*)&h1b[(size_t)ebuf[start + i] * D_ + d2];
            a0 += b2f(v.x); a1 += b2f(v.y);
        }
        float rinv = 1.f / (float)(c + 1);
        ushort2 sv = *(const ushort2*)&h1b[(size_t)n * D_ + d2];
        r0 = f2b(b2f(sv.x) + a0 * rinv);
        r1 = f2b(b2f(sv.y) + a1 * rinv);
    }
    *(ushort2*)&out[(size_t)n * D_ + d2] = make_ushort2(r0, r1);
}

// ===================== MFMA GEMM (BM 64/128, opt gathered A) =====================
template<int BM, int ACT, int OUTB, int GAT>
__global__ __launch_bounds__(256) void k_mgemm(const u16* __restrict__ A, const u16* __restrict__ BT,
                                               const float* __restrict__ bias, void* __restrict__ Cout,
                                               const int* __restrict__ endi, int M, int N, int K) {
    constexpr int SMEMB = (BM == 128) ? 32768 : 24576;
    __shared__ __align__(16) char smem[SMEMB];
    u16* Al = (u16*)smem;
    u16* Bl = Al + (BM == 128 ? 128 * 64 : 64 * 64);
    int tid = threadIdx.x;
    int wid = tid >> 6, lane = tid & 63;
    int row0 = blockIdx.x * BM;
    int col0 = blockIdx.y * 128;
    f32x4 acc[4][4] = {};
    int rA = lane & 15, kq = lane >> 4;

    for (int k0 = 0; k0 < K; k0 += 64) {
        if (k0) __syncthreads();
        if (BM == 128) {
            int srow = wid * 32 + (lane >> 3);
            int ks8 = ((lane & 7) ^ (lane >> 3)) * 8;
#pragma unroll
            for (int i = 0; i < 4; ++i) {
                int row = srow + i * 8;
                size_t arow = (size_t)(row0 + row);
                if (GAT) {
                    int bb2 = row0 + row;
                    arow = (bb2 < B_) ? ((size_t)bb2 * S_ + endi[bb2]) : 0;
                }
                gload16(A + arow * K + k0 + ks8, &Al[(wid * 32 + i * 8) * 64]);
                gload16(BT + (size_t)(col0 + row) * K + k0 + ks8, &Bl[(wid * 32 + i * 8) * 64]);
            }
        } else {
#pragma unroll
            for (int i = 0; i < 6; ++i) {
                int c = wid * 6 + i;
                int rr = c * 8 + (lane >> 3);
                int sl = (((lane & 7) ^ (rr & 7)) << 3);
                if (c < 8) {
                    size_t arow = (size_t)(row0 + rr);
                    if (GAT) {
                        int bb2 = row0 + rr;
                        arow = (bb2 < B_) ? ((size_t)bb2 * S_ + endi[bb2]) : 0;
                    }
                    gload16(A + arow * K + k0 + sl, &Al[rr * 64]);
                } else {
                    gload16(BT + (size_t)(col0 + rr - 64) * K + k0 + sl, &Bl[(rr - 64) * 64]);
                }
            }
        }
        __syncthreads();
#pragma unroll
        for (int ks = 0; ks < 2; ++ks) {
            int sw = ((ks * 4 + kq) ^ (rA & 7)) * 8;
            if (BM == 128) {
                int wr = wid >> 1, wc = wid & 1;
                short8 af[4], bfr[4];
#pragma unroll
                for (int m = 0; m < 4; ++m)
                    af[m] = *(const short8*)&Al[(64 * wr + m * 16 + rA) * 64 + sw];
#pragma unroll
                for (int n = 0; n < 4; ++n)
                    bfr[n] = *(const short8*)&Bl[(64 * wc + n * 16 + rA) * 64 + sw];
#pragma unroll
                for (int m = 0; m < 4; ++m)
#pragma unroll
                    for (int n = 0; n < 4; ++n)
                        acc[m][n] = __builtin_amdgcn_mfma_f32_16x16x32_bf16(af[m], bfr[n], acc[m][n], 0, 0, 0);
            } else {
                int wr2 = wid & 1, wc2 = wid >> 1;
                short8 af[2], bfr[4];
#pragma unroll
                for (int m = 0; m < 2; ++m)
                    af[m] = *(const short8*)&Al[(wr2 * 32 + m * 16 + rA) * 64 + sw];
#pragma unroll
                for (int n = 0; n < 4; ++n)
                    bfr[n] = *(const short8*)&Bl[(wc2 * 64 + n * 16 + rA) * 64 + sw];
#pragma unroll
                for (int m = 0; m < 2; ++m)
#pragma unroll
                    for (int n = 0; n < 4; ++n)
                        acc[m][n] = __builtin_amdgcn_mfma_f32_16x16x32_bf16(af[m], bfr[n], acc[m][n], 0, 0, 0);
            }
        }
    }

    constexpr int MR = (BM == 128) ? 4 : 2;
#pragma unroll
    for (int m = 0; m < MR; ++m) {
#pragma unroll
        for (int n = 0; n < 4; ++n) {
            int cc, cr0;
            if (BM == 128) { cc = col0 + (wid & 1) * 64 + n * 16 + rA; cr0 = row0 + (wid >> 1) * 64 + m * 16 + kq * 4; }
            else           { cc = col0 + (wid >> 1) * 64 + n * 16 + rA; cr0 = row0 + (wid & 1) * 32 + m * 16 + kq * 4; }
            if (cc >= N) continue;
            float bv = bias[cc];
#pragma unroll
            for (int r = 0; r < 4; ++r) {
                int cr = cr0 + r;
                if (cr >= M) continue;
                float v = acc[m][n][r] + bv;
                if (ACT) v = fmaxf(v, 0.f);
                if (OUTB) ((u16*)Cout)[(size_t)cr * N + cc] = f2b(v);
                else      ((float*)Cout)[(size_t)cr * N + cc] = v;
            }
        }
    }
}

// ===================== fused QKV-proj + flash attention =====================
__global__ __launch_bounds__(256) void k_qkvatt(const u16* __restrict__ xb, const u16* __restrict__ wT,
                                                const float* __restrict__ bq, const u16* __restrict__ bias,
                                                u16* __restrict__ o) {
    __shared__ __align__(16) char smem[73728];
    u16* Kl  = (u16*)smem;
    u16* Vt  = (u16*)(smem + 20480);
    u16* Ql  = (u16*)(smem + 29184);
    u16* Pl  = (u16*)(smem + 37376);
    u16* Ast = (u16*)smem;
    u16* Bst = (u16*)(smem + 32768);
    int idx = blockIdx.x;
    int b = (idx & 7) * 8 + (idx >> 6);
    int h = (idx >> 3) & 7;
    int tid = threadIdx.x, wid = tid >> 6, lane = tid & 63;
    int rA = lane & 15, kq = lane >> 4;

    f32x4 acc[4][3] = {};
    for (int k0 = 0; k0 < 128; k0 += 64) {
        if (k0) __syncthreads();
#pragma unroll
        for (int i = 0; i < 8; ++i) {
            int row = wid * 64 + i * 8 + (lane >> 3);
            int sl = (((lane & 7) ^ (row & 7)) << 3);
            gload16(xb + ((size_t)(b * S_ + row)) * 128 + k0 + sl, &Ast[(wid * 64 + i * 8) * 64]);
        }
        if (wid < 3) {
#pragma unroll
            for (int i = 0; i < 2; ++i) {
                int c = wid * 2 + i;
                int brow = c * 8 + (lane >> 3);
                int grow = wid * 128 + h * 16 + (brow & 15);
                int sl = (((lane & 7) ^ (brow & 7)) << 3);
                gload16(wT + (size_t)grow * 128 + k0 + sl, &Bst[c * 8 * 64]);
            }
        }
        __syncthreads();
#pragma unroll
        for (int ks = 0; ks < 2; ++ks) {
            int sw = ((ks * 4 + kq) ^ (rA & 7)) * 8;
            short8 af[4], bfr[3];
#pragma unroll
            for (int m = 0; m < 4; ++m)
                af[m] = *(const short8*)&Ast[(wid * 64 + m * 16 + rA) * 64 + sw];
#pragma unroll
            for (int n = 0; n < 3; ++n)
                bfr[n] = *(const short8*)&Bst[(n * 16 + rA) * 64 + sw];
#pragma unroll
            for (int m = 0; m < 4; ++m)
#pragma unroll
                for (int n = 0; n < 3; ++n)
                    acc[m][n] = __builtin_amdgcn_mfma_f32_16x16x32_bf16(af[m], bfr[n], acc[m][n], 0, 0, 0);
        }
    }
    __syncthreads();
    {
        short8 z = {};
        *(short8*)&Kl[tid * KLS + 16] = z;
        *(short8*)&Kl[tid * KLS + 24] = z;
    }
    {
        float bq0 = bq[h * 16 + rA];
        float bq1 = bq[128 + h * 16 + rA];
        float bq2 = bq[256 + h * 16 + rA];
#pragma unroll
        for (int m = 0; m < 4; ++m) {
            int cr0 = wid * 64 + m * 16 + kq * 4;
#pragma unroll
            for (int r = 0; r < 4; ++r) {
                int row = cr0 + r;
                Ql[row * 16 + rA]  = f2b(acc[m][0][r] + bq0);
                Kl[row * KLS + rA] = f2b(acc[m][1][r] + bq1);
                Vt[rA * VTS + row] = f2b(acc[m][2][r] + bq2);
            }
        }
    }
    __syncthreads();

    u16* pl = Pl + wid * 16 * VTS;
    int qi = lane & 15;
    for (int qt = 0; qt < 4; ++qt) {
        int q = wid * 64 + qt * 16 + qi;
        ushort4 bb[16];
        const u16* bp = bias + (size_t)b * (S_ * S_) + (size_t)q * S_ + kq * 4;
#pragma unroll
        for (int t = 0; t < 16; ++t) bb[t] = *(const ushort4*)(bp + t * 16);
        short8 qf = {};
        if (lane < 32)
            qf = *(const short8*)&Ql[q * 16 + kq * 8];
        f32x4 sc[16];
#pragma unroll
        for (int t = 0; t < 16; ++t) {
            short8 kf = *(const short8*)&Kl[(t * 16 + qi) * KLS + kq * 8];
            f32x4 zz = {0.f, 0.f, 0.f, 0.f};
            sc[t] = __builtin_amdgcn_mfma_f32_16x16x32_bf16(kf, qf, zz, 0, 0, 0);
        }
        float m = -1e30f;
#pragma unroll
        for (int t = 0; t < 16; ++t) {
            sc[t][0] = sc[t][0] * 0.25f + h2f(bb[t].x);
            sc[t][1] = sc[t][1] * 0.25f + h2f(bb[t].y);
            sc[t][2] = sc[t][2] * 0.25f + h2f(bb[t].z);
            sc[t][3] = sc[t][3] * 0.25f + h2f(bb[t].w);
            m = fmaxf(m, fmaxf(fmaxf(sc[t][0], sc[t][1]), fmaxf(sc[t][2], sc[t][3])));
        }
        m = fmaxf(m, __shfl_xor(m, 16, 64));
        m = fmaxf(m, __shfl_xor(m, 32, 64));
        float lsum = 0.f;
#pragma unroll
        for (int t = 0; t < 16; ++t) {
            sc[t][0] = __expf(sc[t][0] - m);
            sc[t][1] = __expf(sc[t][1] - m);
            sc[t][2] = __expf(sc[t][2] - m);
            sc[t][3] = __expf(sc[t][3] - m);
            lsum += (sc[t][0] + sc[t][1]) + (sc[t][2] + sc[t][3]);
        }
        lsum += __shfl_xor(lsum, 16, 64);
        lsum += __shfl_xor(lsum, 32, 64);
        float inv = 1.f / lsum;
#pragma unroll
        for (int t = 0; t < 16; ++t) {
            ushort4 pw = make_ushort4(f2b(sc[t][0] * inv), f2b(sc[t][1] * inv),
                                      f2b(sc[t][2] * inv), f2b(sc[t][3] * inv));
            *(ushort4*)&pl[qi * VTS + t * 16 + kq * 4] = pw;
        }
        f32x4 oa = {0.f, 0.f, 0.f, 0.f};
#pragma unroll
        for (int w8 = 0; w8 < 8; ++w8) {
            short8 vf = *(const short8*)&Vt[qi * VTS + w8 * 32 + kq * 8];
            short8 pf = *(const short8*)&pl[qi * VTS + w8 * 32 + kq * 8];
            oa = __builtin_amdgcn_mfma_f32_16x16x32_bf16(vf, pf, oa, 0, 0, 0);
        }
        ushort4 ow = make_ushort4(f2b(oa[0]), f2b(oa[1]), f2b(oa[2]), f2b(oa[3]));
        *(ushort4*)&o[((size_t)(b * S_ + q)) * D_ + h * 16 + kq * 4] = ow;
    }
}

// ===================== fused layer-tail: LN1(x + atto@wo + bo) -> FFN -> LN2 =====================
__global__ __launch_bounds__(256) void k_layer(const u16* __restrict__ atto,
                                               const u16* __restrict__ woT, const float* __restrict__ bo,
                                               const float* __restrict__ ln1g, const float* __restrict__ ln1b,
                                               const u16* __restrict__ w1T, const float* __restrict__ b1,
                                               const u16* __restrict__ w2T, const float* __restrict__ b2,
                                               const float* __restrict__ ln2g, const float* __restrict__ ln2b,
                                               float* __restrict__ x, u16* __restrict__ xbout) {
    __shared__ __align__(16) char smem[73728];
    u16* Alds = (u16*)smem;
    u16* Wlds = (u16*)(smem + 8192);
    u16* f1   = (u16*)(smem + 40960);
    float* vbuf = (float*)smem;
    int tid = threadIdx.x, wid = tid >> 6, lane = tid & 63;
    int rows0 = blockIdx.x * 32;
    int rA = lane & 15, kq = lane >> 4;
    int row = tid >> 3, sub = tid & 7;

#pragma unroll
    for (int j = 0; j < 2; ++j) {
        int srow = wid * 8 + j * 4 + (lane >> 4);
        int win = (lane >> 3) & 1, slot = lane & 7;
        gload16(atto + (size_t)(rows0 + srow) * 128 + win * 64 + ((slot ^ (srow & 7)) << 3),
                Alds + (wid * 8 + j * 4) * 128);
    }
    f32x4 accw[2][2] = {};
    for (int k0 = 0; k0 < 128; k0 += 64) {
        __syncthreads();
#pragma unroll
        for (int i = 0; i < 4; ++i) {
            int rl2 = i * 32 + wid * 8 + (lane >> 3);
            gload16(woT + (size_t)rl2 * 128 + k0 + (((lane & 7) ^ (rl2 & 7)) << 3),
                    Wlds + (i * 32 + wid * 8) * 64);
        }
        __syncthreads();
#pragma unroll
        for (int ks = 0; ks < 2; ++ks) {
            int sw = ((ks * 4 + kq) ^ (rA & 7)) << 3;
            short8 af0 = *(const short8*)&Alds[rA * 128 + k0 + sw];
            short8 af1 = *(const short8*)&Alds[(16 + rA) * 128 + k0 + sw];
            short8 bf0 = *(const short8*)&Wlds[(wid * 32 + rA) * 64 + sw];
            short8 bf1 = *(const short8*)&Wlds[(wid * 32 + 16 + rA) * 64 + sw];
            accw[0][0] = __builtin_amdgcn_mfma_f32_16x16x32_bf16(af0, bf0, accw[0][0], 0, 0, 0);
            accw[0][1] = __builtin_amdgcn_mfma_f32_16x16x32_bf16(af0, bf1, accw[0][1], 0, 0, 0);
            accw[1][0] = __builtin_amdgcn_mfma_f32_16x16x32_bf16(af1, bf0, accw[1][0], 0, 0, 0);
            accw[1][1] = __builtin_amdgcn_mfma_f32_16x16x32_bf16(af1, bf1, accw[1][1], 0, 0, 0);
        }
    }
    __syncthreads();
#pragma unroll
    for (int m = 0; m < 2; ++m)
#pragma unroll
        for (int n = 0; n < 2; ++n) {
            int cc = wid * 32 + n * 16 + rA;
            float bv = bo[cc];
#pragma unroll
            for (int r = 0; r < 4; ++r) {
                int rl = m * 16 + kq * 4 + r;
                vbuf[rl * 133 + cc] = accw[m][n][r] + bv + x[(size_t)(rows0 + rl) * 128 + cc];
            }
        }
    __syncthreads();
    float x1[16];
    {
        const float* vr = vbuf + row * 133 + sub * 16;
        float s = 0.f, s2 = 0.f;
#pragma unroll
        for (int j = 0; j < 16; ++j) {
            x1[j] = vr[j];
            s += x1[j];
            s2 += x1[j] * x1[j];
        }
        s += __shfl_xor(s, 1, 64);  s2 += __shfl_xor(s2, 1, 64);
        s += __shfl_xor(s, 2, 64);  s2 += __shfl_xor(s2, 2, 64);
        s += __shfl_xor(s, 4, 64);  s2 += __shfl_xor(s2, 4, 64);
        float mean = s * (1.f / 128.f);
        float var = s2 * (1.f / 128.f) - mean * mean;
        float rs = rsqrtf(var + 1e-5f);
#pragma unroll
        for (int j = 0; j < 4; ++j) {
            float4 gv = *(const float4*)(ln1g + sub * 16 + j * 4);
            float4 bv = *(const float4*)(ln1b + sub * 16 + j * 4);
            x1[j * 4 + 0] = (x1[j * 4 + 0] - mean) * rs * gv.x + bv.x;
            x1[j * 4 + 1] = (x1[j * 4 + 1] - mean) * rs * gv.y + bv.y;
            x1[j * 4 + 2] = (x1[j * 4 + 2] - mean) * rs * gv.z + bv.z;
            x1[j * 4 + 3] = (x1[j * 4 + 3] - mean) * rs * gv.w + bv.w;
        }
    }
    __syncthreads();
#pragma unroll
    for (int j = 0; j < 16; ++j) {
        int c = sub * 16 + j;
        int scol = (c & ~63) | ((((c >> 3) & 7) ^ (row & 7)) << 3) | (c & 7);
        Alds[row * 128 + scol] = f2b(x1[j]);
    }
    for (int nh = 0; nh < 2; ++nh) {
        f32x4 acc1[2][4] = {};
        for (int k0 = 0; k0 < 128; k0 += 64) {
            __syncthreads();
#pragma unroll
            for (int i = 0; i < 8; ++i) {
                int rl2 = i * 32 + wid * 8 + (lane >> 3);
                gload16(w1T + (size_t)(nh * 256 + rl2) * 128 + k0 + (((lane & 7) ^ (rl2 & 7)) << 3),
                        Wlds + (i * 32 + wid * 8) * 64);
            }
            __syncthreads();
#pragma unroll
            for (int ks = 0; ks < 2; ++ks) {
                int sw = ((ks * 4 + kq) ^ (rA & 7)) << 3;
                short8 af[2], bf4[4];
                af[0] = *(const short8*)&Alds[rA * 128 + k0 + sw];
                af[1] = *(const short8*)&Alds[(16 + rA) * 128 + k0 + sw];
#pragma unroll
                for (int n = 0; n < 4; ++n)
                    bf4[n] = *(const short8*)&Wlds[(wid * 64 + n * 16 + rA) * 64 + sw];
#pragma unroll
                for (int m = 0; m < 2; ++m)
#pragma unroll
                    for (int n = 0; n < 4; ++n)
                        acc1[m][n] = __builtin_amdgcn_mfma_f32_16x16x32_bf16(af[m], bf4[n], acc1[m][n], 0, 0, 0);
            }
        }
#pragma unroll
        for (int m = 0; m < 2; ++m)
#pragma unroll
            for (int n = 0; n < 4; ++n) {
                int cc = nh * 256 + wid * 64 + n * 16 + rA;
                float bv = b1[cc];
#pragma unroll
                for (int r = 0; r < 4; ++r) {
                    int rl = m * 16 + kq * 4 + r;
                    float v = fmaxf(acc1[m][n][r] + bv, 0.f);
                    int scol = (cc & ~63) | (((((cc >> 3) & 7) ^ (rl & 7)) & 7) << 3) | (cc & 7);
                    f1[rl * 512 + scol] = f2b(v);
                }
            }
    }
    __syncthreads();
    f32x4 acc2[2][2] = {};
    for (int k0 = 0; k0 < 512; k0 += 64) {
        if (k0) __syncthreads();
#pragma unroll
        for (int i = 0; i < 4; ++i) {
            int rl2 = i * 32 + wid * 8 + (lane >> 3);
            gload16(w2T + (size_t)rl2 * 512 + k0 + (((lane & 7) ^ (rl2 & 7)) << 3),
                    Wlds + (i * 32 + wid * 8) * 64);
        }
        __syncthreads();
#pragma unroll
        for (int ks = 0; ks < 2; ++ks) {
            int sw = ((ks * 4 + kq) ^ (rA & 7)) << 3;
            short8 af0 = *(const short8*)&f1[rA * 512 + k0 + sw];
            short8 af1 = *(const short8*)&f1[(16 + rA) * 512 + k0 + sw];
            short8 bf0 = *(const short8*)&Wlds[(wid * 32 + rA) * 64 + sw];
            short8 bf1 = *(const short8*)&Wlds[(wid * 32 + 16 + rA) * 64 + sw];
            acc2[0][0] = __builtin_amdgcn_mfma_f32_16x16x32_bf16(af0, bf0, acc2[0][0], 0, 0, 0);
            acc2[0][1] = __builtin_amdgcn_mfma_f32_16x16x32_bf16(af0, bf1, acc2[0][1], 0, 0, 0);
            acc2[1][0] = __builtin_amdgcn_mfma_f32_16x16x32_bf16(af1, bf0, acc2[1][0], 0, 0, 0);
            acc2[1][1] = __builtin_amdgcn_mfma_f32_16x16x32_bf16(af1, bf1, acc2[1][1], 0, 0, 0);
        }
    }
    __syncthreads();
#pragma unroll
    for (int m = 0; m < 2; ++m)
#pragma unroll
        for (int n = 0; n < 2; ++n) {
            int cc = wid * 32 + n * 16 + rA;
            float bv = b2[cc];
#pragma unroll
            for (int r = 0; r < 4; ++r) {
                int rl = m * 16 + kq * 4 + r;
                vbuf[rl * 133 + cc] = acc2[m][n][r] + bv;
            }
        }
    __syncthreads();
    {
        const float* vr = vbuf + row * 133 + sub * 16;
        float vv[16];
        float s = 0.f, s2 = 0.f;
#pragma unroll
        for (int j = 0; j < 16; ++j) {
            vv[j] = vr[j] + x1[j];
            s += vv[j];
            s2 += vv[j] * vv[j];
        }
        s += __shfl_xor(s, 1, 64);  s2 += __shfl_xor(s2, 1, 64);
        s += __shfl_xor(s, 2, 64);  s2 += __shfl_xor(s2, 2, 64);
        s += __shfl_xor(s, 4, 64);  s2 += __shfl_xor(s2, 4, 64);
        float mean = s * (1.f / 128.f);
        float var = s2 * (1.f / 128.f) - mean * mean;
        float rs = rsqrtf(var + 1e-5f);
        int grow = rows0 + row;
        float* xrow = x + (size_t)grow * 128 + sub * 16;
        u16* xbrow = xbout + (size_t)grow * 128 + sub * 16;
#pragma unroll
        for (int j = 0; j < 4; ++j) {
            float4 gv = *(const float4*)(ln2g + sub * 16 + j * 4);
            float4 bv = *(const float4*)(ln2b + sub * 16 + j * 4);
            float o0 = (vv[j * 4 + 0] - mean) * rs * gv.x + bv.x;
            float o1 = (vv[j * 4 + 1] - mean) * rs * gv.y + bv.y;
            float o2 = (vv[j * 4 + 2] - mean) * rs * gv.z + bv.z;
            float o3 = (vv[j * 4 + 3] - mean) * rs * gv.w + bv.w;
            *(float4*)(xrow + j * 4) = make_float4(o0, o1, o2, o3);
            *(ushort4*)(xbrow + j * 4) = make_ushort4(f2b(o0), f2b(o1), f2b(o2), f2b(o3));
        }
    }
}

// ===================== fusion + positional encoding =====================
__global__ __launch_bounds__(256) void k_fusion(const float* __restrict__ spe, const int* __restrict__ traj,
                                                const float* __restrict__ ue_tab, const int* __restrict__ uid,
                                                const float* __restrict__ tempx, const int* __restrict__ hwx,
                                                const float* __restrict__ ce_tab, const float* __restrict__ flw,
                                                const float* __restrict__ flb, float* __restrict__ x,
                                                u16* __restrict__ xb) {
    __shared__ float Ws[22 * D_];
    __shared__ float bs[D_];
    __shared__ float ins[2][22];
    int tid = threadIdx.x;
    for (int i = tid; i < 22 * D_; i += 256) Ws[i] = flw[i];
    if (tid < D_) bs[tid] = flb[tid];
    __syncthreads();
    int ro = tid >> 7, d = tid & 127;
    int base = blockIdx.x * 32;
    for (int ir = 0; ir < 16; ++ir) {
        int tok = base + ir * 2 + ro;
        int b = tok >> 8, s = tok & 255;
        if (d < TD_) ins[ro][d] = tempx[(size_t)tok * TD_ + d];
        else if (d < 22) ins[ro][d] = ce_tab[(size_t)hwx[tok] * CED_ + (d - TD_)];
        __syncthreads();
        float acc = bs[d];
#pragma unroll
        for (int k = 0; k < 22; ++k) acc = fmaf(ins[ro][k], Ws[k * D_ + d], acc);
        acc = fmaxf(acc, 0.f);
        int i2 = d & ~1;
        float ang = (float)s * __expf(-(float)i2 * 0.0719557841560639f);
        float pe = (d & 1) ? cosf(ang) : sinf(ang);
        float v = spe[(size_t)traj[tok] * D_ + d] + ue_tab[(size_t)uid[b] * D_ + d] + acc + pe;
        x[(size_t)tok * D_ + d] = v;
        xb[(size_t)tok * D_ + d] = f2b(v);
        __syncthreads();
    }
}

// ===================== launch =====================
extern "C" void kernel_launch(void* const* d_in, const int* in_sizes, int n_in,
                              void* d_out, int out_size, void* d_ws, size_t ws_size,
                              hipStream_t stream) {
    const float* node_feature = (const float*)d_in[0];
    const int*   edge_index   = (const int*)d_in[1];
    const int*   traj_x       = (const int*)d_in[2];
    const float* temporal_x   = (const float*)d_in[3];
    const int*   user_id_x    = (const int*)d_in[4];
    const int*   mask         = (const int*)d_in[5];
    const int*   end_idx      = (const int*)d_in[6];
    const float* tmat         = (const float*)d_in[8];
    const float* dmat         = (const float*)d_in[9];
    const int*   highway_x    = (const int*)d_in[10];
    const float* lambda2      = (const float*)d_in[11];
    const float* gnn_w1       = (const float*)d_in[12];
    const float* gnn_b1       = (const float*)d_in[13];
    const float* gnn_w2       = (const float*)d_in[14];
    const float* gnn_b2       = (const float*)d_in[15];
    const float* ue_tab       = (const float*)d_in[16];
    const float* ce_tab       = (const float*)d_in[17];
    const float* fl_w         = (const float*)d_in[18];
    const float* fl_b         = (const float*)d_in[19];
    const float* wqkv         = (const float*)d_in[20];
    const float* bqkv         = (const float*)d_in[21];
    const float* wo           = (const float*)d_in[22];
    const float* bo           = (const float*)d_in[23];
    const float* ln1_g        = (const float*)d_in[24];
    const float* ln1_b        = (const float*)d_in[25];
    const float* ln2_g        = (const float*)d_in[26];
    const float* ln2_b        = (const float*)d_in[27];
    const float* ffn_w1       = (const float*)d_in[28];
    const float* ffn_b1       = (const float*)d_in[29];
    const float* ffn_w2       = (const float*)d_in[30];
    const float* ffn_b2       = (const float*)d_in[31];
    const float* head_w       = (const float*)d_in[32];
    const float* head_b       = (const float*)d_in[33];
    float* out = (float*)d_out;

    // ---- workspace layout (float units), round-10 proven ----
    float* w     = (float*)d_ws;
    int*   cnt   = (int*)w;                  // [0, 40,960)
    float* spe   = w + 40960;                // [40,960, 5,169,152)
    u16*   biasb = (u16*)(w + 5169152);      // [5,169,152, 7,266,304)
    float* wreg  = w + 7266304;              // bf16 weights -> ends 7,999,488
    u16* wqkvT = (u16*)wreg;
    u16* woT   = wqkvT + 4 * 384 * 128;
    u16* w1T   = woT + 4 * 128 * 128;
    u16* w2T   = w1T + 4 * 512 * 128;
    u16* gw1T  = w2T + 4 * 128 * 512;
    u16* gw2T  = gw1T + 128 * 64;
    u16* hwT   = gw2T + 128 * 128;
    float* pool  = w + 8000000;
    // GNN phase
    u16*   h1b   = (u16*)pool;               // [0, 2,564,096) f
    u16*   in1b  = (u16*)(pool + 2564096);   // [2,564,096, 3,846,144)
    u16*   in2b  = (u16*)(pool + 3846144);   // [3,846,144, 6,410,240)
    int*   off   = (int*)(pool + 6410240);
    int*   cursor= (int*)(pool + 6450304);
    int*   ebuf  = (int*)(pool + 6490368);
    // transformer phase (GNN fully done before fusion)
    float* x     = pool;                     // [0, 2,097,152)
    u16*   xb    = (u16*)(pool + 2097152);   // [2,097,152, 2,621,440)
    u16*   attob = (u16*)(pool + 4718592);   // [4,718,592, 5,242,880)

    const int* esrc = edge_index;
    const int* edst = edge_index + E_;

    // ---- uber prep ----
    UberArgs ua;
    const float* srcs[7] = {wqkv, wo, ffn_w1, ffn_w2, gnn_w1, gnn_w2, head_w};
    u16* dsts[7]        = {wqkvT, woT, w1T, w2T, gw1T, gw2T, hwT};
    int Ks[7]    = {128, 128, 128, 512, 32, 128, 128};
    int Npads[7] = {384, 128, 512, 128, 128, 128, UP_};
    int Nsrcs[7] = {384, 128, 512, 128, 128, 128, U_};
    int Kps[7]   = {128, 128, 128, 512, 64, 128, 128};
    int Ls[7]    = {4, 4, 4, 4, 1, 1, 1};
    int bb = UB_CNT_END;
    for (int t = 0; t < 7; ++t) {
        ua.csrc[t] = srcs[t]; ua.cdst[t] = dsts[t];
        ua.K[t] = Ks[t]; ua.Npad[t] = Npads[t]; ua.Nsrc[t] = Nsrcs[t]; ua.Kp[t] = Kps[t];
        ua.base[t] = bb;
        bb += (Npads[t] / 32) * (Kps[t] / 32) * Ls[t];
    }
    ua.tm = tmat; ua.dm = dmat; ua.maskp = mask; ua.lambda2 = lambda2;
    ua.bias = biasb; ua.cnt = cnt;
    k_uber<<<UB_TOTAL, 256, 0, stream>>>(ua);

    // ---- GNN: CSR build + gathers + GEMMs ----
    k_count<<<(E_ + 255) / 256, 256, 0, stream>>>(edst, cnt);
    k_scan<<<NSCB, 256, 0, stream>>>(cnt, off, cursor);
    k_fill<<<(E_ + 255) / 256, 256, 0, stream>>>(esrc, edst, cursor, ebuf);
    k_gprep1<<<NP_ / 8, 256, 0, stream>>>(node_feature, off, cnt, ebuf, in1b);
    k_mgemm<128, 1, 1, 0><<<dim3(NP_ / 128, 1), 256, 0, stream>>>(in1b, gw1T, gnn_b1, h1b, nullptr, NP_, D_, 64);
    k_gprep2<<<NP_ / 4, 256, 0, stream>>>(h1b, off, cnt, ebuf, in2b);
    k_mgemm<128, 1, 0, 0><<<dim3(NP_ / 128, 1), 256, 0, stream>>>(in2b, gw2T, gnn_b2, spe, nullptr, NP_, D_, D_);

    // ---- fusion ----
    k_fusion<<<(B_ * S_) / 32, 256, 0, stream>>>(spe, traj_x, ue_tab, user_id_x,
                                                 temporal_x, highway_x, ce_tab, fl_w, fl_b, x, xb);

    // ---- transformer: 2 kernels per layer ----
    const int M = B_ * S_;
    for (int l = 0; l < L_; ++l) {
        k_qkvatt<<<B_ * H_, 256, 0, stream>>>(xb, wqkvT + (size_t)l * 384 * 128,
                                              bqkv + (size_t)l * 384, biasb, attob);
        k_layer<<<M / 32, 256, 0, stream>>>(attob, woT + (size_t)l * 128 * 128, bo + l * D_,
                                            ln1_g + l * D_, ln1_b + l * D_,
                                            w1T + (size_t)l * 512 * 128, ffn_b1 + l * FF_,
                                            w2T + (size_t)l * 128 * 512, ffn_b2 + l * D_,
                                            ln2_g + l * D_, ln2_b + l * D_, x, xb);
    }

    // ---- head (gather fused) ----
    k_mgemm<64, 0, 0, 1><<<dim3(1, UP_ / 128), 256, 0, stream>>>(xb, hwT, head_b, out, end_idx, B_, U_, D_);
}

// Round 16
// 302.404 us; speedup vs baseline: 3.8417x; 1.0584x over previous
//
#include <hip/hip_runtime.h>
#include <hip/hip_fp16.h>
#include <cstdint>
#include <cstddef>

typedef unsigned short u16;
typedef __attribute__((ext_vector_type(8))) short short8;
typedef __attribute__((ext_vector_type(4))) float f32x4;

// ---- problem constants ----
#define B_   64
#define S_   256
#define D_   128
#define H_   8
#define FF_  512
#define L_   4
#define U_   5000
#define UP_  5120
#define N_   40000
#define NP_  40064
#define E_   160000
#define FEA_ 32
#define CED_ 16
#define TD_  6
#define NSCB 157
#define UB_CNT_END 160
#define UB_CVT_END 1592
#define UB_TOTAL   5688
#define KLS 40
#define VTS 272

static __device__ __forceinline__ u16 f2b(float f) {
    unsigned int u = __float_as_uint(f);
    unsigned int r = (u + 0x7FFFu + ((u >> 16) & 1u)) >> 16;
    return (u16)r;
}
static __device__ __forceinline__ float b2f(u16 u) {
    return __uint_as_float(((unsigned int)u) << 16);
}
static __device__ __forceinline__ u16 f2h(float f) {
    return __half_as_ushort(__float2half(f));
}
static __device__ __forceinline__ float h2f(u16 u) {
    return __half2float(__ushort_as_half(u));
}
static __device__ __forceinline__ void gload16(const void* g, void* l) {
    __builtin_amdgcn_global_load_lds(
        (const __attribute__((address_space(1))) unsigned int*)g,
        (__attribute__((address_space(3))) unsigned int*)l,
        16, 0, 0);
}

// ===================== uber prep: cnt-zero + 7 weight transposes + attn bias =====================
struct UberArgs {
    const float* csrc[7];
    u16* cdst[7];
    int K[7], Npad[7], Nsrc[7], Kp[7], base[7];
    const float* tm; const float* dm; const int* maskp; const float* lambda2;
    u16* bias; int* cnt;
};

__global__ __launch_bounds__(256) void k_uber(UberArgs a) {
    __shared__ float tile[32][33];
    int bid = blockIdx.x, tid = threadIdx.x;
    if (bid < UB_CNT_END) {
        int idx = bid * 256 + tid;
        if (idx < NP_) a.cnt[idx] = 0;
        return;
    }
    if (bid < UB_CVT_END) {
        int t = 0;
#pragma unroll
        for (int i = 1; i < 7; ++i) t += (bid >= a.base[i]);
        int rb = bid - a.base[t];
        int K = a.K[t], Npad = a.Npad[t], Nsrc = a.Nsrc[t], Kp = a.Kp[t];
        int nbn = Npad >> 5, nbk = Kp >> 5;
        int per = nbn * nbk;
        int l = rb / per, rem = rb - l * per;
        int n0 = (rem % nbn) * 32, k0 = (rem / nbn) * 32;
        const float* in = a.csrc[t];
        u16* outp = a.cdst[t];
        int j = tid & 31, i2 = tid >> 5;
#pragma unroll
        for (int r = 0; r < 4; ++r) {
            int k = k0 + i2 + r * 8, n = n0 + j;
            tile[i2 + r * 8][j] = (k < K && n < Nsrc) ? in[(size_t)l * K * Nsrc + (size_t)k * Nsrc + n] : 0.f;
        }
        __syncthreads();
#pragma unroll
        for (int r = 0; r < 4; ++r) {
            int n = n0 + i2 + r * 8, k = k0 + j;
            if (n < Npad && k < Kp)
                outp[(size_t)l * Npad * Kp + (size_t)n * Kp + k] = f2b(tile[j][i2 + r * 8]);
        }
        return;
    }
    int t4 = (bid - UB_CVT_END) * 256 + tid;
    const int total = B_ * S_ * S_ / 4;
    if (t4 >= total) return;
    float l2 = *a.lambda2, l2c = 1.f - l2;
    float4 av = ((const float4*)a.tm)[t4];
    float4 bv = ((const float4*)a.dm)[t4];
    int basei = t4 * 4;
    int bb = basei >> 16;
    int k0 = basei & 255;
    const int* mrow = a.maskp + bb * S_;
    float r0 = (mrow[k0 + 0] > 0 ? 0.f : -30000.f) - (l2 * __logf(1.f + av.x) + l2c * __logf(1.f + bv.x));
    float r1 = (mrow[k0 + 1] > 0 ? 0.f : -30000.f) - (l2 * __logf(1.f + av.y) + l2c * __logf(1.f + bv.y));
    float r2 = (mrow[k0 + 2] > 0 ? 0.f : -30000.f) - (l2 * __logf(1.f + av.z) + l2c * __logf(1.f + bv.z));
    float r3 = (mrow[k0 + 3] > 0 ? 0.f : -30000.f) - (l2 * __logf(1.f + av.w) + l2c * __logf(1.f + bv.w));
    *(ushort4*)&a.bias[(size_t)t4 * 4] = make_ushort4(f2h(r0), f2h(r1), f2h(r2), f2h(r3));
}

// ===================== CSR build =====================
__global__ __launch_bounds__(256) void k_count(const int* __restrict__ dst, int* __restrict__ cnt) {
    int e = blockIdx.x * 256 + threadIdx.x;
    if (e < E_) atomicAdd(&cnt[dst[e]], 1);
}

__global__ __launch_bounds__(256) void k_scanA(const int* __restrict__ cnt, int* __restrict__ part) {
    __shared__ int sh[256];
    int idx = blockIdx.x * 256 + threadIdx.x;
    sh[threadIdx.x] = (idx < NP_) ? cnt[idx] : 0;
    __syncthreads();
    for (int o = 128; o > 0; o >>= 1) {
        if (threadIdx.x < o) sh[threadIdx.x] += sh[threadIdx.x + o];
        __syncthreads();
    }
    if (threadIdx.x == 0) part[blockIdx.x] = sh[0];
}

__global__ __launch_bounds__(256) void k_scanB(const int* __restrict__ cnt, const int* __restrict__ part,
                                               int* __restrict__ off, int* __restrict__ cursor) {
    __shared__ int sh[256];
    __shared__ int bsum;
    int tid = threadIdx.x;
    int pv = (tid < blockIdx.x) ? part[tid] : 0;
    sh[tid] = pv;
    __syncthreads();
    for (int o = 128; o > 0; o >>= 1) {
        if (tid < o) sh[tid] += sh[tid + o];
        __syncthreads();
    }
    if (tid == 0) bsum = sh[0];
    __syncthreads();
    int basev = bsum;
    __syncthreads();
    int idx = blockIdx.x * 256 + tid;
    int v = (idx < NP_) ? cnt[idx] : 0;
    sh[tid] = v;
    __syncthreads();
    for (int o = 1; o < 256; o <<= 1) {
        int t2 = (tid >= o) ? sh[tid - o] : 0;
        __syncthreads();
        sh[tid] += t2;
        __syncthreads();
    }
    if (idx < NP_) {
        int res = sh[tid] - v + basev;
        off[idx] = res;
        cursor[idx] = res;
    }
}

__global__ __launch_bounds__(256) void k_fill(const int* __restrict__ src, const int* __restrict__ dst,
                                              int* __restrict__ cursor, int* __restrict__ ebuf) {
    int e = blockIdx.x * 256 + threadIdx.x;
    if (e >= E_) return;
    int p = atomicAdd(&cursor[dst[e]], 1);
    ebuf[p] = src[e];
}

// ===================== GNN gather+prep =====================
__global__ __launch_bounds__(256) void k_gprep1(const float* __restrict__ nf, const int* __restrict__ off,
                                                const int* __restrict__ cnt, const int* __restrict__ ebuf,
                                                u16* __restrict__ out) {
    int n = blockIdx.x * 8 + (threadIdx.x >> 5);
    int f = threadIdx.x & 31;
    u16 r = 0;
    if (n < N_) {
        int start = off[n], c = cnt[n];
        float acc = 0.f;
        int i = 0;
        for (; i + 4 <= c; i += 4) {
            int s0 = ebuf[start + i], s1 = ebuf[start + i + 1];
            int s2 = ebuf[start + i + 2], s3 = ebuf[start + i + 3];
            float v0 = nf[(size_t)s0 * FEA_ + f];
            float v1 = nf[(size_t)s1 * FEA_ + f];
            float v2 = nf[(size_t)s2 * FEA_ + f];
            float v3 = nf[(size_t)s3 * FEA_ + f];
            acc += (v0 + v1) + (v2 + v3);
        }
        for (; i < c; ++i) acc += nf[(size_t)ebuf[start + i] * FEA_ + f];
        r = f2b(nf[(size_t)n * FEA_ + f] + acc / (float)(c + 1));
    }
    if (n < NP_) {
        out[(size_t)n * 64 + f] = r;
        out[(size_t)n * 64 + 32 + f] = 0;
    }
}

__global__ __launch_bounds__(256) void k_gprep2(const u16* __restrict__ h1b, const int* __restrict__ off,
                                                const int* __restrict__ cnt, const int* __restrict__ ebuf,
                                                u16* __restrict__ out) {
    int n = blockIdx.x * 4 + (threadIdx.x >> 6);
    int d2 = (threadIdx.x & 63) * 2;
    if (n >= NP_) return;
    u16 r0 = 0, r1 = 0;
    if (n < N_) {
        int start = off[n], c = cnt[n];
        float a0 = 0.f, a1 = 0.f;
        int i = 0;
        for (; i + 4 <= c; i += 4) {
            int s0 = ebuf[start + i], s1 = ebuf[start + i + 1];
            int s2 = ebuf[start + i + 2], s3 = ebuf[start + i + 3];
            ushort2 v0 = *(const ushort2*)&h1b[(size_t)s0 * D_ + d2];
            ushort2 v1 = *(const ushort2*)&h1b[(size_t)s1 * D_ + d2];
            ushort2 v2 = *(const ushort2*)&h1b[(size_t)s2 * D_ + d2];
            ushort2 v3 = *(const ushort2*)&h1b[(size_t)s3 * D_ + d2];
            a0 += (b2f(v0.x) + b2f(v1.x)) + (b2f(v2.x) + b2f(v3.x));
            a1 += (b2f(v0.y) + b2f(v1.y)) + (b2f(v2.y) + b2f(v3.y));
        }
        for (; i < c; ++i) {
            ushort2 v = *(const ushort2*)&h1b[(size_t)ebuf[start + i] * D_ + d2];
            a0 += b2f(v.x); a1 += b2f(v.y);
        }
        float rinv = 1.f / (float)(c + 1);
        ushort2 sv = *(const ushort2*)&h1b[(size_t)n * D_ + d2];
        r0 = f2b(b2f(sv.x) + a0 * rinv);
        r1 = f2b(b2f(sv.y) + a1 * rinv);
    }
    *(ushort2*)&out[(size_t)n * D_ + d2] = make_ushort2(r0, r1);
}

// ===================== MFMA GEMM (BM 64/128, opt gathered A) =====================
template<int BM, int ACT, int OUTB, int GAT>
__global__ __launch_bounds__(256) void k_mgemm(const u16* __restrict__ A, const u16* __restrict__ BT,
                                               const float* __restrict__ bias, void* __restrict__ Cout,
                                               const int* __restrict__ endi, int M, int N, int K) {
    constexpr int SMEMB = (BM == 128) ? 32768 : 24576;
    __shared__ __align__(16) char smem[SMEMB];
    u16* Al = (u16*)smem;
    u16* Bl = Al + (BM == 128 ? 128 * 64 : 64 * 64);
    int tid = threadIdx.x;
    int wid = tid >> 6, lane = tid & 63;
    int row0 = blockIdx.x * BM;
    int col0 = blockIdx.y * 128;
    f32x4 acc[4][4] = {};
    int rA = lane & 15, kq = lane >> 4;

    for (int k0 = 0; k0 < K; k0 += 64) {
        if (k0) __syncthreads();
        if (BM == 128) {
            int srow = wid * 32 + (lane >> 3);
            int ks8 = ((lane & 7) ^ (lane >> 3)) * 8;
#pragma unroll
            for (int i = 0; i < 4; ++i) {
                int row = srow + i * 8;
                size_t arow = (size_t)(row0 + row);
                if (GAT) {
                    int bb2 = row0 + row;
                    arow = (bb2 < B_) ? ((size_t)bb2 * S_ + endi[bb2]) : 0;
                }
                gload16(A + arow * K + k0 + ks8, &Al[(wid * 32 + i * 8) * 64]);
                gload16(BT + (size_t)(col0 + row) * K + k0 + ks8, &Bl[(wid * 32 + i * 8) * 64]);
            }
        } else {
#pragma unroll
            for (int i = 0; i < 6; ++i) {
                int c = wid * 6 + i;
                int rr = c * 8 + (lane >> 3);
                int sl = (((lane & 7) ^ (rr & 7)) << 3);
                if (c < 8) {
                    size_t arow = (size_t)(row0 + rr);
                    if (GAT) {
                        int bb2 = row0 + rr;
                        arow = (bb2 < B_) ? ((size_t)bb2 * S_ + endi[bb2]) : 0;
                    }
                    gload16(A + arow * K + k0 + sl, &Al[rr * 64]);
                } else {
                    gload16(BT + (size_t)(col0 + rr - 64) * K + k0 + sl, &Bl[(rr - 64) * 64]);
                }
            }
        }
        __syncthreads();
#pragma unroll
        for (int ks = 0; ks < 2; ++ks) {
            int sw = ((ks * 4 + kq) ^ (rA & 7)) * 8;
            if (BM == 128) {
                int wr = wid >> 1, wc = wid & 1;
                short8 af[4], bfr[4];
#pragma unroll
                for (int m = 0; m < 4; ++m)
                    af[m] = *(const short8*)&Al[(64 * wr + m * 16 + rA) * 64 + sw];
#pragma unroll
                for (int n = 0; n < 4; ++n)
                    bfr[n] = *(const short8*)&Bl[(64 * wc + n * 16 + rA) * 64 + sw];
#pragma unroll
                for (int m = 0; m < 4; ++m)
#pragma unroll
                    for (int n = 0; n < 4; ++n)
                        acc[m][n] = __builtin_amdgcn_mfma_f32_16x16x32_bf16(af[m], bfr[n], acc[m][n], 0, 0, 0);
            } else {
                int wr2 = wid & 1, wc2 = wid >> 1;
                short8 af[2], bfr[4];
#pragma unroll
                for (int m = 0; m < 2; ++m)
                    af[m] = *(const short8*)&Al[(wr2 * 32 + m * 16 + rA) * 64 + sw];
#pragma unroll
                for (int n = 0; n < 4; ++n)
                    bfr[n] = *(const short8*)&Bl[(wc2 * 64 + n * 16 + rA) * 64 + sw];
#pragma unroll
                for (int m = 0; m < 2; ++m)
#pragma unroll
                    for (int n = 0; n < 4; ++n)
                        acc[m][n] = __builtin_amdgcn_mfma_f32_16x16x32_bf16(af[m], bfr[n], acc[m][n], 0, 0, 0);
            }
        }
    }

    constexpr int MR = (BM == 128) ? 4 : 2;
#pragma unroll
    for (int m = 0; m < MR; ++m) {
#pragma unroll
        for (int n = 0; n < 4; ++n) {
            int cc, cr0;
            if (BM == 128) { cc = col0 + (wid & 1) * 64 + n * 16 + rA; cr0 = row0 + (wid >> 1) * 64 + m * 16 + kq * 4; }
            else           { cc = col0 + (wid >> 1) * 64 + n * 16 + rA; cr0 = row0 + (wid & 1) * 32 + m * 16 + kq * 4; }
            if (cc >= N) continue;
            float bv = bias[cc];
#pragma unroll
            for (int r = 0; r < 4; ++r) {
                int cr = cr0 + r;
                if (cr >= M) continue;
                float v = acc[m][n][r] + bv;
                if (ACT) v = fmaxf(v, 0.f);
                if (OUTB) ((u16*)Cout)[(size_t)cr * N + cc] = f2b(v);
                else      ((float*)Cout)[(size_t)cr * N + cc] = v;
            }
        }
    }
}

// ===================== fused QKV-proj + flash attention =====================
__global__ __launch_bounds__(256) void k_qkvatt(const u16* __restrict__ xb, const u16* __restrict__ wT,
                                                const float* __restrict__ bq, const u16* __restrict__ bias,
                                                u16* __restrict__ o) {
    __shared__ __align__(16) char smem[73728];
    u16* Kl  = (u16*)smem;
    u16* Vt  = (u16*)(smem + 20480);
    u16* Ql  = (u16*)(smem + 29184);
    u16* Pl  = (u16*)(smem + 37376);
    u16* Ast = (u16*)smem;
    u16* Bst = (u16*)(smem + 32768);
    int idx = blockIdx.x;
    int b = (idx & 7) * 8 + (idx >> 6);
    int h = (idx >> 3) & 7;
    int tid = threadIdx.x, wid = tid >> 6, lane = tid & 63;
    int rA = lane & 15, kq = lane >> 4;

    f32x4 acc[4][3] = {};
    for (int k0 = 0; k0 < 128; k0 += 64) {
        if (k0) __syncthreads();
#pragma unroll
        for (int i = 0; i < 8; ++i) {
            int row = wid * 64 + i * 8 + (lane >> 3);
            int sl = (((lane & 7) ^ (row & 7)) << 3);
            gload16(xb + ((size_t)(b * S_ + row)) * 128 + k0 + sl, &Ast[(wid * 64 + i * 8) * 64]);
        }
        if (wid < 3) {
#pragma unroll
            for (int i = 0; i < 2; ++i) {
                int c = wid * 2 + i;
                int brow = c * 8 + (lane >> 3);
                int grow = wid * 128 + h * 16 + (brow & 15);
                int sl = (((lane & 7) ^ (brow & 7)) << 3);
                gload16(wT + (size_t)grow * 128 + k0 + sl, &Bst[c * 8 * 64]);
            }
        }
        __syncthreads();
#pragma unroll
        for (int ks = 0; ks < 2; ++ks) {
            int sw = ((ks * 4 + kq) ^ (rA & 7)) * 8;
            short8 af[4], bfr[3];
#pragma unroll
            for (int m = 0; m < 4; ++m)
                af[m] = *(const short8*)&Ast[(wid * 64 + m * 16 + rA) * 64 + sw];
#pragma unroll
            for (int n = 0; n < 3; ++n)
                bfr[n] = *(const short8*)&Bst[(n * 16 + rA) * 64 + sw];
#pragma unroll
            for (int m = 0; m < 4; ++m)
#pragma unroll
                for (int n = 0; n < 3; ++n)
                    acc[m][n] = __builtin_amdgcn_mfma_f32_16x16x32_bf16(af[m], bfr[n], acc[m][n], 0, 0, 0);
        }
    }
    __syncthreads();
    {
        short8 z = {};
        *(short8*)&Kl[tid * KLS + 16] = z;
        *(short8*)&Kl[tid * KLS + 24] = z;
    }
    {
        float bq0 = bq[h * 16 + rA];
        float bq1 = bq[128 + h * 16 + rA];
        float bq2 = bq[256 + h * 16 + rA];
#pragma unroll
        for (int m = 0; m < 4; ++m) {
            int cr0 = wid * 64 + m * 16 + kq * 4;
#pragma unroll
            for (int r = 0; r < 4; ++r) {
                int row = cr0 + r;
                Ql[row * 16 + rA]  = f2b(acc[m][0][r] + bq0);
                Kl[row * KLS + rA] = f2b(acc[m][1][r] + bq1);
                Vt[rA * VTS + row] = f2b(acc[m][2][r] + bq2);
            }
        }
    }
    __syncthreads();

    u16* pl = Pl + wid * 16 * VTS;
    int qi = lane & 15;
    for (int qt = 0; qt < 4; ++qt) {
        int q = wid * 64 + qt * 16 + qi;
        ushort4 bb[16];
        const u16* bp = bias + (size_t)b * (S_ * S_) + (size_t)q * S_ + kq * 4;
#pragma unroll
        for (int t = 0; t < 16; ++t) bb[t] = *(const ushort4*)(bp + t * 16);
        short8 qf = {};
        if (lane < 32)
            qf = *(const short8*)&Ql[q * 16 + kq * 8];
        f32x4 sc[16];
#pragma unroll
        for (int t = 0; t < 16; ++t) {
            short8 kf = *(const short8*)&Kl[(t * 16 + qi) * KLS + kq * 8];
            f32x4 zz = {0.f, 0.f, 0.f, 0.f};
            sc[t] = __builtin_amdgcn_mfma_f32_16x16x32_bf16(kf, qf, zz, 0, 0, 0);
        }
        float m = -1e30f;
#pragma unroll
        for (int t = 0; t < 16; ++t) {
            sc[t][0] = sc[t][0] * 0.25f + h2f(bb[t].x);
            sc[t][1] = sc[t][1] * 0.25f + h2f(bb[t].y);
            sc[t][2] = sc[t][2] * 0.25f + h2f(bb[t].z);
            sc[t][3] = sc[t][3] * 0.25f + h2f(bb[t].w);
            m = fmaxf(m, fmaxf(fmaxf(sc[t][0], sc[t][1]), fmaxf(sc[t][2], sc[t][3])));
        }
        m = fmaxf(m, __shfl_xor(m, 16, 64));
        m = fmaxf(m, __shfl_xor(m, 32, 64));
        float lsum = 0.f;
#pragma unroll
        for (int t = 0; t < 16; ++t) {
            sc[t][0] = __expf(sc[t][0] - m);
            sc[t][1] = __expf(sc[t][1] - m);
            sc[t][2] = __expf(sc[t][2] - m);
            sc[t][3] = __expf(sc[t][3] - m);
            lsum += (sc[t][0] + sc[t][1]) + (sc[t][2] + sc[t][3]);
        }
        lsum += __shfl_xor(lsum, 16, 64);
        lsum += __shfl_xor(lsum, 32, 64);
        float inv = 1.f / lsum;
#pragma unroll
        for (int t = 0; t < 16; ++t) {
            ushort4 pw = make_ushort4(f2b(sc[t][0] * inv), f2b(sc[t][1] * inv),
                                      f2b(sc[t][2] * inv), f2b(sc[t][3] * inv));
            *(ushort4*)&pl[qi * VTS + t * 16 + kq * 4] = pw;
        }
        f32x4 oa = {0.f, 0.f, 0.f, 0.f};
#pragma unroll
        for (int w8 = 0; w8 < 8; ++w8) {
            short8 vf = *(const short8*)&Vt[qi * VTS + w8 * 32 + kq * 8];
            short8 pf = *(const short8*)&pl[qi * VTS + w8 * 32 + kq * 8];
            oa = __builtin_amdgcn_mfma_f32_16x16x32_bf16(vf, pf, oa, 0, 0, 0);
        }
        ushort4 ow = make_ushort4(f2b(oa[0]), f2b(oa[1]), f2b(oa[2]), f2b(oa[3]));
        *(ushort4*)&o[((size_t)(b * S_ + q)) * D_ + h * 16 + kq * 4] = ow;
    }
}

// ===================== fused layer-tail: LN1(x + atto@wo + bo) -> FFN -> LN2 =====================
__global__ __launch_bounds__(256) void k_layer(const u16* __restrict__ atto,
                                               const u16* __restrict__ woT, const float* __restrict__ bo,
                                               const float* __restrict__ ln1g, const float* __restrict__ ln1b,
                                               const u16* __restrict__ w1T, const float* __restrict__ b1,
                                               const u16* __restrict__ w2T, const float* __restrict__ b2,
                                               const float* __restrict__ ln2g, const float* __restrict__ ln2b,
                                               float* __restrict__ x, u16* __restrict__ xbout) {
    __shared__ __align__(16) char smem[73728];
    u16* Alds = (u16*)smem;
    u16* Wlds = (u16*)(smem + 8192);
    u16* f1   = (u16*)(smem + 40960);
    float* vbuf = (float*)smem;
    int tid = threadIdx.x, wid = tid >> 6, lane = tid & 63;
    int rows0 = blockIdx.x * 32;
    int rA = lane & 15, kq = lane >> 4;
    int row = tid >> 3, sub = tid & 7;

#pragma unroll
    for (int j = 0; j < 2; ++j) {
        int srow = wid * 8 + j * 4 + (lane >> 4);
        int win = (lane >> 3) & 1, slot = lane & 7;
        gload16(atto + (size_t)(rows0 + srow) * 128 + win * 64 + ((slot ^ (srow & 7)) << 3),
                Alds + (wid * 8 + j * 4) * 128);
    }
    f32x4 accw[2][2] = {};
    for (int k0 = 0; k0 < 128; k0 += 64) {
        __syncthreads();
#pragma unroll
        for (int i = 0; i < 4; ++i) {
            int rl2 = i * 32 + wid * 8 + (lane >> 3);
            gload16(woT + (size_t)rl2 * 128 + k0 + (((lane & 7) ^ (rl2 & 7)) << 3),
                    Wlds + (i * 32 + wid * 8) * 64);
        }
        __syncthreads();
#pragma unroll
        for (int ks = 0; ks < 2; ++ks) {
            int sw = ((ks * 4 + kq) ^ (rA & 7)) << 3;
            short8 af0 = *(const short8*)&Alds[rA * 128 + k0 + sw];
            short8 af1 = *(const short8*)&Alds[(16 + rA) * 128 + k0 + sw];
            short8 bf0 = *(const short8*)&Wlds[(wid * 32 + rA) * 64 + sw];
            short8 bf1 = *(const short8*)&Wlds[(wid * 32 + 16 + rA) * 64 + sw];
            accw[0][0] = __builtin_amdgcn_mfma_f32_16x16x32_bf16(af0, bf0, accw[0][0], 0, 0, 0);
            accw[0][1] = __builtin_amdgcn_mfma_f32_16x16x32_bf16(af0, bf1, accw[0][1], 0, 0, 0);
            accw[1][0] = __builtin_amdgcn_mfma_f32_16x16x32_bf16(af1, bf0, accw[1][0], 0, 0, 0);
            accw[1][1] = __builtin_amdgcn_mfma_f32_16x16x32_bf16(af1, bf1, accw[1][1], 0, 0, 0);
        }
    }
    __syncthreads();
#pragma unroll
    for (int m = 0; m < 2; ++m)
#pragma unroll
        for (int n = 0; n < 2; ++n) {
            int cc = wid * 32 + n * 16 + rA;
            float bv = bo[cc];
#pragma unroll
            for (int r = 0; r < 4; ++r) {
                int rl = m * 16 + kq * 4 + r;
                vbuf[rl * 133 + cc] = accw[m][n][r] + bv + x[(size_t)(rows0 + rl) * 128 + cc];
            }
        }
    __syncthreads();
    float x1[16];
    {
        const float* vr = vbuf + row * 133 + sub * 16;
        float s = 0.f, s2 = 0.f;
#pragma unroll
        for (int j = 0; j < 16; ++j) {
            x1[j] = vr[j];
            s += x1[j];
            s2 += x1[j] * x1[j];
        }
        s += __shfl_xor(s, 1, 64);  s2 += __shfl_xor(s2, 1, 64);
        s += __shfl_xor(s, 2, 64);  s2 += __shfl_xor(s2, 2, 64);
        s += __shfl_xor(s, 4, 64);  s2 += __shfl_xor(s2, 4, 64);
        float mean = s * (1.f / 128.f);
        float var = s2 * (1.f / 128.f) - mean * mean;
        float rs = rsqrtf(var + 1e-5f);
#pragma unroll
        for (int j = 0; j < 4; ++j) {
            float4 gv = *(const float4*)(ln1g + sub * 16 + j * 4);
            float4 bv = *(const float4*)(ln1b + sub * 16 + j * 4);
            x1[j * 4 + 0] = (x1[j * 4 + 0] - mean) * rs * gv.x + bv.x;
            x1[j * 4 + 1] = (x1[j * 4 + 1] - mean) * rs * gv.y + bv.y;
            x1[j * 4 + 2] = (x1[j * 4 + 2] - mean) * rs * gv.z + bv.z;
            x1[j * 4 + 3] = (x1[j * 4 + 3] - mean) * rs * gv.w + bv.w;
        }
    }
    __syncthreads();
#pragma unroll
    for (int j = 0; j < 16; ++j) {
        int c = sub * 16 + j;
        int scol = (c & ~63) | ((((c >> 3) & 7) ^ (row & 7)) << 3) | (c & 7);
        Alds[row * 128 + scol] = f2b(x1[j]);
    }
    for (int nh = 0; nh < 2; ++nh) {
        f32x4 acc1[2][4] = {};
        for (int k0 = 0; k0 < 128; k0 += 64) {
            __syncthreads();
#pragma unroll
            for (int i = 0; i < 8; ++i) {
                int rl2 = i * 32 + wid * 8 + (lane >> 3);
                gload16(w1T + (size_t)(nh * 256 + rl2) * 128 + k0 + (((lane & 7) ^ (rl2 & 7)) << 3),
                        Wlds + (i * 32 + wid * 8) * 64);
            }
            __syncthreads();
#pragma unroll
            for (int ks = 0; ks < 2; ++ks) {
                int sw = ((ks * 4 + kq) ^ (rA & 7)) << 3;
                short8 af[2], bf4[4];
                af[0] = *(const short8*)&Alds[rA * 128 + k0 + sw];
                af[1] = *(const short8*)&Alds[(16 + rA) * 128 + k0 + sw];
#pragma unroll
                for (int n = 0; n < 4; ++n)
                    bf4[n] = *(const short8*)&Wlds[(wid * 64 + n * 16 + rA) * 64 + sw];
#pragma unroll
                for (int m = 0; m < 2; ++m)
#pragma unroll
                    for (int n = 0; n < 4; ++n)
                        acc1[m][n] = __builtin_amdgcn_mfma_f32_16x16x32_bf16(af[m], bf4[n], acc1[m][n], 0, 0, 0);
            }
        }
#pragma unroll
        for (int m = 0; m < 2; ++m)
#pragma unroll
            for (int n = 0; n < 4; ++n) {
                int cc = nh * 256 + wid * 64 + n * 16 + rA;
                float bv = b1[cc];
#pragma unroll
                for (int r = 0; r < 4; ++r) {
                    int rl = m * 16 + kq * 4 + r;
                    float v = fmaxf(acc1[m][n][r] + bv, 0.f);
                    int scol = (cc & ~63) | (((((cc >> 3) & 7) ^ (rl & 7)) & 7) << 3) | (cc & 7);
                    f1[rl * 512 + scol] = f2b(v);
                }
            }
    }
    __syncthreads();
    f32x4 acc2[2][2] = {};
    for (int k0 = 0; k0 < 512; k0 += 64) {
        if (k0) __syncthreads();
#pragma unroll
        for (int i = 0; i < 4; ++i) {
            int rl2 = i * 32 + wid * 8 + (lane >> 3);
            gload16(w2T + (size_t)rl2 * 512 + k0 + (((lane & 7) ^ (rl2 & 7)) << 3),
                    Wlds + (i * 32 + wid * 8) * 64);
        }
        __syncthreads();
#pragma unroll
        for (int ks = 0; ks < 2; ++ks) {
            int sw = ((ks * 4 + kq) ^ (rA & 7)) << 3;
            short8 af0 = *(const short8*)&f1[rA * 512 + k0 + sw];
            short8 af1 = *(const short8*)&f1[(16 + rA) * 512 + k0 + sw];
            short8 bf0 = *(const short8*)&Wlds[(wid * 32 + rA) * 64 + sw];
            short8 bf1 = *(const short8*)&Wlds[(wid * 32 + 16 + rA) * 64 + sw];
            acc2[0][0] = __builtin_amdgcn_mfma_f32_16x16x32_bf16(af0, bf0, acc2[0][0], 0, 0, 0);
            acc2[0][1] = __builtin_amdgcn_mfma_f32_16x16x32_bf16(af0, bf1, acc2[0][1], 0, 0, 0);
            acc2[1][0] = __builtin_amdgcn_mfma_f32_16x16x32_bf16(af1, bf0, acc2[1][0], 0, 0, 0);
            acc2[1][1] = __builtin_amdgcn_mfma_f32_16x16x32_bf16(af1, bf1, acc2[1][1], 0, 0, 0);
        }
    }
    __syncthreads();
#pragma unroll
    for (int m = 0; m < 2; ++m)
#pragma unroll
        for (int n = 0; n < 2; ++n) {
            int cc = wid * 32 + n * 16 + rA;
            float bv = b2[cc];
#pragma unroll
            for (int r = 0; r < 4; ++r) {
                int rl = m * 16 + kq * 4 + r;
                vbuf[rl * 133 + cc] = acc2[m][n][r] + bv;
            }
        }
    __syncthreads();
    {
        const float* vr = vbuf + row * 133 + sub * 16;
        float vv[16];
        float s = 0.f, s2 = 0.f;
#pragma unroll
        for (int j = 0; j < 16; ++j) {
            vv[j] = vr[j] + x1[j];
            s += vv[j];
            s2 += vv[j] * vv[j];
        }
        s += __shfl_xor(s, 1, 64);  s2 += __shfl_xor(s2, 1, 64);
        s += __shfl_xor(s, 2, 64);  s2 += __shfl_xor(s2, 2, 64);
        s += __shfl_xor(s, 4, 64);  s2 += __shfl_xor(s2, 4, 64);
        float mean = s * (1.f / 128.f);
        float var = s2 * (1.f / 128.f) - mean * mean;
        float rs = rsqrtf(var + 1e-5f);
        int grow = rows0 + row;
        float* xrow = x + (size_t)grow * 128 + sub * 16;
        u16* xbrow = xbout + (size_t)grow * 128 + sub * 16;
#pragma unroll
        for (int j = 0; j < 4; ++j) {
            float4 gv = *(const float4*)(ln2g + sub * 16 + j * 4);
            float4 bv = *(const float4*)(ln2b + sub * 16 + j * 4);
            float o0 = (vv[j * 4 + 0] - mean) * rs * gv.x + bv.x;
            float o1 = (vv[j * 4 + 1] - mean) * rs * gv.y + bv.y;
            float o2 = (vv[j * 4 + 2] - mean) * rs * gv.z + bv.z;
            float o3 = (vv[j * 4 + 3] - mean) * rs * gv.w + bv.w;
            *(float4*)(xrow + j * 4) = make_float4(o0, o1, o2, o3);
            *(ushort4*)(xbrow + j * 4) = make_ushort4(f2b(o0), f2b(o1), f2b(o2), f2b(o3));
        }
    }
}

// ===================== fusion + positional encoding =====================
__global__ __launch_bounds__(256) void k_fusion(const float* __restrict__ spe, const int* __restrict__ traj,
                                                const float* __restrict__ ue_tab, const int* __restrict__ uid,
                                                const float* __restrict__ tempx, const int* __restrict__ hwx,
                                                const float* __restrict__ ce_tab, const float* __restrict__ flw,
                                                const float* __restrict__ flb, float* __restrict__ x,
                                                u16* __restrict__ xb) {
    __shared__ float Ws[22 * D_];
    __shared__ float bs[D_];
    __shared__ float ins[2][22];
    int tid = threadIdx.x;
    for (int i = tid; i < 22 * D_; i += 256) Ws[i] = flw[i];
    if (tid < D_) bs[tid] = flb[tid];
    __syncthreads();
    int ro = tid >> 7, d = tid & 127;
    int base = blockIdx.x * 32;
    for (int ir = 0; ir < 16; ++ir) {
        int tok = base + ir * 2 + ro;
        int b = tok >> 8, s = tok & 255;
        if (d < TD_) ins[ro][d] = tempx[(size_t)tok * TD_ + d];
        else if (d < 22) ins[ro][d] = ce_tab[(size_t)hwx[tok] * CED_ + (d - TD_)];
        __syncthreads();
        float acc = bs[d];
#pragma unroll
        for (int k = 0; k < 22; ++k) acc = fmaf(ins[ro][k], Ws[k * D_ + d], acc);
        acc = fmaxf(acc, 0.f);
        int i2 = d & ~1;
        float ang = (float)s * __expf(-(float)i2 * 0.0719557841560639f);
        float pe = (d & 1) ? cosf(ang) : sinf(ang);
        float v = spe[(size_t)traj[tok] * D_ + d] + ue_tab[(size_t)uid[b] * D_ + d] + acc + pe;
        x[(size_t)tok * D_ + d] = v;
        xb[(size_t)tok * D_ + d] = f2b(v);
        __syncthreads();
    }
}

// ===================== launch =====================
extern "C" void kernel_launch(void* const* d_in, const int* in_sizes, int n_in,
                              void* d_out, int out_size, void* d_ws, size_t ws_size,
                              hipStream_t stream) {
    const float* node_feature = (const float*)d_in[0];
    const int*   edge_index   = (const int*)d_in[1];
    const int*   traj_x       = (const int*)d_in[2];
    const float* temporal_x   = (const float*)d_in[3];
    const int*   user_id_x    = (const int*)d_in[4];
    const int*   mask         = (const int*)d_in[5];
    const int*   end_idx      = (const int*)d_in[6];
    const float* tmat         = (const float*)d_in[8];
    const float* dmat         = (const float*)d_in[9];
    const int*   highway_x    = (const int*)d_in[10];
    const float* lambda2      = (const float*)d_in[11];
    const float* gnn_w1       = (const float*)d_in[12];
    const float* gnn_b1       = (const float*)d_in[13];
    const float* gnn_w2       = (const float*)d_in[14];
    const float* gnn_b2       = (const float*)d_in[15];
    const float* ue_tab       = (const float*)d_in[16];
    const float* ce_tab       = (const float*)d_in[17];
    const float* fl_w         = (const float*)d_in[18];
    const float* fl_b         = (const float*)d_in[19];
    const float* wqkv         = (const float*)d_in[20];
    const float* bqkv         = (const float*)d_in[21];
    const float* wo           = (const float*)d_in[22];
    const float* bo           = (const float*)d_in[23];
    const float* ln1_g        = (const float*)d_in[24];
    const float* ln1_b        = (const float*)d_in[25];
    const float* ln2_g        = (const float*)d_in[26];
    const float* ln2_b        = (const float*)d_in[27];
    const float* ffn_w1       = (const float*)d_in[28];
    const float* ffn_b1       = (const float*)d_in[29];
    const float* ffn_w2       = (const float*)d_in[30];
    const float* ffn_b2       = (const float*)d_in[31];
    const float* head_w       = (const float*)d_in[32];
    const float* head_b       = (const float*)d_in[33];
    float* out = (float*)d_out;

    // ---- workspace layout (float units) ----
    float* w     = (float*)d_ws;
    int*   cnt   = (int*)w;                  // [0, 40,960)
    float* spe   = w + 40960;                // [40,960, 5,169,152)
    u16*   biasb = (u16*)(w + 5169152);      // [5,169,152, 7,266,304)
    float* wreg  = w + 7266304;              // bf16 weights -> ends 7,999,488
    u16* wqkvT = (u16*)wreg;
    u16* woT   = wqkvT + 4 * 384 * 128;
    u16* w1T   = woT + 4 * 128 * 128;
    u16* w2T   = w1T + 4 * 512 * 128;
    u16* gw1T  = w2T + 4 * 128 * 512;
    u16* gw2T  = gw1T + 128 * 64;
    u16* hwT   = gw2T + 128 * 128;
    float* pool  = w + 8000000;
    // GNN phase
    u16*   h1b   = (u16*)pool;               // [0, 2,564,096) f
    u16*   in1b  = (u16*)(pool + 2564096);   // [2,564,096, 3,846,144)
    u16*   in2b  = (u16*)(pool + 3846144);   // [3,846,144, 6,410,240)
    int*   off   = (int*)(pool + 6410240);
    int*   cursor= (int*)(pool + 6450304);
    int*   ebuf  = (int*)(pool + 6490368);
    int*   part  = (int*)(pool + 6650368);
    // transformer phase
    float* x     = pool;                     // [0, 2,097,152)
    u16*   xb    = (u16*)(pool + 2097152);   // [2,097,152, 2,621,440)
    u16*   attob = (u16*)(pool + 4718592);   // [4,718,592, 5,242,880)

    const int* esrc = edge_index;
    const int* edst = edge_index + E_;

    // ---- uber prep ----
    UberArgs ua;
    const float* srcs[7] = {wqkv, wo, ffn_w1, ffn_w2, gnn_w1, gnn_w2, head_w};
    u16* dsts[7]        = {wqkvT, woT, w1T, w2T, gw1T, gw2T, hwT};
    int Ks[7]    = {128, 128, 128, 512, 32, 128, 128};
    int Npads[7] = {384, 128, 512, 128, 128, 128, UP_};
    int Nsrcs[7] = {384, 128, 512, 128, 128, 128, U_};
    int Kps[7]   = {128, 128, 128, 512, 64, 128, 128};
    int Ls[7]    = {4, 4, 4, 4, 1, 1, 1};
    int bb = UB_CNT_END;
    for (int t = 0; t < 7; ++t) {
        ua.csrc[t] = srcs[t]; ua.cdst[t] = dsts[t];
        ua.K[t] = Ks[t]; ua.Npad[t] = Npads[t]; ua.Nsrc[t] = Nsrcs[t]; ua.Kp[t] = Kps[t];
        ua.base[t] = bb;
        bb += (Npads[t] / 32) * (Kps[t] / 32) * Ls[t];
    }
    ua.tm = tmat; ua.dm = dmat; ua.maskp = mask; ua.lambda2 = lambda2;
    ua.bias = biasb; ua.cnt = cnt;
    k_uber<<<UB_TOTAL, 256, 0, stream>>>(ua);

    // ---- GNN: CSR build + gathers + GEMMs ----
    k_count<<<(E_ + 255) / 256, 256, 0, stream>>>(edst, cnt);
    k_scanA<<<NSCB, 256, 0, stream>>>(cnt, part);
    k_scanB<<<NSCB, 256, 0, stream>>>(cnt, part, off, cursor);
    k_fill<<<(E_ + 255) / 256, 256, 0, stream>>>(esrc, edst, cursor, ebuf);
    k_gprep1<<<NP_ / 8, 256, 0, stream>>>(node_feature, off, cnt, ebuf, in1b);
    k_mgemm<128, 1, 1, 0><<<dim3(NP_ / 128, 1), 256, 0, stream>>>(in1b, gw1T, gnn_b1, h1b, nullptr, NP_, D_, 64);
    k_gprep2<<<NP_ / 4, 256, 0, stream>>>(h1b, off, cnt, ebuf, in2b);
    k_mgemm<128, 1, 0, 0><<<dim3(NP_ / 128, 1), 256, 0, stream>>>(in2b, gw2T, gnn_b2, spe, nullptr, NP_, D_, D_);

    // ---- fusion ----
    k_fusion<<<(B_ * S_) / 32, 256, 0, stream>>>(spe, traj_x, ue_tab, user_id_x,
                                                 temporal_x, highway_x, ce_tab, fl_w, fl_b, x, xb);

    // ---- transformer: 2 kernels per layer ----
    const int M = B_ * S_;
    for (int l = 0; l < L_; ++l) {
        k_qkvatt<<<B_ * H_, 256, 0, stream>>>(xb, wqkvT + (size_t)l * 384 * 128,
                                              bqkv + (size_t)l * 384, biasb, attob);
        k_layer<<<M / 32, 256, 0, stream>>>(attob, woT + (size_t)l * 128 * 128, bo + l * D_,
                                            ln1_g + l * D_, ln1_b + l * D_,
                                            w1T + (size_t)l * 512 * 128, ffn_b1 + l * FF_,
                                            w2T + (size_t)l * 128 * 512, ffn_b2 + l * D_,
                                            ln2_g + l * D_, ln2_b + l * D_, x, xb);
    }

    // ---- head (gather fused) ----
    k_mgemm<64, 0, 0, 1><<<dim3(1, UP_ / 128), 256, 0, stream>>>(xb, hwT, head_b, out, end_idx, B_, U_, D_);
}